// Round 6
// baseline (2560.952 us; speedup 1.0000x reference)
//
#include <hip/hip_runtime.h>

typedef unsigned short u16;
typedef unsigned int u32;
typedef __attribute__((ext_vector_type(8))) short s8v;      // 8 bf16
typedef __attribute__((ext_vector_type(8))) _Float16 h8v;   // 8 fp16
typedef __attribute__((ext_vector_type(4))) float f4v;      // C/D frag

#define NN 100000
#define MROW 100096
#define EE 500000
#define GG 16
#define HPIT 304      // h row pitch (u16): [hi 152 | lo 152]
#define UPIT 152      // u/U row pitch (u16): fp16, cols 150/151 carry degrees
#define WPIT 320      // weight row pitch (u16): [hi 160 | lo 160]
#define WMAT (192*WPIT)   // one weight matrix (u16 elems)

__device__ __forceinline__ u16 f2bf(float x){ u32 u=__float_as_uint(x); return (u16)((u + 0x7fffu + ((u>>16)&1u))>>16); }
__device__ __forceinline__ float bf2f(u16 h){ return __uint_as_float(((u32)h)<<16); }
__device__ __forceinline__ u16 f2h(float x){ union{u16 u;_Float16 f;}c; c.f=(_Float16)x; return c.u; }
__device__ __forceinline__ float h2f(u16 b){ union{u16 u;_Float16 f;}c; c.u=b; return (float)c.f; }

#define GLOAD_LDS(gp, lp) \
    __builtin_amdgcn_global_load_lds((const __attribute__((address_space(1))) void*)(gp), \
                                     (__attribute__((address_space(3))) void*)(lp), 16, 0, 0)

// ---------------- staging helper (A only; W goes direct global->reg) ----------------
template<int NI>
__device__ __forceinline__ void stage_a(const u16* base, const int (&off)[NI], int koff,
                                        const int (&lds)[NI], u16* dst){
#pragma unroll
    for (int i=0;i<NI;i++) GLOAD_LDS(base+off[i]+koff, dst+lds[i]);
}

// ---------------- MFMA helpers (A frags in regs, W frags in regs) ----------------
template<bool ISBF>
__device__ __forceinline__ void mf3(const s8v (&af)[4], s8v w0, s8v w1, s8v w2,
                                    f4v (&X)[4], f4v (&Y)[4], f4v (&Z)[4]){
#pragma unroll
    for (int mi=0;mi<4;mi++){
        if constexpr (ISBF){
            X[mi]=__builtin_amdgcn_mfma_f32_16x16x32_bf16(af[mi],w0,X[mi],0,0,0);
            Y[mi]=__builtin_amdgcn_mfma_f32_16x16x32_bf16(af[mi],w1,Y[mi],0,0,0);
            Z[mi]=__builtin_amdgcn_mfma_f32_16x16x32_bf16(af[mi],w2,Z[mi],0,0,0);
        } else {
            X[mi]=__builtin_amdgcn_mfma_f32_16x16x32_f16(*(const h8v*)&af[mi],*(const h8v*)&w0,X[mi],0,0,0);
            Y[mi]=__builtin_amdgcn_mfma_f32_16x16x32_f16(*(const h8v*)&af[mi],*(const h8v*)&w1,Y[mi],0,0,0);
            Z[mi]=__builtin_amdgcn_mfma_f32_16x16x32_f16(*(const h8v*)&af[mi],*(const h8v*)&w2,Z[mi],0,0,0);
        }
    }
}

template<bool ISBF>
__device__ __forceinline__ void mf2(const s8v (&af)[4], s8v w0, s8v w1,
                                    f4v (&X)[4], f4v (&Y)[4]){
#pragma unroll
    for (int mi=0;mi<4;mi++){
        if constexpr (ISBF){
            X[mi]=__builtin_amdgcn_mfma_f32_16x16x32_bf16(af[mi],w0,X[mi],0,0,0);
            Y[mi]=__builtin_amdgcn_mfma_f32_16x16x32_bf16(af[mi],w1,Y[mi],0,0,0);
        } else {
            X[mi]=__builtin_amdgcn_mfma_f32_16x16x32_f16(*(const h8v*)&af[mi],*(const h8v*)&w0,X[mi],0,0,0);
            Y[mi]=__builtin_amdgcn_mfma_f32_16x16x32_f16(*(const h8v*)&af[mi],*(const h8v*)&w1,Y[mi],0,0,0);
        }
    }
}

// load 8 A-frags (2 ks x 4 mi) from 64-wide LDS tile
__device__ __forceinline__ void lda64(const u16* lA_, const int (&aF)[2][4], s8v (&a)[2][4]){
#pragma unroll
    for (int ks=0;ks<2;ks++)
#pragma unroll
        for (int mi=0;mi<4;mi++) a[ks][mi] = *(const s8v*)(lA_+aF[ks][mi]);
}
__device__ __forceinline__ void lda32(const u16* lA_, const int (&aF)[4], s8v (&a)[4]){
#pragma unroll
    for (int mi=0;mi<4;mi++) a[mi] = *(const s8v*)(lA_+aF[mi]);
}

// ---------------- edge-MLP layer 1 (both sets): u_s = lrelu(h @ W1_s^T + b1_s) ----------------
__global__ __launch_bounds__(256,3) void k_ugemm2(const u16* __restrict__ H,
    const u16* __restrict__ W1b,   // 2 mats contiguous: [set0|set1]
    const float* __restrict__ b1t0, const float* __restrict__ b1t1,
    u16* __restrict__ u0, u16* __restrict__ u1)
{
    __shared__ u16 lA0[64*64], lA1[64*64];
    int tid=threadIdx.x, wv=tid>>6, lane=tid&63, lr=lane&15, quad=lane>>4;
    int m0=blockIdx.x*64, n0=blockIdx.y*64;
    int aL64[2], hO64[2];
#pragma unroll
    for (int i=0;i<2;i++){ int s=tid+i*256, row=s>>3, q8=((s&7)^(row&7))<<3;
        aL64[i]=s<<3; hO64[i]=(m0+row)*HPIT+q8; }
    int aL32[1], hO32[1];
    { int s=tid, row=s>>2, q8=((s&3)^(row&3))<<3; aL32[0]=s<<3; hO32[0]=(m0+row)*HPIT+q8; }
    int aF64[2][4], aF32[4];
#pragma unroll
    for (int ks=0;ks<2;ks++)
#pragma unroll
        for (int mi=0;mi<4;mi++){ int row=mi*16+lr, ph=(ks*4+quad)^(row&7); aF64[ks][mi]=row*64+ph*8; }
#pragma unroll
    for (int mi=0;mi<4;mi++){ int row=mi*16+lr, ph=quad^(row&3); aF32[mi]=row*32+ph*8; }
    // direct-W per-lane offset (elements); scalar mat/plane/k offsets fold in
    const u16* Ww = W1b + (n0+wv*16+lr)*WPIT + quad*8;

    const u16* Hlo = H + 152;
    f4v a0[4]={}, a1[4]={};
    s8v a[2][4]; s8v a32[4];
#pragma unroll
    for (int kc=0;kc<2;kc++){
        int koff=kc*64;
        __syncthreads();
        stage_a<2>(H,  hO64,koff,aL64,lA0);
        stage_a<2>(Hlo,hO64,koff,aL64,lA1);
        __syncthreads();
        lda64(lA0,aF64,a);                                   // A-hi
#pragma unroll
        for (int pl=0;pl<2;pl++){
            int wo = pl*160 + koff;
#pragma unroll
            for (int ks=0;ks<2;ks++)
                mf2<true>(a[ks], *(const s8v*)(Ww+wo+ks*32), *(const s8v*)(Ww+WMAT+wo+ks*32), a0,a1);
        }
        lda64(lA1,aF64,a);                                   // A-lo x W-hi
#pragma unroll
        for (int ks=0;ks<2;ks++)
            mf2<true>(a[ks], *(const s8v*)(Ww+koff+ks*32), *(const s8v*)(Ww+WMAT+koff+ks*32), a0,a1);
    }
    __syncthreads();
    stage_a<1>(H,  hO32,128,aL32,lA0);
    stage_a<1>(Hlo,hO32,128,aL32,lA1);
    __syncthreads();
    lda32(lA0,aF32,a32);
#pragma unroll
    for (int pl=0;pl<2;pl++){
        int wo = pl*160 + 128;
        mf2<true>(a32, *(const s8v*)(Ww+wo), *(const s8v*)(Ww+WMAT+wo), a0,a1);
    }
    lda32(lA1,aF32,a32);
    mf2<true>(a32, *(const s8v*)(Ww+128), *(const s8v*)(Ww+WMAT+128), a0,a1);

    int c = n0 + wv*16 + lr;
    if (c < 152){
        float bb0=b1t0[c], bb1=b1t1[c];
#pragma unroll
        for (int mi=0;mi<4;mi++)
#pragma unroll
            for (int reg=0;reg<4;reg++){
                int r = m0 + mi*16 + quad*4 + reg;
                if (r >= NN) continue;
                float v0=a0[mi][reg]+bb0; v0 = v0>0.f ? v0 : 0.01f*v0;
                float v1=a1[mi][reg]+bb1; v1 = v1>0.f ? v1 : 0.01f*v1;
                if (c>=150){ v0=0.f; v1=0.f; }
                u0[(size_t)r*UPIT+c]=f2h(v0);
                u1[(size_t)r*UPIT+c]=f2h(v1);
            }
    }
}

// ---------------- fused GRU mega-kernel ----------------
__global__ __launch_bounds__(256,3) void k_mega(const u16* __restrict__ H,
    const u16* __restrict__ U0, const u16* __restrict__ U1,
    const u16* __restrict__ Cb,   // 6 mats: [s][gate r,z,n], fp16-split
    const u16* __restrict__ Wh,   // 3 mats: Whh gates r,z,n (split-bf16)
    const float* __restrict__ tb, u16* __restrict__ Hn)
{
    __shared__ u16 lA0[64*64], lA1[64*64];
    int tid=threadIdx.x, wv=tid>>6, lane=tid&63, lr=lane&15, quad=lane>>4;
    int m0=blockIdx.x*64, n0=blockIdx.y*64;
    int aL64[2], uO64[2], hO64[2];
#pragma unroll
    for (int i=0;i<2;i++){ int s=tid+i*256, row=s>>3, q8=((s&7)^(row&7))<<3;
        aL64[i]=s<<3; uO64[i]=(m0+row)*UPIT+q8; hO64[i]=(m0+row)*HPIT+q8; }
    int aL32[1], uO32[1], hO32[1];
    { int s=tid, row=s>>2, q8=((s&3)^(row&3))<<3; aL32[0]=s<<3; uO32[0]=(m0+row)*UPIT+q8; hO32[0]=(m0+row)*HPIT+q8; }
    int aF64[2][4], aF32[4];
#pragma unroll
    for (int ks=0;ks<2;ks++)
#pragma unroll
        for (int mi=0;mi<4;mi++){ int row=mi*16+lr, ph=(ks*4+quad)^(row&7); aF64[ks][mi]=row*64+ph*8; }
#pragma unroll
    for (int mi=0;mi<4;mi++){ int row=mi*16+lr, ph=quad^(row&3); aF32[mi]=row*32+ph*8; }
    int wvo = (n0+wv*16+lr)*WPIT + quad*8;
    const u16* Whw = Wh + wvo;

    f4v aR[4]={}, aZ[4]={}, aI[4]={}, aHh[4]={};
    s8v a[2][4]; s8v a32[4];

    // ---- u-side (fp16): r,z,in from U0,U1 with composite weights (deg folded at k=150/151) ----
#pragma unroll
    for (int s=0;s<2;s++){
        const u16* U  = s ? U1 : U0;
        const u16* Cw = Cb + (size_t)s*(3*WMAT) + wvo;
#pragma unroll
        for (int kc=0;kc<2;kc++){
            int koff=kc*64;
            __syncthreads();
            stage_a<2>(U,uO64,koff,aL64,lA0);
            __syncthreads();
            lda64(lA0,aF64,a);
#pragma unroll
            for (int pl=0;pl<2;pl++){
                int wo = pl*160 + koff;
#pragma unroll
                for (int ks=0;ks<2;ks++)
                    mf3<false>(a[ks], *(const s8v*)(Cw+wo+ks*32),
                                      *(const s8v*)(Cw+WMAT+wo+ks*32),
                                      *(const s8v*)(Cw+2*WMAT+wo+ks*32), aR,aZ,aI);
            }
        }
        __syncthreads();
        stage_a<1>(U,uO32,128,aL32,lA0);
        __syncthreads();
        lda32(lA0,aF32,a32);
#pragma unroll
        for (int pl=0;pl<2;pl++){
            int wo = pl*160 + 128;
            mf3<false>(a32, *(const s8v*)(Cw+wo), *(const s8v*)(Cw+WMAT+wo),
                            *(const s8v*)(Cw+2*WMAT+wo), aR,aZ,aI);
        }
    }
    // ---- h-side (split-bf16): r,z,hn ----
    const u16* Hlo = H + 152;
#pragma unroll
    for (int kc=0;kc<2;kc++){
        int koff=kc*64;
        __syncthreads();
        stage_a<2>(H,  hO64,koff,aL64,lA0);
        stage_a<2>(Hlo,hO64,koff,aL64,lA1);
        __syncthreads();
        lda64(lA0,aF64,a);                                   // A-hi x (W-hi, W-lo)
#pragma unroll
        for (int pl=0;pl<2;pl++){
            int wo = pl*160 + koff;
#pragma unroll
            for (int ks=0;ks<2;ks++)
                mf3<true>(a[ks], *(const s8v*)(Whw+wo+ks*32),
                                 *(const s8v*)(Whw+WMAT+wo+ks*32),
                                 *(const s8v*)(Whw+2*WMAT+wo+ks*32), aR,aZ,aHh);
        }
        lda64(lA1,aF64,a);                                   // A-lo x W-hi
#pragma unroll
        for (int ks=0;ks<2;ks++)
            mf3<true>(a[ks], *(const s8v*)(Whw+koff+ks*32),
                             *(const s8v*)(Whw+WMAT+koff+ks*32),
                             *(const s8v*)(Whw+2*WMAT+koff+ks*32), aR,aZ,aHh);
    }
    __syncthreads();
    stage_a<1>(H,  hO32,128,aL32,lA0);
    stage_a<1>(Hlo,hO32,128,aL32,lA1);
    __syncthreads();
    lda32(lA0,aF32,a32);
#pragma unroll
    for (int pl=0;pl<2;pl++){
        int wo = pl*160 + 128;
        mf3<true>(a32, *(const s8v*)(Whw+wo), *(const s8v*)(Whw+WMAT+wo),
                       *(const s8v*)(Whw+2*WMAT+wo), aR,aZ,aHh);
    }
    lda32(lA1,aF32,a32);
    mf3<true>(a32, *(const s8v*)(Whw+128), *(const s8v*)(Whw+WMAT+128),
                   *(const s8v*)(Whw+2*WMAT+128), aR,aZ,aHh);

    // ---- GRU epilogue ----
    int c = n0 + wv*16 + lr;
    if (c < 152){
        float bR=tb[c], bZ=tb[160+c], bI=tb[320+c], bHn=tb[480+c];
#pragma unroll
        for (int mi=0;mi<4;mi++)
#pragma unroll
            for (int reg=0;reg<4;reg++){
                int r = m0 + mi*16 + quad*4 + reg;
                if (r >= NN) continue;
                float pr=aR[mi][reg]+bR, pz=aZ[mi][reg]+bZ, pi=aI[mi][reg]+bI, ph_=aHh[mi][reg]+bHn;
                float rg = 1.f/(1.f+__expf(-pr));
                float zg = 1.f/(1.f+__expf(-pz));
                float e2 = __expf(2.f*(pi + rg*ph_));
                float n  = 1.f - 2.f/(e2+1.f);
                float hold = bf2f(H[(size_t)r*HPIT+c]) + bf2f(H[(size_t)r*HPIT+152+c]);
                float o = (1.f-zg)*n + zg*hold;
                if (c>=150) o = 0.f;
                u16 hi = f2bf(o);
                Hn[(size_t)r*HPIT+c] = hi;
                Hn[(size_t)r*HPIT+152+c] = f2bf(o - bf2f(hi));
            }
    }
}

// ---------------- prep kernels ----------------
__global__ void k_splitW(const float* __restrict__ src, int rowoff, u16* __restrict__ dst){
    int idx = blockIdx.x*256 + threadIdx.x;     // 192*160
    if (idx >= 192*160) return;
    int r = idx/160, c = idx - r*160;
    float x = (r<150 && c<150) ? src[(size_t)(rowoff+r)*150 + c] : 0.f;
    u16 hi = f2bf(x);
    dst[(size_t)r*WPIT + c] = hi;
    dst[(size_t)r*WPIT + 160 + c] = f2bf(x - bf2f(hi));
}

// composite C[s*3+g] = Wih_g @ W2_s (cols 0..149) ; col 150 (s=0) / 151 (s=1) = Wih_g @ b2_s
__global__ void k_comp(const float* __restrict__ Wih, const float* __restrict__ W2_0,
                       const float* __restrict__ W2_1, const float* __restrict__ b2_0,
                       const float* __restrict__ b2_1, u16* __restrict__ Cb){
    int idx = blockIdx.x*256 + threadIdx.x;     // 6*192*160
    if (idx >= 6*192*160) return;
    int mat = idx/(192*160), rem = idx - mat*(192*160);
    int o = rem/160, c = rem - o*160;
    int s = mat/3, g = mat - s*3;
    float v = 0.f;
    if (o < 150){
        const float* wrow = Wih + (size_t)(g*150+o)*150;
        if (c < 150){
            const float* W2 = s ? W2_1 : W2_0;
            for (int j=0;j<150;j++) v += wrow[j] * W2[(size_t)j*150 + c];
        } else if (c==150 && s==0){
            for (int j=0;j<150;j++) v += wrow[j] * b2_0[j];
        } else if (c==151 && s==1){
            for (int j=0;j<150;j++) v += wrow[j] * b2_1[j];
        }
    }
    u16* D = Cb + (size_t)mat*WMAT;
    union{u16 u;_Float16 f;} h1,h2;
    h1.f = (_Float16)v;
    h2.f = (_Float16)(v - (float)h1.f);
    D[(size_t)o*WPIT + c] = h1.u;
    D[(size_t)o*WPIT + 160 + c] = h2.u;
}

__global__ void k_tabs(const float* bih,const float* bhh,
                       const float* b1_0,const float* b1_1,
                       float* tb, float* b1t0, float* b1t1){
    int idx = blockIdx.x*256 + threadIdx.x;     // 6*160
    if (idx >= 6*160) return;
    int t = idx/160, c = idx - t*160;
    float v = 0.f;
    if (c < 150){
        if (t==0) v = bih[c]+bhh[c];
        else if (t==1) v = bih[150+c]+bhh[150+c];
        else if (t==2) v = bih[300+c];
        else if (t==3) v = bhh[300+c];
        else if (t==4) v = b1_0[c];
        else v = b1_1[c];
    }
    if (t<4) tb[t*160+c]=v;
    else if (t==4) b1t0[c]=v;
    else b1t1[c]=v;
}

__global__ void k_padfc1(const float* __restrict__ s, float* __restrict__ d){
    int idx = blockIdx.x*256 + threadIdx.x;     // 80*160
    if (idx >= 80*160) return;
    int r = idx/160, c = idx - r*160;
    d[idx] = (c<151) ? s[r*151 + c] : 0.f;
}

__global__ void k_inith(const float* __restrict__ nodes, u16* __restrict__ H){
    int idx = blockIdx.x*256 + threadIdx.x;     // NN*152
    if (idx >= NN*152) return;
    int m = idx/152, c = idx - m*152;
    float x = (c<150) ? nodes[(size_t)m*150 + c] : 0.f;
    u16 hi = f2bf(x);
    H[(size_t)m*HPIT + c] = hi;
    H[(size_t)m*HPIT + 152 + c] = f2bf(x - bf2f(hi));
}

// ---------------- CSR build ----------------
__global__ void k_hist(const int* __restrict__ edges, int* __restrict__ cnt){
    int e = blockIdx.x*256 + threadIdx.x;
    if (e >= EE) return;
    atomicAdd(&cnt[edges[2*e]], 1);
}

__global__ __launch_bounds__(1024) void k_scan(const int* __restrict__ cnt,
                                               int* __restrict__ off, int* __restrict__ cur){
    __shared__ int sd[1024];
    __shared__ int s_run;
    int t = threadIdx.x;
    if (t==0) s_run = 0;
    __syncthreads();
    for (int base=0; base<NN; base+=8192){
        int i0 = base + t*8;
        int v[8]; int s = 0;
#pragma unroll
        for (int u=0; u<8; u++){ int i=i0+u; v[u]=(i<NN)?cnt[i]:0; s+=v[u]; }
        sd[t]=s;
        __syncthreads();
        int runbase = s_run;
        for (int ofs=1; ofs<1024; ofs<<=1){
            int y=0;
            if (t>=ofs) y=sd[t-ofs];
            __syncthreads();
            if (t>=ofs) sd[t]+=y;
            __syncthreads();
        }
        int excl = runbase + sd[t] - s;
#pragma unroll
        for (int u=0; u<8; u++){
            int i=i0+u;
            if (i<NN){ off[i]=excl; cur[i]=excl; excl+=v[u]; }
        }
        __syncthreads();
        if (t==1023) s_run = runbase + sd[1023];
        __syncthreads();
    }
    if (t==0) off[NN] = s_run;
}

__global__ void k_fill(const int* __restrict__ edges, int* __restrict__ cur, int* __restrict__ csr){
    int e = blockIdx.x*256 + threadIdx.x;
    if (e >= EE) return;
    int dst = edges[2*e], src = edges[2*e+1];
    int pos = atomicAdd(&cur[dst], 1);
    csr[pos] = src;
}

// ---------------- gather (u32 packed fp16); degree -> cols 150/151 ----------------
__global__ void k_gath2(const u16* __restrict__ u0, const u16* __restrict__ u1,
                        const int* __restrict__ off0, const int* __restrict__ csr0,
                        const int* __restrict__ off1, const int* __restrict__ csr1,
                        u16* __restrict__ U0, u16* __restrict__ U1){
    int d = blockIdx.x*4 + (threadIdx.x>>6);
    if (d >= NN) return;
    int lane = threadIdx.x & 63;
    const u16* u = blockIdx.y ? u1 : u0;
    const int* off = blockIdx.y ? off1 : off0;
    const int* csr = blockIdx.y ? csr1 : csr0;
    u16* U = blockIdx.y ? U1 : U0;
    int e0 = off[d], e1 = off[d+1];
    bool tl = lane < 12;
    float s0=0.f, s1=0.f, t0=0.f, t1=0.f;
    for (int e=e0; e<e1; e++){
        const u32* r = (const u32*)(u + (size_t)csr[e]*UPIT);
        u32 v = r[lane];
        s0 += h2f((u16)(v & 0xffffu));
        s1 += h2f((u16)(v >> 16));
        if (tl){
            u32 w = r[64+lane];
            t0 += h2f((u16)(w & 0xffffu));
            t1 += h2f((u16)(w >> 16));
        }
    }
    if (lane == 11){ t0 = (float)(e1-e0); t1 = t0; }   // cols 150,151 = degree
    u32* Ur = (u32*)(U + (size_t)d*UPIT);
    Ur[lane] = (u32)f2h(s0) | ((u32)f2h(s1) << 16);
    if (tl) Ur[64+lane] = (u32)f2h(t0) | ((u32)f2h(t1) << 16);
}

// ---------------- segment sum + readout ----------------
__global__ void k_seg(const u16* __restrict__ H, const int* __restrict__ gid, float* __restrict__ g){
    int f = threadIdx.x;
    if (f >= 150) return;
    int i0 = blockIdx.x*512;
    int i1 = i0 + 512; if (i1 > NN) i1 = NN;
    float acc = 0.f;
    int cg = gid[i0];
    for (int i=i0; i<i1; i++){
        int gg = gid[i];
        if (gg != cg){ atomicAdd(&g[cg*150+f], acc); acc=0.f; cg=gg; }
        acc += bf2f(H[(size_t)i*HPIT + f]) + bf2f(H[(size_t)i*HPIT + 152 + f]);
    }
    atomicAdd(&g[cg*150+f], acc);
}

__global__ void k_mlp(const float* __restrict__ g, const float* __restrict__ pt,
                      const float* __restrict__ fc1p, const float* __restrict__ fc1b,
                      const float* __restrict__ fc2W, const float* __restrict__ fc2b,
                      const float* __restrict__ fcLW, const float* __restrict__ fcLb,
                      float* __restrict__ out){
    __shared__ float X[GG][152];
    __shared__ float Y[GG][80];
    __shared__ float Z[GG][80];
    int t = threadIdx.x;
    for (int idx=t; idx<GG*152; idx+=256){
        int gi=idx/152, c=idx-gi*152;
        float v = 0.f;
        if (c < 150){
            float lg = logf(g[gi*150+c]);
            if (lg != lg) lg = 0.f;
            v = fmaxf(lg, 0.f);
        } else if (c == 150) v = pt[gi];
        X[gi][c] = v;
    }
    __syncthreads();
    for (int idx=t; idx<GG*80; idx+=256){
        int gi=idx/80, o=idx-gi*80;
        float acc = fc1b[o];
        for (int k=0;k<151;k++) acc = fmaf(X[gi][k], fc1p[o*160+k], acc);
        Y[gi][o] = acc>0.f ? acc : 0.01f*acc;
    }
    __syncthreads();
    for (int idx=t; idx<GG*80; idx+=256){
        int gi=idx/80, o=idx-gi*80;
        float acc = fc2b[o];
        for (int k=0;k<80;k++) acc = fmaf(Y[gi][k], fc2W[o*80+k], acc);
        Z[gi][o] = acc>0.f ? acc : 0.01f*acc;
    }
    __syncthreads();
    for (int idx=t; idx<GG*10; idx+=256){
        int gi=idx/10, o=idx-gi*10;
        float acc = fcLb[o];
        for (int k=0;k<80;k++) acc = fmaf(Z[gi][k], fcLW[o*80+k], acc);
        out[idx] = acc;
    }
}

// ---------------- host ----------------
extern "C" void kernel_launch(void* const* d_in, const int* in_sizes, int n_in,
                              void* d_out, int out_size, void* d_ws, size_t ws_size,
                              hipStream_t stream) {
    const float* nodes = (const float*)d_in[0];
    const float* pt    = (const float*)d_in[1];
    const float* W1_0 = (const float*)d_in[2];  const float* b1_0 = (const float*)d_in[3];
    const float* W2_0 = (const float*)d_in[4];  const float* b2_0 = (const float*)d_in[5];
    const float* W1_1 = (const float*)d_in[6];  const float* b1_1 = (const float*)d_in[7];
    const float* W2_1 = (const float*)d_in[8];  const float* b2_1 = (const float*)d_in[9];
    const float* Wih = (const float*)d_in[10];  const float* bih = (const float*)d_in[11];
    const float* Whh = (const float*)d_in[12];  const float* bhh = (const float*)d_in[13];
    const float* fc1W = (const float*)d_in[14]; const float* fc1b = (const float*)d_in[15];
    const float* fc2W = (const float*)d_in[16]; const float* fc2b = (const float*)d_in[17];
    const float* fcLW = (const float*)d_in[18]; const float* fcLb = (const float*)d_in[19];
    const int* edges[2] = {(const int*)d_in[20], (const int*)d_in[21]};
    const int* gid = (const int*)d_in[22];
    float* out = (float*)d_out;

    char* p = (char*)d_ws;
    auto alloc = [&](size_t bytes){ char* r = p; p += (bytes + 255) & ~(size_t)255; return r; };
    u16* XA = (u16*)alloc((size_t)MROW*HPIT*2);
    u16* XB = (u16*)alloc((size_t)MROW*HPIT*2);
    u16* U0 = (u16*)alloc((size_t)MROW*UPIT*2);
    u16* U1 = (u16*)alloc((size_t)MROW*UPIT*2);
    u16* W1b = (u16*)alloc((size_t)2*WMAT*2);    // [set0|set1] split-bf16
    u16* Wh  = (u16*)alloc((size_t)3*WMAT*2);    // Whh gates r,z,n split-bf16
    u16* Cb  = (u16*)alloc((size_t)6*WMAT*2);    // composite, fp16-split
    float* tb   = (float*)alloc(4*160*4);
    float* b1t0 = (float*)alloc(160*4);
    float* b1t1 = (float*)alloc(160*4);
    float* fc1p = (float*)alloc(80*160*4);
    float* gbuf = (float*)alloc(GG*150*4);
    int* off0 = (int*)alloc((NN+1)*4);
    int* off1 = (int*)alloc((NN+1)*4);
    int* cur  = (int*)alloc(NN*4);
    int* hist = (int*)alloc(NN*4);
    int* csr0 = (int*)alloc((size_t)EE*4);
    int* csr1 = (int*)alloc((size_t)EE*4);
    (void)alloc(4096);   // tail pad for harmless last-row K-chunk overrun reads
    int* offs[2] = {off0, off1};
    int* csrs[2] = {csr0, csr1};

    // ---- prep ----
    k_splitW<<<120, 256, 0, stream>>>(W1_0, 0, W1b);
    k_splitW<<<120, 256, 0, stream>>>(W1_1, 0, W1b + WMAT);
    k_splitW<<<120, 256, 0, stream>>>(Whh, 0,   Wh);
    k_splitW<<<120, 256, 0, stream>>>(Whh, 150, Wh + WMAT);
    k_splitW<<<120, 256, 0, stream>>>(Whh, 300, Wh + 2*WMAT);
    k_comp<<<(6*192*160 + 255)/256, 256, 0, stream>>>(Wih, W2_0, W2_1, b2_0, b2_1, Cb);
    k_tabs<<<4, 256, 0, stream>>>(bih, bhh, b1_0, b1_1, tb, b1t0, b1t1);
    k_padfc1<<<50, 256, 0, stream>>>(fc1W, fc1p);
    k_inith<<<(NN*152 + 255)/256, 256, 0, stream>>>(nodes, XA);

    // ---- CSR ----
    for (int s=0; s<2; s++){
        hipMemsetAsync(hist, 0, NN*sizeof(int), stream);
        k_hist<<<(EE+255)/256, 256, 0, stream>>>(edges[s], hist);
        k_scan<<<1, 1024, 0, stream>>>(hist, offs[s], cur);
        k_fill<<<(EE+255)/256, 256, 0, stream>>>(edges[s], cur, csrs[s]);
    }

    // ---- message passes ----
    u16* Hc = XA; u16* Hx = XB;
    dim3 gT(MROW/64, 3);
    dim3 gGa((NN+3)/4, 2);
    for (int ps=0; ps<4; ps++){
        u16* yu0 = Hx;                          // u scratch aliases h_next; dead before mega writes Hx
        u16* yu1 = Hx + (size_t)MROW*UPIT;
        k_ugemm2<<<gT, 256, 0, stream>>>(Hc, W1b, b1t0, b1t1, yu0, yu1);
        k_gath2<<<gGa, 256, 0, stream>>>(yu0, yu1, off0, csr0, off1, csr1, U0, U1);
        k_mega<<<gT, 256, 0, stream>>>(Hc, U0, U1, Cb, Wh, tb, Hx);
        u16* t = Hc; Hc = Hx; Hx = t;
    }

    // ---- readout ----
    hipMemsetAsync(gbuf, 0, GG*150*sizeof(float), stream);
    k_seg<<<(NN+511)/512, 192, 0, stream>>>(Hc, gid, gbuf);
    k_mlp<<<1, 256, 0, stream>>>(gbuf, pt, fc1p, fc1b, fc2W, fc2b, fcLW, fcLb, out);
}

// Round 8
// 2135.299 us; speedup vs baseline: 1.1993x; 1.1993x over previous
//
#include <hip/hip_runtime.h>

typedef unsigned short u16;
typedef unsigned int u32;
typedef __attribute__((ext_vector_type(8))) short s8v;      // 8 bf16
typedef __attribute__((ext_vector_type(8))) _Float16 h8v;   // 8 fp16
typedef __attribute__((ext_vector_type(4))) float f4v;      // C/D frag

#define NN 100000
#define MROW 100096
#define EE 500000
#define GG 16
#define HPIT 304      // h row pitch (u16): [hi 152 | lo 152]
#define UPIT 152      // u/U row pitch (u16): fp16, cols 150/151 carry degrees
#define WPIT 320      // split weight row pitch (u16): [hi 160 | lo 160]
#define WMAT (192*WPIT)
#define CPIT 160      // composite (fp16 single) row pitch
#define CMAT (192*CPIT)

__device__ __forceinline__ u16 f2bf(float x){ u32 u=__float_as_uint(x); return (u16)((u + 0x7fffu + ((u>>16)&1u))>>16); }
__device__ __forceinline__ float bf2f(u16 h){ return __uint_as_float(((u32)h)<<16); }
__device__ __forceinline__ u16 f2h(float x){ union{u16 u;_Float16 f;}c; c.f=(_Float16)x; return c.u; }
__device__ __forceinline__ float h2f(u16 b){ union{u16 u;_Float16 f;}c; c.u=b; return (float)c.f; }

#define GLOAD_LDS(gp, lp) \
    __builtin_amdgcn_global_load_lds((const __attribute__((address_space(1))) void*)(gp), \
                                     (__attribute__((address_space(3))) void*)(lp), 16, 0, 0)

// ---------------- staging (coalesced, swizzled) ----------------
template<int NI>
__device__ __forceinline__ void stage(const u16* base, const int (&off)[NI], int koff,
                                      const int (&lds)[NI], u16* dst){
#pragma unroll
    for (int i=0;i<NI;i++) GLOAD_LDS(base+off[i]+koff, dst+lds[i]);
}

// ---------------- MFMA helpers: A frags in regs, W frags read from LDS ----------------
template<bool ISBF>
__device__ __forceinline__ void mf3L(const s8v (&af)[4], const u16* lWp, int wfo, int mstr,
                                     f4v (&X)[4], f4v (&Y)[4], f4v (&Z)[4]){
    s8v w0 = *(const s8v*)(lWp+wfo);
    s8v w1 = *(const s8v*)(lWp+mstr+wfo);
    s8v w2 = *(const s8v*)(lWp+2*mstr+wfo);
#pragma unroll
    for (int mi=0;mi<4;mi++){
        if constexpr (ISBF){
            X[mi]=__builtin_amdgcn_mfma_f32_16x16x32_bf16(af[mi],w0,X[mi],0,0,0);
            Y[mi]=__builtin_amdgcn_mfma_f32_16x16x32_bf16(af[mi],w1,Y[mi],0,0,0);
            Z[mi]=__builtin_amdgcn_mfma_f32_16x16x32_bf16(af[mi],w2,Z[mi],0,0,0);
        } else {
            X[mi]=__builtin_amdgcn_mfma_f32_16x16x32_f16(*(const h8v*)&af[mi],*(const h8v*)&w0,X[mi],0,0,0);
            Y[mi]=__builtin_amdgcn_mfma_f32_16x16x32_f16(*(const h8v*)&af[mi],*(const h8v*)&w1,Y[mi],0,0,0);
            Z[mi]=__builtin_amdgcn_mfma_f32_16x16x32_f16(*(const h8v*)&af[mi],*(const h8v*)&w2,Z[mi],0,0,0);
        }
    }
}

__device__ __forceinline__ void mf2L(const s8v (&af)[4], const u16* lWp, int wfo, int mstr,
                                     f4v (&X)[4], f4v (&Y)[4]){
    s8v w0 = *(const s8v*)(lWp+wfo);
    s8v w1 = *(const s8v*)(lWp+mstr+wfo);
#pragma unroll
    for (int mi=0;mi<4;mi++){
        X[mi]=__builtin_amdgcn_mfma_f32_16x16x32_bf16(af[mi],w0,X[mi],0,0,0);
        Y[mi]=__builtin_amdgcn_mfma_f32_16x16x32_bf16(af[mi],w1,Y[mi],0,0,0);
    }
}

__device__ __forceinline__ void lda64(const u16* lA_, const int (&aF)[2][4], s8v (&a)[2][4]){
#pragma unroll
    for (int ks=0;ks<2;ks++)
#pragma unroll
        for (int mi=0;mi<4;mi++) a[ks][mi] = *(const s8v*)(lA_+aF[ks][mi]);
}
__device__ __forceinline__ void lda32(const u16* lA_, const int (&aF)[4], s8v (&a)[4]){
#pragma unroll
    for (int mi=0;mi<4;mi++) a[mi] = *(const s8v*)(lA_+aF[mi]);
}

// ---------------- edge-MLP layer 1 (both sets): u_s = lrelu(h @ W1_s^T + b1_s) ----------------
__global__ __launch_bounds__(256,3) void k_ugemm2(const u16* __restrict__ H,
    const u16* __restrict__ W1b,   // 2 split mats contiguous: [set0|set1]
    const float* __restrict__ b1t0, const float* __restrict__ b1t1,
    u16* __restrict__ u0, u16* __restrict__ u1)
{
    __shared__ u16 lA0[64*64], lA1[64*64], lW[2*64*64];
    int tid=threadIdx.x, wv=tid>>6, lane=tid&63, lr=lane&15, quad=lane>>4;
    int m0=blockIdx.x*64, n0=blockIdx.y*64;
    int aL64[2], hO64[2];
#pragma unroll
    for (int i=0;i<2;i++){ int s=tid+i*256, row=s>>3, q8=((s&7)^(row&7))<<3;
        aL64[i]=s<<3; hO64[i]=(m0+row)*HPIT+q8; }
    int aL32[1], hO32[1];
    { int s=tid, row=s>>2, q8=((s&3)^(row&3))<<3; aL32[0]=s<<3; hO32[0]=(m0+row)*HPIT+q8; }
    int wL64[4], wO64[4];
#pragma unroll
    for (int i=0;i<4;i++){ int s=tid+i*256, sel=s>>9, rem=s&511, row=rem>>3, q8=((rem&7)^(row&7))<<3;
        wL64[i]=sel*4096+rem*8; wO64[i]=sel*WMAT+(n0+row)*WPIT+q8; }
    int wL32[2], wO32[2];
#pragma unroll
    for (int i=0;i<2;i++){ int s=tid+i*256, sel=s>>8, rem=s&255, row=rem>>2, q8=((rem&3)^(row&3))<<3;
        wL32[i]=sel*2048+rem*8; wO32[i]=sel*WMAT+(n0+row)*WPIT+q8; }
    int aF64[2][4], wF64[2], aF32[4], wF32;
#pragma unroll
    for (int ks=0;ks<2;ks++){
#pragma unroll
        for (int mi=0;mi<4;mi++){ int row=mi*16+lr, ph=(ks*4+quad)^(row&7); aF64[ks][mi]=row*64+ph*8; }
        int wr=wv*16+lr, wp=(ks*4+quad)^(wr&7); wF64[ks]=wr*64+wp*8;
    }
#pragma unroll
    for (int mi=0;mi<4;mi++){ int row=mi*16+lr, ph=quad^(row&3); aF32[mi]=row*32+ph*8; }
    { int wr=wv*16+lr, wp=quad^(wr&3); wF32=wr*32+wp*8; }

    const u16* Hlo = H + 152;
    f4v a0[4]={}, a1[4]={};
    s8v a[2][4]; s8v a32[4];
#pragma unroll
    for (int kc=0;kc<2;kc++){
        int koff=kc*64;
        __syncthreads();
        stage<2>(H,  hO64,koff,aL64,lA0);
        stage<2>(Hlo,hO64,koff,aL64,lA1);
        stage<4>(W1b,wO64,koff,wL64,lW);        // W-hi plane, both sets
        __syncthreads();
        lda64(lA0,aF64,a);                       // A-hi x W-hi
#pragma unroll
        for (int ks=0;ks<2;ks++) mf2L(a[ks],lW,wF64[ks],4096,a0,a1);
        lda64(lA1,aF64,a);                       // A-lo x W-hi
#pragma unroll
        for (int ks=0;ks<2;ks++) mf2L(a[ks],lW,wF64[ks],4096,a0,a1);
        __syncthreads();
        stage<4>(W1b,wO64,160+koff,wL64,lW);    // W-lo plane
        __syncthreads();
        lda64(lA0,aF64,a);                       // A-hi x W-lo
#pragma unroll
        for (int ks=0;ks<2;ks++) mf2L(a[ks],lW,wF64[ks],4096,a0,a1);
    }
    __syncthreads();
    stage<1>(H,  hO32,128,aL32,lA0);
    stage<1>(Hlo,hO32,128,aL32,lA1);
    stage<2>(W1b,wO32,128,wL32,lW);
    __syncthreads();
    lda32(lA0,aF32,a32); mf2L(a32,lW,wF32,2048,a0,a1);
    lda32(lA1,aF32,a32); mf2L(a32,lW,wF32,2048,a0,a1);
    __syncthreads();
    stage<2>(W1b,wO32,288,wL32,lW);
    __syncthreads();
    lda32(lA0,aF32,a32); mf2L(a32,lW,wF32,2048,a0,a1);

    int c = n0 + wv*16 + lr;
    if (c < 152){
        float bb0=b1t0[c], bb1=b1t1[c];
#pragma unroll
        for (int mi=0;mi<4;mi++)
#pragma unroll
            for (int reg=0;reg<4;reg++){
                int r = m0 + mi*16 + quad*4 + reg;
                if (r >= NN) continue;
                float v0=a0[mi][reg]+bb0; v0 = v0>0.f ? v0 : 0.01f*v0;
                float v1=a1[mi][reg]+bb1; v1 = v1>0.f ? v1 : 0.01f*v1;
                if (c>=150){ v0=0.f; v1=0.f; }
                u0[(size_t)r*UPIT+c]=f2h(v0);
                u1[(size_t)r*UPIT+c]=f2h(v1);
            }
    }
}

// ---------------- fused GRU mega-kernel ----------------
__global__ __launch_bounds__(256,3) void k_mega(const u16* __restrict__ H,
    const u16* __restrict__ U0, const u16* __restrict__ U1,
    const u16* __restrict__ Cb,   // 6 mats fp16 single-plane (pitch 160): [s][gate r,z,n]
    const u16* __restrict__ Wh,   // 3 mats split-bf16 (pitch 320): Whh r,z,n
    const float* __restrict__ tb, u16* __restrict__ Hn)
{
    __shared__ u16 lA0[64*64], lA1[64*64], lW[3*64*64];
    int tid=threadIdx.x, wv=tid>>6, lane=tid&63, lr=lane&15, quad=lane>>4;
    int m0=blockIdx.x*64, n0=blockIdx.y*64;
    int aL64[2], uO64[2], hO64[2];
#pragma unroll
    for (int i=0;i<2;i++){ int s=tid+i*256, row=s>>3, q8=((s&7)^(row&7))<<3;
        aL64[i]=s<<3; uO64[i]=(m0+row)*UPIT+q8; hO64[i]=(m0+row)*HPIT+q8; }
    int aL32[1], uO32[1], hO32[1];
    { int s=tid, row=s>>2, q8=((s&3)^(row&3))<<3; aL32[0]=s<<3; uO32[0]=(m0+row)*UPIT+q8; hO32[0]=(m0+row)*HPIT+q8; }
    int wL64[6], wL32[3];
#pragma unroll
    for (int i=0;i<6;i++){ int s=tid+i*256, sel=s>>9, rem=s&511; wL64[i]=sel*4096+rem*8; }
#pragma unroll
    for (int i=0;i<3;i++){ int s=tid+i*256, sel=s>>8, rem=s&255; wL32[i]=sel*2048+rem*8; }
    int aF64[2][4], wF64[2], aF32[4], wF32;
#pragma unroll
    for (int ks=0;ks<2;ks++){
#pragma unroll
        for (int mi=0;mi<4;mi++){ int row=mi*16+lr, ph=(ks*4+quad)^(row&7); aF64[ks][mi]=row*64+ph*8; }
        int wr=wv*16+lr, wp=(ks*4+quad)^(wr&7); wF64[ks]=wr*64+wp*8;
    }
#pragma unroll
    for (int mi=0;mi<4;mi++){ int row=mi*16+lr, ph=quad^(row&3); aF32[mi]=row*32+ph*8; }
    { int wr=wv*16+lr, wp=quad^(wr&3); wF32=wr*32+wp*8; }

    f4v aR[4]={}, aZ[4]={}, aI[4]={}, aHh[4]={};
    s8v a[2][4]; s8v a32[4];

    // ---- u-side (fp16 single-plane composite weights; deg folded at k=150/151) ----
    {
        int wUO64[6], wUO32[3];
#pragma unroll
        for (int i=0;i<6;i++){ int s=tid+i*256, sel=s>>9, rem=s&511, row=rem>>3, q8=((rem&7)^(row&7))<<3;
            wUO64[i]=sel*CMAT+(n0+row)*CPIT+q8; }
#pragma unroll
        for (int i=0;i<3;i++){ int s=tid+i*256, sel=s>>8, rem=s&255, row=rem>>2, q8=((rem&3)^(row&3))<<3;
            wUO32[i]=sel*CMAT+(n0+row)*CPIT+q8; }
#pragma unroll
        for (int s=0;s<2;s++){
            const u16* U  = s ? U1 : U0;
            const u16* Cg = Cb + (size_t)s*(3*CMAT);
#pragma unroll
            for (int kc=0;kc<2;kc++){
                int koff=kc*64;
                __syncthreads();
                stage<2>(U,uO64,koff,aL64,lA0);
                stage<6>(Cg,wUO64,koff,wL64,lW);
                __syncthreads();
                lda64(lA0,aF64,a);
#pragma unroll
                for (int ks=0;ks<2;ks++) mf3L<false>(a[ks],lW,wF64[ks],4096,aR,aZ,aI);
            }
            __syncthreads();
            stage<1>(U,uO32,128,aL32,lA0);
            stage<3>(Cg,wUO32,128,wL32,lW);
            __syncthreads();
            lda32(lA0,aF32,a32);
            mf3L<false>(a32,lW,wF32,2048,aR,aZ,aI);
        }
    }
    // ---- h-side (split-bf16): r,z,hn ----
    {
        int wHO64[6], wHO32[3];
#pragma unroll
        for (int i=0;i<6;i++){ int s=tid+i*256, sel=s>>9, rem=s&511, row=rem>>3, q8=((rem&7)^(row&7))<<3;
            wHO64[i]=sel*WMAT+(n0+row)*WPIT+q8; }
#pragma unroll
        for (int i=0;i<3;i++){ int s=tid+i*256, sel=s>>8, rem=s&255, row=rem>>2, q8=((rem&3)^(row&3))<<3;
            wHO32[i]=sel*WMAT+(n0+row)*WPIT+q8; }
        const u16* Hlo = H + 152;
#pragma unroll
        for (int kc=0;kc<2;kc++){
            int koff=kc*64;
            __syncthreads();
            stage<2>(H,  hO64,koff,aL64,lA0);
            stage<2>(Hlo,hO64,koff,aL64,lA1);
            stage<6>(Wh,wHO64,koff,wL64,lW);          // W-hi
            __syncthreads();
            lda64(lA0,aF64,a);                         // A-hi x W-hi
#pragma unroll
            for (int ks=0;ks<2;ks++) mf3L<true>(a[ks],lW,wF64[ks],4096,aR,aZ,aHh);
            lda64(lA1,aF64,a);                         // A-lo x W-hi
#pragma unroll
            for (int ks=0;ks<2;ks++) mf3L<true>(a[ks],lW,wF64[ks],4096,aR,aZ,aHh);
            __syncthreads();
            stage<6>(Wh,wHO64,160+koff,wL64,lW);      // W-lo
            __syncthreads();
            lda64(lA0,aF64,a);                         // A-hi x W-lo
#pragma unroll
            for (int ks=0;ks<2;ks++) mf3L<true>(a[ks],lW,wF64[ks],4096,aR,aZ,aHh);
        }
        __syncthreads();
        stage<1>(H,  hO32,128,aL32,lA0);
        stage<1>(Hlo,hO32,128,aL32,lA1);
        stage<3>(Wh,wHO32,128,wL32,lW);
        __syncthreads();
        lda32(lA0,aF32,a32); mf3L<true>(a32,lW,wF32,2048,aR,aZ,aHh);
        lda32(lA1,aF32,a32); mf3L<true>(a32,lW,wF32,2048,aR,aZ,aHh);
        __syncthreads();
        stage<3>(Wh,wHO32,288,wL32,lW);
        __syncthreads();
        lda32(lA0,aF32,a32); mf3L<true>(a32,lW,wF32,2048,aR,aZ,aHh);
    }

    // ---- GRU epilogue ----
    int c = n0 + wv*16 + lr;
    if (c < 152){
        float bR=tb[c], bZ=tb[160+c], bI=tb[320+c], bHn=tb[480+c];
#pragma unroll
        for (int mi=0;mi<4;mi++)
#pragma unroll
            for (int reg=0;reg<4;reg++){
                int r = m0 + mi*16 + quad*4 + reg;
                if (r >= NN) continue;
                float pr=aR[mi][reg]+bR, pz=aZ[mi][reg]+bZ, pi=aI[mi][reg]+bI, ph_=aHh[mi][reg]+bHn;
                float rg = 1.f/(1.f+__expf(-pr));
                float zg = 1.f/(1.f+__expf(-pz));
                float e2 = __expf(2.f*(pi + rg*ph_));
                float n  = 1.f - 2.f/(e2+1.f);
                float hold = bf2f(H[(size_t)r*HPIT+c]) + bf2f(H[(size_t)r*HPIT+152+c]);
                float o = (1.f-zg)*n + zg*hold;
                if (c>=150) o = 0.f;
                u16 hi = f2bf(o);
                Hn[(size_t)r*HPIT+c] = hi;
                Hn[(size_t)r*HPIT+152+c] = f2bf(o - bf2f(hi));
            }
    }
}

// ---------------- prep kernels ----------------
__global__ void k_splitW(const float* __restrict__ src, int rowoff, u16* __restrict__ dst){
    int idx = blockIdx.x*256 + threadIdx.x;     // 192*160
    if (idx >= 192*160) return;
    int r = idx/160, c = idx - r*160;
    float x = (r<150 && c<150) ? src[(size_t)(rowoff+r)*150 + c] : 0.f;
    u16 hi = f2bf(x);
    dst[(size_t)r*WPIT + c] = hi;
    dst[(size_t)r*WPIT + 160 + c] = f2bf(x - bf2f(hi));
}

// composite C[s*3+g] = Wih_g @ W2_s (cols 0..149); col150(s=0)/col151(s=1) = Wih_g @ b2_s ; fp16 single
__global__ void k_comp(const float* __restrict__ Wih, const float* __restrict__ W2_0,
                       const float* __restrict__ W2_1, const float* __restrict__ b2_0,
                       const float* __restrict__ b2_1, u16* __restrict__ Cb){
    int idx = blockIdx.x*256 + threadIdx.x;     // 6*192*160
    if (idx >= 6*192*160) return;
    int mat = idx/(192*160), rem = idx - mat*(192*160);
    int o = rem/160, c = rem - o*160;
    int s = mat/3, g = mat - s*3;
    float v = 0.f;
    if (o < 150){
        const float* wrow = Wih + (size_t)(g*150+o)*150;
        if (c < 150){
            const float* W2 = s ? W2_1 : W2_0;
            for (int j=0;j<150;j++) v += wrow[j] * W2[(size_t)j*150 + c];
        } else if (c==150 && s==0){
            for (int j=0;j<150;j++) v += wrow[j] * b2_0[j];
        } else if (c==151 && s==1){
            for (int j=0;j<150;j++) v += wrow[j] * b2_1[j];
        }
    }
    Cb[(size_t)mat*CMAT + o*CPIT + c] = f2h(v);
}

__global__ void k_tabs(const float* bih,const float* bhh,
                       const float* b1_0,const float* b1_1,
                       float* tb, float* b1t0, float* b1t1){
    int idx = blockIdx.x*256 + threadIdx.x;     // 6*160
    if (idx >= 6*160) return;
    int t = idx/160, c = idx - t*160;
    float v = 0.f;
    if (c < 150){
        if (t==0) v = bih[c]+bhh[c];
        else if (t==1) v = bih[150+c]+bhh[150+c];
        else if (t==2) v = bih[300+c];
        else if (t==3) v = bhh[300+c];
        else if (t==4) v = b1_0[c];
        else v = b1_1[c];
    }
    if (t<4) tb[t*160+c]=v;
    else if (t==4) b1t0[c]=v;
    else b1t1[c]=v;
}

__global__ void k_padfc1(const float* __restrict__ s, float* __restrict__ d){
    int idx = blockIdx.x*256 + threadIdx.x;     // 80*160
    if (idx >= 80*160) return;
    int r = idx/160, c = idx - r*160;
    d[idx] = (c<151) ? s[r*151 + c] : 0.f;
}

__global__ void k_inith(const float* __restrict__ nodes, u16* __restrict__ H){
    int idx = blockIdx.x*256 + threadIdx.x;     // NN*152
    if (idx >= NN*152) return;
    int m = idx/152, c = idx - m*152;
    float x = (c<150) ? nodes[(size_t)m*150 + c] : 0.f;
    u16 hi = f2bf(x);
    H[(size_t)m*HPIT + c] = hi;
    H[(size_t)m*HPIT + 152 + c] = f2bf(x - bf2f(hi));
}

// ---------------- CSR build ----------------
__global__ void k_hist(const int* __restrict__ edges, int* __restrict__ cnt){
    int e = blockIdx.x*256 + threadIdx.x;
    if (e >= EE) return;
    atomicAdd(&cnt[edges[2*e]], 1);
}

__global__ __launch_bounds__(1024) void k_scan(const int* __restrict__ cnt,
                                               int* __restrict__ off, int* __restrict__ cur){
    __shared__ int sd[1024];
    __shared__ int s_run;
    int t = threadIdx.x;
    if (t==0) s_run = 0;
    __syncthreads();
    for (int base=0; base<NN; base+=8192){
        int i0 = base + t*8;
        int v[8]; int s = 0;
#pragma unroll
        for (int u=0; u<8; u++){ int i=i0+u; v[u]=(i<NN)?cnt[i]:0; s+=v[u]; }
        sd[t]=s;
        __syncthreads();
        int runbase = s_run;
        for (int ofs=1; ofs<1024; ofs<<=1){
            int y=0;
            if (t>=ofs) y=sd[t-ofs];
            __syncthreads();
            if (t>=ofs) sd[t]+=y;
            __syncthreads();
        }
        int excl = runbase + sd[t] - s;
#pragma unroll
        for (int u=0; u<8; u++){
            int i=i0+u;
            if (i<NN){ off[i]=excl; cur[i]=excl; excl+=v[u]; }
        }
        __syncthreads();
        if (t==1023) s_run = runbase + sd[1023];
        __syncthreads();
    }
    if (t==0) off[NN] = s_run;
}

__global__ void k_fill(const int* __restrict__ edges, int* __restrict__ cur, int* __restrict__ csr){
    int e = blockIdx.x*256 + threadIdx.x;
    if (e >= EE) return;
    int dst = edges[2*e], src = edges[2*e+1];
    int pos = atomicAdd(&cur[dst], 1);
    csr[pos] = src;
}

// ---------------- gather (u32 packed fp16); degree -> cols 150/151 ----------------
__global__ void k_gath2(const u16* __restrict__ u0, const u16* __restrict__ u1,
                        const int* __restrict__ off0, const int* __restrict__ csr0,
                        const int* __restrict__ off1, const int* __restrict__ csr1,
                        u16* __restrict__ U0, u16* __restrict__ U1){
    int d = blockIdx.x*4 + (threadIdx.x>>6);
    if (d >= NN) return;
    int lane = threadIdx.x & 63;
    const u16* u = blockIdx.y ? u1 : u0;
    const int* off = blockIdx.y ? off1 : off0;
    const int* csr = blockIdx.y ? csr1 : csr0;
    u16* U = blockIdx.y ? U1 : U0;
    int e0 = off[d], e1 = off[d+1];
    bool tl = lane < 12;
    float s0=0.f, s1=0.f, t0=0.f, t1=0.f;
    for (int e=e0; e<e1; e++){
        const u32* r = (const u32*)(u + (size_t)csr[e]*UPIT);
        u32 v = r[lane];
        s0 += h2f((u16)(v & 0xffffu));
        s1 += h2f((u16)(v >> 16));
        if (tl){
            u32 w = r[64+lane];
            t0 += h2f((u16)(w & 0xffffu));
            t1 += h2f((u16)(w >> 16));
        }
    }
    if (lane == 11){ t0 = (float)(e1-e0); t1 = t0; }   // cols 150,151 = degree
    u32* Ur = (u32*)(U + (size_t)d*UPIT);
    Ur[lane] = (u32)f2h(s0) | ((u32)f2h(s1) << 16);
    if (tl) Ur[64+lane] = (u32)f2h(t0) | ((u32)f2h(t1) << 16);
}

// ---------------- segment sum + readout ----------------
__global__ void k_seg(const u16* __restrict__ H, const int* __restrict__ gid, float* __restrict__ g){
    int f = threadIdx.x;
    if (f >= 150) return;
    int i0 = blockIdx.x*512;
    int i1 = i0 + 512; if (i1 > NN) i1 = NN;
    float acc = 0.f;
    int cg = gid[i0];
    for (int i=i0; i<i1; i++){
        int gg = gid[i];
        if (gg != cg){ atomicAdd(&g[cg*150+f], acc); acc=0.f; cg=gg; }
        acc += bf2f(H[(size_t)i*HPIT + f]) + bf2f(H[(size_t)i*HPIT + 152 + f]);
    }
    atomicAdd(&g[cg*150+f], acc);
}

__global__ void k_mlp(const float* __restrict__ g, const float* __restrict__ pt,
                      const float* __restrict__ fc1p, const float* __restrict__ fc1b,
                      const float* __restrict__ fc2W, const float* __restrict__ fc2b,
                      const float* __restrict__ fcLW, const float* __restrict__ fcLb,
                      float* __restrict__ out){
    __shared__ float X[GG][152];
    __shared__ float Y[GG][80];
    __shared__ float Z[GG][80];
    int t = threadIdx.x;
    for (int idx=t; idx<GG*152; idx+=256){
        int gi=idx/152, c=idx-gi*152;
        float v = 0.f;
        if (c < 150){
            float lg = logf(g[gi*150+c]);
            if (lg != lg) lg = 0.f;
            v = fmaxf(lg, 0.f);
        } else if (c == 150) v = pt[gi];
        X[gi][c] = v;
    }
    __syncthreads();
    for (int idx=t; idx<GG*80; idx+=256){
        int gi=idx/80, o=idx-gi*80;
        float acc = fc1b[o];
        for (int k=0;k<151;k++) acc = fmaf(X[gi][k], fc1p[o*160+k], acc);
        Y[gi][o] = acc>0.f ? acc : 0.01f*acc;
    }
    __syncthreads();
    for (int idx=t; idx<GG*80; idx+=256){
        int gi=idx/80, o=idx-gi*80;
        float acc = fc2b[o];
        for (int k=0;k<80;k++) acc = fmaf(Y[gi][k], fc2W[o*80+k], acc);
        Z[gi][o] = acc>0.f ? acc : 0.01f*acc;
    }
    __syncthreads();
    for (int idx=t; idx<GG*10; idx+=256){
        int gi=idx/10, o=idx-gi*10;
        float acc = fcLb[o];
        for (int k=0;k<80;k++) acc = fmaf(Z[gi][k], fcLW[o*80+k], acc);
        out[idx] = acc;
    }
}

// ---------------- host ----------------
extern "C" void kernel_launch(void* const* d_in, const int* in_sizes, int n_in,
                              void* d_out, int out_size, void* d_ws, size_t ws_size,
                              hipStream_t stream) {
    const float* nodes = (const float*)d_in[0];
    const float* pt    = (const float*)d_in[1];
    const float* W1_0 = (const float*)d_in[2];  const float* b1_0 = (const float*)d_in[3];
    const float* W2_0 = (const float*)d_in[4];  const float* b2_0 = (const float*)d_in[5];
    const float* W1_1 = (const float*)d_in[6];  const float* b1_1 = (const float*)d_in[7];
    const float* W2_1 = (const float*)d_in[8];  const float* b2_1 = (const float*)d_in[9];
    const float* Wih = (const float*)d_in[10];  const float* bih = (const float*)d_in[11];
    const float* Whh = (const float*)d_in[12];  const float* bhh = (const float*)d_in[13];
    const float* fc1W = (const float*)d_in[14]; const float* fc1b = (const float*)d_in[15];
    const float* fc2W = (const float*)d_in[16]; const float* fc2b = (const float*)d_in[17];
    const float* fcLW = (const float*)d_in[18]; const float* fcLb = (const float*)d_in[19];
    const int* edges[2] = {(const int*)d_in[20], (const int*)d_in[21]};
    const int* gid = (const int*)d_in[22];
    float* out = (float*)d_out;

    char* p = (char*)d_ws;
    auto alloc = [&](size_t bytes){ char* r = p; p += (bytes + 255) & ~(size_t)255; return r; };
    u16* XA = (u16*)alloc((size_t)MROW*HPIT*2);
    u16* XB = (u16*)alloc((size_t)MROW*HPIT*2);
    u16* U0 = (u16*)alloc((size_t)MROW*UPIT*2);
    u16* U1 = (u16*)alloc((size_t)MROW*UPIT*2);
    u16* W1b = (u16*)alloc((size_t)2*WMAT*2);    // [set0|set1] split-bf16
    u16* Wh  = (u16*)alloc((size_t)3*WMAT*2);    // Whh gates r,z,n split-bf16
    u16* Cb  = (u16*)alloc((size_t)6*CMAT*2);    // composite, fp16 single-plane
    float* tb   = (float*)alloc(4*160*4);
    float* b1t0 = (float*)alloc(160*4);
    float* b1t1 = (float*)alloc(160*4);
    float* fc1p = (float*)alloc(80*160*4);
    float* gbuf = (float*)alloc(GG*150*4);
    int* off0 = (int*)alloc((NN+1)*4);
    int* off1 = (int*)alloc((NN+1)*4);
    int* cur  = (int*)alloc(NN*4);
    int* hist = (int*)alloc(NN*4);
    int* csr0 = (int*)alloc((size_t)EE*4);
    int* csr1 = (int*)alloc((size_t)EE*4);
    (void)alloc(4096);   // tail pad for harmless last-row K-chunk overrun reads
    int* offs[2] = {off0, off1};
    int* csrs[2] = {csr0, csr1};

    // ---- prep ----
    k_splitW<<<120, 256, 0, stream>>>(W1_0, 0, W1b);
    k_splitW<<<120, 256, 0, stream>>>(W1_1, 0, W1b + WMAT);
    k_splitW<<<120, 256, 0, stream>>>(Whh, 0,   Wh);
    k_splitW<<<120, 256, 0, stream>>>(Whh, 150, Wh + WMAT);
    k_splitW<<<120, 256, 0, stream>>>(Whh, 300, Wh + 2*WMAT);
    k_comp<<<(6*192*160 + 255)/256, 256, 0, stream>>>(Wih, W2_0, W2_1, b2_0, b2_1, Cb);
    k_tabs<<<4, 256, 0, stream>>>(bih, bhh, b1_0, b1_1, tb, b1t0, b1t1);
    k_padfc1<<<50, 256, 0, stream>>>(fc1W, fc1p);
    k_inith<<<(NN*152 + 255)/256, 256, 0, stream>>>(nodes, XA);

    // ---- CSR ----
    for (int s=0; s<2; s++){
        hipMemsetAsync(hist, 0, NN*sizeof(int), stream);
        k_hist<<<(EE+255)/256, 256, 0, stream>>>(edges[s], hist);
        k_scan<<<1, 1024, 0, stream>>>(hist, offs[s], cur);
        k_fill<<<(EE+255)/256, 256, 0, stream>>>(edges[s], cur, csrs[s]);
    }

    // ---- message passes ----
    u16* Hc = XA; u16* Hx = XB;
    dim3 gT(MROW/64, 3);
    dim3 gGa((NN+3)/4, 2);
    for (int ps=0; ps<4; ps++){
        u16* yu0 = Hx;                          // u scratch aliases h_next; dead before mega writes Hx
        u16* yu1 = Hx + (size_t)MROW*UPIT;
        k_ugemm2<<<gT, 256, 0, stream>>>(Hc, W1b, b1t0, b1t1, yu0, yu1);
        k_gath2<<<gGa, 256, 0, stream>>>(yu0, yu1, off0, csr0, off1, csr1, U0, U1);
        k_mega<<<gT, 256, 0, stream>>>(Hc, U0, U1, Cb, Wh, tb, Hx);
        u16* t = Hc; Hc = Hx; Hx = t;
    }

    // ---- readout ----
    hipMemsetAsync(gbuf, 0, GG*150*sizeof(float), stream);
    k_seg<<<(NN+511)/512, 192, 0, stream>>>(Hc, gid, gbuf);
    k_mlp<<<1, 256, 0, stream>>>(gbuf, pt, fc1p, fc1b, fc2W, fc2b, fcLW, fcLb, out);
}

// Round 9
// 1820.475 us; speedup vs baseline: 1.4067x; 1.1729x over previous
//
#include <hip/hip_runtime.h>

typedef unsigned short u16;
typedef unsigned int u32;
typedef __attribute__((ext_vector_type(8))) short s8v;      // 8x16-bit
typedef __attribute__((ext_vector_type(8))) _Float16 h8v;   // 8 fp16
typedef __attribute__((ext_vector_type(4))) float f4v;      // C/D frag

#define NN 100000
#define MROW 100096
#define EE 500000
#define GG 16
#define APIT 152      // A-source row pitch (u16, fp16): H, u, U ; U cols 150/151 = degree
#define CPIT 160      // weight row pitch (u16, fp16 single-plane)
#define CMAT (192*CPIT)

__device__ __forceinline__ u16 f2h(float x){ union{u16 u;_Float16 f;}c; c.f=(_Float16)x; return c.u; }
__device__ __forceinline__ float h2f(u16 b){ union{u16 u;_Float16 f;}c; c.u=b; return (float)c.f; }

#define GLOAD_LDS(gp, lp) \
    __builtin_amdgcn_global_load_lds((const __attribute__((address_space(1))) void*)(gp), \
                                     (__attribute__((address_space(3))) void*)(lp), 16, 0, 0)

// ---------------- staging (coalesced, swizzled) ----------------
template<int NI>
__device__ __forceinline__ void stage(const u16* base, const int (&off)[NI], int koff,
                                      const int (&lds)[NI], u16* dst){
#pragma unroll
    for (int i=0;i<NI;i++) GLOAD_LDS(base+off[i]+koff, dst+lds[i]);
}

// ---------------- MFMA helpers (fp16): A frags in regs, W frags from LDS ----------------
__device__ __forceinline__ void mf3h(const s8v (&af)[4], const u16* lWp, int wfo, int mstr,
                                     f4v (&X)[4], f4v (&Y)[4], f4v (&Z)[4]){
    h8v w0 = *(const h8v*)(lWp+wfo);
    h8v w1 = *(const h8v*)(lWp+mstr+wfo);
    h8v w2 = *(const h8v*)(lWp+2*mstr+wfo);
#pragma unroll
    for (int mi=0;mi<4;mi++){
        X[mi]=__builtin_amdgcn_mfma_f32_16x16x32_f16(*(const h8v*)&af[mi],w0,X[mi],0,0,0);
        Y[mi]=__builtin_amdgcn_mfma_f32_16x16x32_f16(*(const h8v*)&af[mi],w1,Y[mi],0,0,0);
        Z[mi]=__builtin_amdgcn_mfma_f32_16x16x32_f16(*(const h8v*)&af[mi],w2,Z[mi],0,0,0);
    }
}
__device__ __forceinline__ void mf2h(const s8v (&af)[4], const u16* lWp, int wfo, int mstr,
                                     f4v (&X)[4], f4v (&Y)[4]){
    h8v w0 = *(const h8v*)(lWp+wfo);
    h8v w1 = *(const h8v*)(lWp+mstr+wfo);
#pragma unroll
    for (int mi=0;mi<4;mi++){
        X[mi]=__builtin_amdgcn_mfma_f32_16x16x32_f16(*(const h8v*)&af[mi],w0,X[mi],0,0,0);
        Y[mi]=__builtin_amdgcn_mfma_f32_16x16x32_f16(*(const h8v*)&af[mi],w1,Y[mi],0,0,0);
    }
}

__device__ __forceinline__ void lda64(const u16* lA_, const int (&aF)[2][4], s8v (&a)[2][4]){
#pragma unroll
    for (int ks=0;ks<2;ks++)
#pragma unroll
        for (int mi=0;mi<4;mi++) a[ks][mi] = *(const s8v*)(lA_+aF[ks][mi]);
}
__device__ __forceinline__ void lda32(const u16* lA_, const int (&aF)[4], s8v (&a)[4]){
#pragma unroll
    for (int mi=0;mi<4;mi++) a[mi] = *(const s8v*)(lA_+aF[mi]);
}

// ---------------- edge-MLP layer 1 (both sets): u_s = lrelu(h @ W1_s^T + b1_s) ----------------
__global__ __launch_bounds__(256,3) void k_ugemm2(const u16* __restrict__ H,
    const u16* __restrict__ W1h,   // 2 fp16 mats contiguous: [set0|set1]
    const float* __restrict__ b1t0, const float* __restrict__ b1t1,
    u16* __restrict__ u0, u16* __restrict__ u1)
{
    __shared__ u16 lA[64*64], lW[2*64*64];
    int tid=threadIdx.x, wv=tid>>6, lane=tid&63, lr=lane&15, quad=lane>>4;
    int m0=blockIdx.x*64, n0=blockIdx.y*64;
    int aL64[2], aO64[2];
#pragma unroll
    for (int i=0;i<2;i++){ int s=tid+i*256, row=s>>3, q8=((s&7)^(row&7))<<3;
        aL64[i]=s<<3; aO64[i]=(m0+row)*APIT+q8; }
    int aL32[1], aO32[1];
    { int s=tid, row=s>>2, q8=((s&3)^(row&3))<<3; aL32[0]=s<<3; aO32[0]=(m0+row)*APIT+q8; }
    int wL64[4], wO64[4];
#pragma unroll
    for (int i=0;i<4;i++){ int s=tid+i*256, sel=s>>9, rem=s&511, row=rem>>3, q8=((rem&7)^(row&7))<<3;
        wL64[i]=sel*4096+rem*8; wO64[i]=sel*CMAT+(n0+row)*CPIT+q8; }
    int wL32[2], wO32[2];
#pragma unroll
    for (int i=0;i<2;i++){ int s=tid+i*256, sel=s>>8, rem=s&255, row=rem>>2, q8=((rem&3)^(row&3))<<3;
        wL32[i]=sel*2048+rem*8; wO32[i]=sel*CMAT+(n0+row)*CPIT+q8; }
    int aF64[2][4], wF64[2], aF32[4], wF32;
#pragma unroll
    for (int ks=0;ks<2;ks++){
#pragma unroll
        for (int mi=0;mi<4;mi++){ int row=mi*16+lr, ph=(ks*4+quad)^(row&7); aF64[ks][mi]=row*64+ph*8; }
        int wr=wv*16+lr, wp=(ks*4+quad)^(wr&7); wF64[ks]=wr*64+wp*8;
    }
#pragma unroll
    for (int mi=0;mi<4;mi++){ int row=mi*16+lr, ph=quad^(row&3); aF32[mi]=row*32+ph*8; }
    { int wr=wv*16+lr, wp=quad^(wr&3); wF32=wr*32+wp*8; }

    f4v a0[4]={}, a1[4]={};
    s8v a[2][4]; s8v a32[4];
#pragma unroll
    for (int kc=0;kc<2;kc++){
        int koff=kc*64;
        __syncthreads();
        stage<2>(H,aO64,koff,aL64,lA);
        stage<4>(W1h,wO64,koff,wL64,lW);
        __syncthreads();
        lda64(lA,aF64,a);
#pragma unroll
        for (int ks=0;ks<2;ks++) mf2h(a[ks],lW,wF64[ks],4096,a0,a1);
    }
    __syncthreads();
    stage<1>(H,aO32,128,aL32,lA);
    stage<2>(W1h,wO32,128,wL32,lW);
    __syncthreads();
    lda32(lA,aF32,a32);
    mf2h(a32,lW,wF32,2048,a0,a1);

    int c = n0 + wv*16 + lr;
    if (c < 152){
        float bb0=b1t0[c], bb1=b1t1[c];
#pragma unroll
        for (int mi=0;mi<4;mi++)
#pragma unroll
            for (int reg=0;reg<4;reg++){
                int r = m0 + mi*16 + quad*4 + reg;
                if (r >= NN) continue;
                float v0=a0[mi][reg]+bb0; v0 = v0>0.f ? v0 : 0.01f*v0;
                float v1=a1[mi][reg]+bb1; v1 = v1>0.f ? v1 : 0.01f*v1;
                if (c>=150){ v0=0.f; v1=0.f; }
                u0[(size_t)r*APIT+c]=f2h(v0);
                u1[(size_t)r*APIT+c]=f2h(v1);
            }
    }
}

// ---------------- fused GRU mega-kernel (all-fp16) ----------------
__global__ __launch_bounds__(256,3) void k_mega(const u16* __restrict__ H,
    const u16* __restrict__ U0, const u16* __restrict__ U1,
    const u16* __restrict__ Cb,   // 6 fp16 mats: [s][gate r,z,n] (deg cols 150/151 folded)
    const u16* __restrict__ Wh,   // 3 fp16 mats: Whh gates r,z,n
    const float* __restrict__ tb, u16* __restrict__ Hn)
{
    __shared__ u16 lA[64*64], lW[3*64*64];
    int tid=threadIdx.x, wv=tid>>6, lane=tid&63, lr=lane&15, quad=lane>>4;
    int m0=blockIdx.x*64, n0=blockIdx.y*64;
    int aL64[2], aO64[2];
#pragma unroll
    for (int i=0;i<2;i++){ int s=tid+i*256, row=s>>3, q8=((s&7)^(row&7))<<3;
        aL64[i]=s<<3; aO64[i]=(m0+row)*APIT+q8; }
    int aL32[1], aO32[1];
    { int s=tid, row=s>>2, q8=((s&3)^(row&3))<<3; aL32[0]=s<<3; aO32[0]=(m0+row)*APIT+q8; }
    int wL64[6], wO64[6];
#pragma unroll
    for (int i=0;i<6;i++){ int s=tid+i*256, sel=s>>9, rem=s&511, row=rem>>3, q8=((rem&7)^(row&7))<<3;
        wL64[i]=sel*4096+rem*8; wO64[i]=sel*CMAT+(n0+row)*CPIT+q8; }
    int wL32[3], wO32[3];
#pragma unroll
    for (int i=0;i<3;i++){ int s=tid+i*256, sel=s>>8, rem=s&255, row=rem>>2, q8=((rem&3)^(row&3))<<3;
        wL32[i]=sel*2048+rem*8; wO32[i]=sel*CMAT+(n0+row)*CPIT+q8; }
    int aF64[2][4], wF64[2], aF32[4], wF32;
#pragma unroll
    for (int ks=0;ks<2;ks++){
#pragma unroll
        for (int mi=0;mi<4;mi++){ int row=mi*16+lr, ph=(ks*4+quad)^(row&7); aF64[ks][mi]=row*64+ph*8; }
        int wr=wv*16+lr, wp=(ks*4+quad)^(wr&7); wF64[ks]=wr*64+wp*8;
    }
#pragma unroll
    for (int mi=0;mi<4;mi++){ int row=mi*16+lr, ph=quad^(row&3); aF32[mi]=row*32+ph*8; }
    { int wr=wv*16+lr, wp=quad^(wr&3); wF32=wr*32+wp*8; }

    f4v aR[4]={}, aZ[4]={}, aI[4]={}, aHh[4]={};

    auto dopass = [&](const u16* A, const u16* Wg, f4v (&aT)[4]){
        s8v a[2][4]; s8v a32[4];
#pragma unroll
        for (int kc=0;kc<2;kc++){
            int koff=kc*64;
            __syncthreads();
            stage<2>(A,aO64,koff,aL64,lA);
            stage<6>(Wg,wO64,koff,wL64,lW);
            __syncthreads();
            lda64(lA,aF64,a);
#pragma unroll
            for (int ks=0;ks<2;ks++) mf3h(a[ks],lW,wF64[ks],4096,aR,aZ,aT);
        }
        __syncthreads();
        stage<1>(A,aO32,128,aL32,lA);
        stage<3>(Wg,wO32,128,wL32,lW);
        __syncthreads();
        lda32(lA,aF32,a32);
        mf3h(a32,lW,wF32,2048,aR,aZ,aT);
    };
    dopass(U0, Cb,          aI);
    dopass(U1, Cb + 3*CMAT, aI);
    dopass(H,  Wh,          aHh);

    // ---- GRU epilogue ----
    int c = n0 + wv*16 + lr;
    if (c < 152){
        float bR=tb[c], bZ=tb[160+c], bI=tb[320+c], bHn=tb[480+c];
#pragma unroll
        for (int mi=0;mi<4;mi++)
#pragma unroll
            for (int reg=0;reg<4;reg++){
                int r = m0 + mi*16 + quad*4 + reg;
                if (r >= NN) continue;
                float pr=aR[mi][reg]+bR, pz=aZ[mi][reg]+bZ, pi=aI[mi][reg]+bI, ph_=aHh[mi][reg]+bHn;
                float rg = 1.f/(1.f+__expf(-pr));
                float zg = 1.f/(1.f+__expf(-pz));
                float e2 = __expf(2.f*(pi + rg*ph_));
                float n  = 1.f - 2.f/(e2+1.f);
                float hold = h2f(H[(size_t)r*APIT+c]);
                float o = (1.f-zg)*n + zg*hold;
                if (c>=150) o = 0.f;
                Hn[(size_t)r*APIT+c] = f2h(o);
            }
    }
}

// ---------------- prep kernels ----------------
__global__ void k_cast16(const float* __restrict__ src, int rowoff, u16* __restrict__ dst){
    int idx = blockIdx.x*256 + threadIdx.x;     // 192*160
    if (idx >= 192*160) return;
    int r = idx/160, c = idx - r*160;
    float x = (r<150 && c<150) ? src[(size_t)(rowoff+r)*150 + c] : 0.f;
    dst[(size_t)r*CPIT + c] = f2h(x);
}

// composite C[s*3+g] = Wih_g @ W2_s (cols 0..149); col150(s=0)/col151(s=1) = Wih_g @ b2_s ; fp16
__global__ void k_comp(const float* __restrict__ Wih, const float* __restrict__ W2_0,
                       const float* __restrict__ W2_1, const float* __restrict__ b2_0,
                       const float* __restrict__ b2_1, u16* __restrict__ Cb){
    int idx = blockIdx.x*256 + threadIdx.x;     // 6*192*160
    if (idx >= 6*192*160) return;
    int mat = idx/(192*160), rem = idx - mat*(192*160);
    int o = rem/160, c = rem - o*160;
    int s = mat/3, g = mat - s*3;
    float v = 0.f;
    if (o < 150){
        const float* wrow = Wih + (size_t)(g*150+o)*150;
        if (c < 150){
            const float* W2 = s ? W2_1 : W2_0;
            for (int j=0;j<150;j++) v += wrow[j] * W2[(size_t)j*150 + c];
        } else if (c==150 && s==0){
            for (int j=0;j<150;j++) v += wrow[j] * b2_0[j];
        } else if (c==151 && s==1){
            for (int j=0;j<150;j++) v += wrow[j] * b2_1[j];
        }
    }
    Cb[(size_t)mat*CMAT + o*CPIT + c] = f2h(v);
}

__global__ void k_tabs(const float* bih,const float* bhh,
                       const float* b1_0,const float* b1_1,
                       float* tb, float* b1t0, float* b1t1){
    int idx = blockIdx.x*256 + threadIdx.x;     // 6*160
    if (idx >= 6*160) return;
    int t = idx/160, c = idx - t*160;
    float v = 0.f;
    if (c < 150){
        if (t==0) v = bih[c]+bhh[c];
        else if (t==1) v = bih[150+c]+bhh[150+c];
        else if (t==2) v = bih[300+c];
        else if (t==3) v = bhh[300+c];
        else if (t==4) v = b1_0[c];
        else v = b1_1[c];
    }
    if (t<4) tb[t*160+c]=v;
    else if (t==4) b1t0[c]=v;
    else b1t1[c]=v;
}

__global__ void k_padfc1(const float* __restrict__ s, float* __restrict__ d){
    int idx = blockIdx.x*256 + threadIdx.x;     // 80*160
    if (idx >= 80*160) return;
    int r = idx/160, c = idx - r*160;
    d[idx] = (c<151) ? s[r*151 + c] : 0.f;
}

__global__ void k_inith(const float* __restrict__ nodes, u16* __restrict__ H){
    int idx = blockIdx.x*256 + threadIdx.x;     // NN*152
    if (idx >= NN*152) return;
    int m = idx/152, c = idx - m*152;
    float x = (c<150) ? nodes[(size_t)m*150 + c] : 0.f;
    H[(size_t)m*APIT + c] = f2h(x);
}

// ---------------- CSR build ----------------
__global__ void k_hist(const int* __restrict__ edges, int* __restrict__ cnt){
    int e = blockIdx.x*256 + threadIdx.x;
    if (e >= EE) return;
    atomicAdd(&cnt[edges[2*e]], 1);
}

__global__ __launch_bounds__(1024) void k_scan(const int* __restrict__ cnt,
                                               int* __restrict__ off, int* __restrict__ cur){
    __shared__ int sd[1024];
    __shared__ int s_run;
    int t = threadIdx.x;
    if (t==0) s_run = 0;
    __syncthreads();
    for (int base=0; base<NN; base+=8192){
        int i0 = base + t*8;
        int v[8]; int s = 0;
#pragma unroll
        for (int u=0; u<8; u++){ int i=i0+u; v[u]=(i<NN)?cnt[i]:0; s+=v[u]; }
        sd[t]=s;
        __syncthreads();
        int runbase = s_run;
        for (int ofs=1; ofs<1024; ofs<<=1){
            int y=0;
            if (t>=ofs) y=sd[t-ofs];
            __syncthreads();
            if (t>=ofs) sd[t]+=y;
            __syncthreads();
        }
        int excl = runbase + sd[t] - s;
#pragma unroll
        for (int u=0; u<8; u++){
            int i=i0+u;
            if (i<NN){ off[i]=excl; cur[i]=excl; excl+=v[u]; }
        }
        __syncthreads();
        if (t==1023) s_run = runbase + sd[1023];
        __syncthreads();
    }
    if (t==0) off[NN] = s_run;
}

__global__ void k_fill(const int* __restrict__ edges, int* __restrict__ cur, int* __restrict__ csr){
    int e = blockIdx.x*256 + threadIdx.x;
    if (e >= EE) return;
    int dst = edges[2*e], src = edges[2*e+1];
    int pos = atomicAdd(&cur[dst], 1);
    csr[pos] = src;
}

// ---------------- gather (u32 packed fp16); degree -> cols 150/151 ----------------
__global__ void k_gath2(const u16* __restrict__ u0, const u16* __restrict__ u1,
                        const int* __restrict__ off0, const int* __restrict__ csr0,
                        const int* __restrict__ off1, const int* __restrict__ csr1,
                        u16* __restrict__ U0, u16* __restrict__ U1){
    int d = blockIdx.x*4 + (threadIdx.x>>6);
    if (d >= NN) return;
    int lane = threadIdx.x & 63;
    const u16* u = blockIdx.y ? u1 : u0;
    const int* off = blockIdx.y ? off1 : off0;
    const int* csr = blockIdx.y ? csr1 : csr0;
    u16* U = blockIdx.y ? U1 : U0;
    int e0 = off[d], e1 = off[d+1];
    bool tl = lane < 12;
    float s0=0.f, s1=0.f, t0=0.f, t1=0.f;
    for (int e=e0; e<e1; e++){
        const u32* r = (const u32*)(u + (size_t)csr[e]*APIT);
        u32 v = r[lane];
        s0 += h2f((u16)(v & 0xffffu));
        s1 += h2f((u16)(v >> 16));
        if (tl){
            u32 w = r[64+lane];
            t0 += h2f((u16)(w & 0xffffu));
            t1 += h2f((u16)(w >> 16));
        }
    }
    if (lane == 11){ t0 = (float)(e1-e0); t1 = t0; }   // cols 150,151 = degree
    u32* Ur = (u32*)(U + (size_t)d*APIT);
    Ur[lane] = (u32)f2h(s0) | ((u32)f2h(s1) << 16);
    if (tl) Ur[64+lane] = (u32)f2h(t0) | ((u32)f2h(t1) << 16);
}

// ---------------- segment sum + readout ----------------
__global__ void k_seg(const u16* __restrict__ H, const int* __restrict__ gid, float* __restrict__ g){
    int f = threadIdx.x;
    if (f >= 150) return;
    int i0 = blockIdx.x*512;
    int i1 = i0 + 512; if (i1 > NN) i1 = NN;
    float acc = 0.f;
    int cg = gid[i0];
    for (int i=i0; i<i1; i++){
        int gg = gid[i];
        if (gg != cg){ atomicAdd(&g[cg*150+f], acc); acc=0.f; cg=gg; }
        acc += h2f(H[(size_t)i*APIT + f]);
    }
    atomicAdd(&g[cg*150+f], acc);
}

__global__ void k_mlp(const float* __restrict__ g, const float* __restrict__ pt,
                      const float* __restrict__ fc1p, const float* __restrict__ fc1b,
                      const float* __restrict__ fc2W, const float* __restrict__ fc2b,
                      const float* __restrict__ fcLW, const float* __restrict__ fcLb,
                      float* __restrict__ out){
    __shared__ float X[GG][152];
    __shared__ float Y[GG][80];
    __shared__ float Z[GG][80];
    int t = threadIdx.x;
    for (int idx=t; idx<GG*152; idx+=256){
        int gi=idx/152, c=idx-gi*152;
        float v = 0.f;
        if (c < 150){
            float lg = logf(g[gi*150+c]);
            if (lg != lg) lg = 0.f;
            v = fmaxf(lg, 0.f);
        } else if (c == 150) v = pt[gi];
        X[gi][c] = v;
    }
    __syncthreads();
    for (int idx=t; idx<GG*80; idx+=256){
        int gi=idx/80, o=idx-gi*80;
        float acc = fc1b[o];
        for (int k=0;k<151;k++) acc = fmaf(X[gi][k], fc1p[o*160+k], acc);
        Y[gi][o] = acc>0.f ? acc : 0.01f*acc;
    }
    __syncthreads();
    for (int idx=t; idx<GG*80; idx+=256){
        int gi=idx/80, o=idx-gi*80;
        float acc = fc2b[o];
        for (int k=0;k<80;k++) acc = fmaf(Y[gi][k], fc2W[o*80+k], acc);
        Z[gi][o] = acc>0.f ? acc : 0.01f*acc;
    }
    __syncthreads();
    for (int idx=t; idx<GG*10; idx+=256){
        int gi=idx/10, o=idx-gi*10;
        float acc = fcLb[o];
        for (int k=0;k<80;k++) acc = fmaf(Z[gi][k], fcLW[o*80+k], acc);
        out[idx] = acc;
    }
}

// ---------------- host ----------------
extern "C" void kernel_launch(void* const* d_in, const int* in_sizes, int n_in,
                              void* d_out, int out_size, void* d_ws, size_t ws_size,
                              hipStream_t stream) {
    const float* nodes = (const float*)d_in[0];
    const float* pt    = (const float*)d_in[1];
    const float* W1_0 = (const float*)d_in[2];  const float* b1_0 = (const float*)d_in[3];
    const float* W2_0 = (const float*)d_in[4];  const float* b2_0 = (const float*)d_in[5];
    const float* W1_1 = (const float*)d_in[6];  const float* b1_1 = (const float*)d_in[7];
    const float* W2_1 = (const float*)d_in[8];  const float* b2_1 = (const float*)d_in[9];
    const float* Wih = (const float*)d_in[10];  const float* bih = (const float*)d_in[11];
    const float* Whh = (const float*)d_in[12];  const float* bhh = (const float*)d_in[13];
    const float* fc1W = (const float*)d_in[14]; const float* fc1b = (const float*)d_in[15];
    const float* fc2W = (const float*)d_in[16]; const float* fc2b = (const float*)d_in[17];
    const float* fcLW = (const float*)d_in[18]; const float* fcLb = (const float*)d_in[19];
    const int* edges[2] = {(const int*)d_in[20], (const int*)d_in[21]};
    const int* gid = (const int*)d_in[22];
    float* out = (float*)d_out;

    char* p = (char*)d_ws;
    auto alloc = [&](size_t bytes){ char* r = p; p += (bytes + 255) & ~(size_t)255; return r; };
    u16* XA  = (u16*)alloc((size_t)MROW*APIT*2);
    u16* XB  = (u16*)alloc((size_t)MROW*APIT*2);
    u16* U0  = (u16*)alloc((size_t)MROW*APIT*2);
    u16* U1  = (u16*)alloc((size_t)MROW*APIT*2);
    u16* Yu1 = (u16*)alloc((size_t)MROW*APIT*2);
    u16* W1h = (u16*)alloc((size_t)2*CMAT*2);    // [set0|set1] fp16
    u16* Wh  = (u16*)alloc((size_t)3*CMAT*2);    // Whh gates r,z,n fp16
    u16* Cb  = (u16*)alloc((size_t)6*CMAT*2);    // composite fp16 (deg cols folded)
    float* tb   = (float*)alloc(4*160*4);
    float* b1t0 = (float*)alloc(160*4);
    float* b1t1 = (float*)alloc(160*4);
    float* fc1p = (float*)alloc(80*160*4);
    float* gbuf = (float*)alloc(GG*150*4);
    int* off0 = (int*)alloc((NN+1)*4);
    int* off1 = (int*)alloc((NN+1)*4);
    int* cur  = (int*)alloc(NN*4);
    int* hist = (int*)alloc(NN*4);
    int* csr0 = (int*)alloc((size_t)EE*4);
    int* csr1 = (int*)alloc((size_t)EE*4);
    (void)alloc(4096);   // tail pad for harmless last-row K-chunk overrun reads
    int* offs[2] = {off0, off1};
    int* csrs[2] = {csr0, csr1};

    // ---- prep ----
    k_cast16<<<120, 256, 0, stream>>>(W1_0, 0, W1h);
    k_cast16<<<120, 256, 0, stream>>>(W1_1, 0, W1h + CMAT);
    k_cast16<<<120, 256, 0, stream>>>(Whh, 0,   Wh);
    k_cast16<<<120, 256, 0, stream>>>(Whh, 150, Wh + CMAT);
    k_cast16<<<120, 256, 0, stream>>>(Whh, 300, Wh + 2*CMAT);
    k_comp<<<(6*192*160 + 255)/256, 256, 0, stream>>>(Wih, W2_0, W2_1, b2_0, b2_1, Cb);
    k_tabs<<<4, 256, 0, stream>>>(bih, bhh, b1_0, b1_1, tb, b1t0, b1t1);
    k_padfc1<<<50, 256, 0, stream>>>(fc1W, fc1p);
    k_inith<<<(NN*152 + 255)/256, 256, 0, stream>>>(nodes, XA);

    // ---- CSR ----
    for (int s=0; s<2; s++){
        hipMemsetAsync(hist, 0, NN*sizeof(int), stream);
        k_hist<<<(EE+255)/256, 256, 0, stream>>>(edges[s], hist);
        k_scan<<<1, 1024, 0, stream>>>(hist, offs[s], cur);
        k_fill<<<(EE+255)/256, 256, 0, stream>>>(edges[s], cur, csrs[s]);
    }

    // ---- message passes ----
    u16* Hc = XA; u16* Hx = XB;
    dim3 gT(MROW/64, 3);
    dim3 gGa((NN+3)/4, 2);
    for (int ps=0; ps<4; ps++){
        u16* yu0 = Hx;   // u scratch for set0 aliases h_next; dead before mega writes Hx
        k_ugemm2<<<gT, 256, 0, stream>>>(Hc, W1h, b1t0, b1t1, yu0, Yu1);
        k_gath2<<<gGa, 256, 0, stream>>>(yu0, Yu1, off0, csr0, off1, csr1, U0, U1);
        k_mega<<<gT, 256, 0, stream>>>(Hc, U0, U1, Cb, Wh, tb, Hx);
        u16* t = Hc; Hc = Hx; Hx = t;
    }

    // ---- readout ----
    hipMemsetAsync(gbuf, 0, GG*150*sizeof(float), stream);
    k_seg<<<(NN+511)/512, 192, 0, stream>>>(Hc, gid, gbuf);
    k_mlp<<<1, 256, 0, stream>>>(gbuf, pt, fc1p, fc1b, fc2W, fc2b, fcLW, fcLb, out);
}

// Round 10
// 1529.142 us; speedup vs baseline: 1.6748x; 1.1905x over previous
//
#include <hip/hip_runtime.h>

typedef unsigned short u16;
typedef unsigned int u32;
typedef __attribute__((ext_vector_type(8))) short s8v;      // 8x16-bit
typedef __attribute__((ext_vector_type(8))) _Float16 h8v;   // 8 fp16
typedef __attribute__((ext_vector_type(4))) float f4v;      // C/D frag

#define NN 100000
#define MROW 100096
#define EE 500000
#define GG 16
#define APIT 152      // A-source row pitch (u16, fp16): H, u, U ; U cols 150/151 = degree
#define CPIT 160      // weight row pitch (u16, fp16 single-plane)
#define CMAT (192*CPIT)
#define SCB 1024      // scan elems per block
#define SNB 98        // ceil(NN/SCB)

__device__ __forceinline__ u16 f2h(float x){ union{u16 u;_Float16 f;}c; c.f=(_Float16)x; return c.u; }
__device__ __forceinline__ float h2f(u16 b){ union{u16 u;_Float16 f;}c; c.u=b; return (float)c.f; }

#define GLOAD_LDS(gp, lp) \
    __builtin_amdgcn_global_load_lds((const __attribute__((address_space(1))) void*)(gp), \
                                     (__attribute__((address_space(3))) void*)(lp), 16, 0, 0)

// ---------------- staging (coalesced, swizzled) ----------------
template<int NI>
__device__ __forceinline__ void stage(const u16* base, const int (&off)[NI], int koff,
                                      const int (&lds)[NI], u16* dst){
#pragma unroll
    for (int i=0;i<NI;i++) GLOAD_LDS(base+off[i]+koff, dst+lds[i]);
}

// ---------------- MFMA helpers (fp16): A frags in regs, W frags from LDS ----------------
__device__ __forceinline__ void mf3h(const s8v (&af)[4], const u16* lWp, int wfo, int mstr,
                                     f4v (&X)[4], f4v (&Y)[4], f4v (&Z)[4]){
    h8v w0 = *(const h8v*)(lWp+wfo);
    h8v w1 = *(const h8v*)(lWp+mstr+wfo);
    h8v w2 = *(const h8v*)(lWp+2*mstr+wfo);
#pragma unroll
    for (int mi=0;mi<4;mi++){
        X[mi]=__builtin_amdgcn_mfma_f32_16x16x32_f16(*(const h8v*)&af[mi],w0,X[mi],0,0,0);
        Y[mi]=__builtin_amdgcn_mfma_f32_16x16x32_f16(*(const h8v*)&af[mi],w1,Y[mi],0,0,0);
        Z[mi]=__builtin_amdgcn_mfma_f32_16x16x32_f16(*(const h8v*)&af[mi],w2,Z[mi],0,0,0);
    }
}
__device__ __forceinline__ void mf2h(const s8v (&af)[4], const u16* lWp, int wfo, int mstr,
                                     f4v (&X)[4], f4v (&Y)[4]){
    h8v w0 = *(const h8v*)(lWp+wfo);
    h8v w1 = *(const h8v*)(lWp+mstr+wfo);
#pragma unroll
    for (int mi=0;mi<4;mi++){
        X[mi]=__builtin_amdgcn_mfma_f32_16x16x32_f16(*(const h8v*)&af[mi],w0,X[mi],0,0,0);
        Y[mi]=__builtin_amdgcn_mfma_f32_16x16x32_f16(*(const h8v*)&af[mi],w1,Y[mi],0,0,0);
    }
}

__device__ __forceinline__ void lda64(const u16* lA_, const int (&aF)[2][4], s8v (&a)[2][4]){
#pragma unroll
    for (int ks=0;ks<2;ks++)
#pragma unroll
        for (int mi=0;mi<4;mi++) a[ks][mi] = *(const s8v*)(lA_+aF[ks][mi]);
}
__device__ __forceinline__ void lda32(const u16* lA_, const int (&aF)[4], s8v (&a)[4]){
#pragma unroll
    for (int mi=0;mi<4;mi++) a[mi] = *(const s8v*)(lA_+aF[mi]);
}

// ---------------- edge-MLP layer 1 (both sets): u_s = lrelu(h @ W1_s^T + b1_s) ----------------
__global__ __launch_bounds__(256,3) void k_ugemm2(const u16* __restrict__ H,
    const u16* __restrict__ W1h,   // 2 fp16 mats contiguous: [set0|set1]
    const float* __restrict__ b1t0, const float* __restrict__ b1t1,
    u16* __restrict__ u0, u16* __restrict__ u1)
{
    __shared__ u16 lA[64*64], lW[2*64*64];
    int tid=threadIdx.x, wv=tid>>6, lane=tid&63, lr=lane&15, quad=lane>>4;
    int m0=blockIdx.x*64, n0=blockIdx.y*64;
    int aL64[2], aO64[2];
#pragma unroll
    for (int i=0;i<2;i++){ int s=tid+i*256, row=s>>3, q8=((s&7)^(row&7))<<3;
        aL64[i]=s<<3; aO64[i]=(m0+row)*APIT+q8; }
    int aL32[1], aO32[1];
    { int s=tid, row=s>>2, q8=((s&3)^(row&3))<<3; aL32[0]=s<<3; aO32[0]=(m0+row)*APIT+q8; }
    int wL64[4], wO64[4];
#pragma unroll
    for (int i=0;i<4;i++){ int s=tid+i*256, sel=s>>9, rem=s&511, row=rem>>3, q8=((rem&7)^(row&7))<<3;
        wL64[i]=sel*4096+rem*8; wO64[i]=sel*CMAT+(n0+row)*CPIT+q8; }
    int wL32[2], wO32[2];
#pragma unroll
    for (int i=0;i<2;i++){ int s=tid+i*256, sel=s>>8, rem=s&255, row=rem>>2, q8=((rem&3)^(row&3))<<3;
        wL32[i]=sel*2048+rem*8; wO32[i]=sel*CMAT+(n0+row)*CPIT+q8; }
    int aF64[2][4], wF64[2], aF32[4], wF32;
#pragma unroll
    for (int ks=0;ks<2;ks++){
#pragma unroll
        for (int mi=0;mi<4;mi++){ int row=mi*16+lr, ph=(ks*4+quad)^(row&7); aF64[ks][mi]=row*64+ph*8; }
        int wr=wv*16+lr, wp=(ks*4+quad)^(wr&7); wF64[ks]=wr*64+wp*8;
    }
#pragma unroll
    for (int mi=0;mi<4;mi++){ int row=mi*16+lr, ph=quad^(row&3); aF32[mi]=row*32+ph*8; }
    { int wr=wv*16+lr, wp=quad^(wr&3); wF32=wr*32+wp*8; }

    f4v a0[4]={}, a1[4]={};
    s8v a[2][4]; s8v a32[4];
#pragma unroll
    for (int kc=0;kc<2;kc++){
        int koff=kc*64;
        __syncthreads();
        stage<2>(H,aO64,koff,aL64,lA);
        stage<4>(W1h,wO64,koff,wL64,lW);
        __syncthreads();
        lda64(lA,aF64,a);
#pragma unroll
        for (int ks=0;ks<2;ks++) mf2h(a[ks],lW,wF64[ks],4096,a0,a1);
    }
    __syncthreads();
    stage<1>(H,aO32,128,aL32,lA);
    stage<2>(W1h,wO32,128,wL32,lW);
    __syncthreads();
    lda32(lA,aF32,a32);
    mf2h(a32,lW,wF32,2048,a0,a1);

    int c = n0 + wv*16 + lr;
    if (c < 152){
        float bb0=b1t0[c], bb1=b1t1[c];
#pragma unroll
        for (int mi=0;mi<4;mi++)
#pragma unroll
            for (int reg=0;reg<4;reg++){
                int r = m0 + mi*16 + quad*4 + reg;
                if (r >= NN) continue;
                float v0=a0[mi][reg]+bb0; v0 = v0>0.f ? v0 : 0.01f*v0;
                float v1=a1[mi][reg]+bb1; v1 = v1>0.f ? v1 : 0.01f*v1;
                if (c>=150){ v0=0.f; v1=0.f; }
                u0[(size_t)r*APIT+c]=f2h(v0);
                u1[(size_t)r*APIT+c]=f2h(v1);
            }
    }
}

// ---------------- fused GRU mega-kernel (all-fp16) ----------------
__global__ __launch_bounds__(256,3) void k_mega(const u16* __restrict__ H,
    const u16* __restrict__ U0, const u16* __restrict__ U1,
    const u16* __restrict__ Cb,   // 6 fp16 mats: [s][gate r,z,n] (deg cols 150/151 folded)
    const u16* __restrict__ Wh,   // 3 fp16 mats: Whh gates r,z,n
    const float* __restrict__ tb, u16* __restrict__ Hn)
{
    __shared__ u16 lA[64*64], lW[3*64*64];
    int tid=threadIdx.x, wv=tid>>6, lane=tid&63, lr=lane&15, quad=lane>>4;
    int m0=blockIdx.x*64, n0=blockIdx.y*64;
    int aL64[2], aO64[2];
#pragma unroll
    for (int i=0;i<2;i++){ int s=tid+i*256, row=s>>3, q8=((s&7)^(row&7))<<3;
        aL64[i]=s<<3; aO64[i]=(m0+row)*APIT+q8; }
    int aL32[1], aO32[1];
    { int s=tid, row=s>>2, q8=((s&3)^(row&3))<<3; aL32[0]=s<<3; aO32[0]=(m0+row)*APIT+q8; }
    int wL64[6], wO64[6];
#pragma unroll
    for (int i=0;i<6;i++){ int s=tid+i*256, sel=s>>9, rem=s&511, row=rem>>3, q8=((rem&7)^(row&7))<<3;
        wL64[i]=sel*4096+rem*8; wO64[i]=sel*CMAT+(n0+row)*CPIT+q8; }
    int wL32[3], wO32[3];
#pragma unroll
    for (int i=0;i<3;i++){ int s=tid+i*256, sel=s>>8, rem=s&255, row=rem>>2, q8=((rem&3)^(row&3))<<3;
        wL32[i]=sel*2048+rem*8; wO32[i]=sel*CMAT+(n0+row)*CPIT+q8; }
    int aF64[2][4], wF64[2], aF32[4], wF32;
#pragma unroll
    for (int ks=0;ks<2;ks++){
#pragma unroll
        for (int mi=0;mi<4;mi++){ int row=mi*16+lr, ph=(ks*4+quad)^(row&7); aF64[ks][mi]=row*64+ph*8; }
        int wr=wv*16+lr, wp=(ks*4+quad)^(wr&7); wF64[ks]=wr*64+wp*8;
    }
#pragma unroll
    for (int mi=0;mi<4;mi++){ int row=mi*16+lr, ph=quad^(row&3); aF32[mi]=row*32+ph*8; }
    { int wr=wv*16+lr, wp=quad^(wr&3); wF32=wr*32+wp*8; }

    f4v aR[4]={}, aZ[4]={}, aI[4]={}, aHh[4]={};

    auto dopass = [&](const u16* A, const u16* Wg, f4v (&aT)[4]){
        s8v a[2][4]; s8v a32[4];
#pragma unroll
        for (int kc=0;kc<2;kc++){
            int koff=kc*64;
            __syncthreads();
            stage<2>(A,aO64,koff,aL64,lA);
            stage<6>(Wg,wO64,koff,wL64,lW);
            __syncthreads();
            lda64(lA,aF64,a);
#pragma unroll
            for (int ks=0;ks<2;ks++) mf3h(a[ks],lW,wF64[ks],4096,aR,aZ,aT);
        }
        __syncthreads();
        stage<1>(A,aO32,128,aL32,lA);
        stage<3>(Wg,wO32,128,wL32,lW);
        __syncthreads();
        lda32(lA,aF32,a32);
        mf3h(a32,lW,wF32,2048,aR,aZ,aT);
    };
    dopass(U0, Cb,          aI);
    dopass(U1, Cb + 3*CMAT, aI);
    dopass(H,  Wh,          aHh);

    // ---- GRU epilogue ----
    int c = n0 + wv*16 + lr;
    if (c < 152){
        float bR=tb[c], bZ=tb[160+c], bI=tb[320+c], bHn=tb[480+c];
#pragma unroll
        for (int mi=0;mi<4;mi++)
#pragma unroll
            for (int reg=0;reg<4;reg++){
                int r = m0 + mi*16 + quad*4 + reg;
                if (r >= NN) continue;
                float pr=aR[mi][reg]+bR, pz=aZ[mi][reg]+bZ, pi=aI[mi][reg]+bI, ph_=aHh[mi][reg]+bHn;
                float rg = 1.f/(1.f+__expf(-pr));
                float zg = 1.f/(1.f+__expf(-pz));
                float e2 = __expf(2.f*(pi + rg*ph_));
                float n  = 1.f - 2.f/(e2+1.f);
                float hold = h2f(H[(size_t)r*APIT+c]);
                float o = (1.f-zg)*n + zg*hold;
                if (c>=150) o = 0.f;
                Hn[(size_t)r*APIT+c] = f2h(o);
            }
    }
}

// ---------------- prep kernels ----------------
__global__ void k_cast16(const float* __restrict__ src, int rowoff, u16* __restrict__ dst){
    int idx = blockIdx.x*256 + threadIdx.x;     // 192*160
    if (idx >= 192*160) return;
    int r = idx/160, c = idx - r*160;
    float x = (r<150 && c<150) ? src[(size_t)(rowoff+r)*150 + c] : 0.f;
    dst[(size_t)r*CPIT + c] = f2h(x);
}

// composite C[s*3+g] = Wih_g @ W2_s (cols 0..149); col150(s=0)/col151(s=1) = Wih_g @ b2_s ; fp16
__global__ void k_comp(const float* __restrict__ Wih, const float* __restrict__ W2_0,
                       const float* __restrict__ W2_1, const float* __restrict__ b2_0,
                       const float* __restrict__ b2_1, u16* __restrict__ Cb){
    int idx = blockIdx.x*256 + threadIdx.x;     // 6*192*160
    if (idx >= 6*192*160) return;
    int mat = idx/(192*160), rem = idx - mat*(192*160);
    int o = rem/160, c = rem - o*160;
    int s = mat/3, g = mat - s*3;
    float v = 0.f;
    if (o < 150){
        const float* wrow = Wih + (size_t)(g*150+o)*150;
        if (c < 150){
            const float* W2 = s ? W2_1 : W2_0;
            for (int j=0;j<150;j++) v += wrow[j] * W2[(size_t)j*150 + c];
        } else if (c==150 && s==0){
            for (int j=0;j<150;j++) v += wrow[j] * b2_0[j];
        } else if (c==151 && s==1){
            for (int j=0;j<150;j++) v += wrow[j] * b2_1[j];
        }
    }
    Cb[(size_t)mat*CMAT + o*CPIT + c] = f2h(v);
}

__global__ void k_tabs(const float* bih,const float* bhh,
                       const float* b1_0,const float* b1_1,
                       float* tb, float* b1t0, float* b1t1){
    int idx = blockIdx.x*256 + threadIdx.x;     // 6*160
    if (idx >= 6*160) return;
    int t = idx/160, c = idx - t*160;
    float v = 0.f;
    if (c < 150){
        if (t==0) v = bih[c]+bhh[c];
        else if (t==1) v = bih[150+c]+bhh[150+c];
        else if (t==2) v = bih[300+c];
        else if (t==3) v = bhh[300+c];
        else if (t==4) v = b1_0[c];
        else v = b1_1[c];
    }
    if (t<4) tb[t*160+c]=v;
    else if (t==4) b1t0[c]=v;
    else b1t1[c]=v;
}

__global__ void k_padfc1(const float* __restrict__ s, float* __restrict__ d){
    int idx = blockIdx.x*256 + threadIdx.x;     // 80*160
    if (idx >= 80*160) return;
    int r = idx/160, c = idx - r*160;
    d[idx] = (c<151) ? s[r*151 + c] : 0.f;
}

__global__ void k_inith(const float* __restrict__ nodes, u16* __restrict__ H){
    int idx = blockIdx.x*256 + threadIdx.x;     // NN*152
    if (idx >= NN*152) return;
    int m = idx/152, c = idx - m*152;
    float x = (c<150) ? nodes[(size_t)m*150 + c] : 0.f;
    H[(size_t)m*APIT + c] = f2h(x);
}

// ---------------- CSR build (multi-block scan; grid.y = edge set) ----------------
__global__ void k_hist2(const int* __restrict__ e0, const int* __restrict__ e1, int* __restrict__ hist){
    int e = blockIdx.x*256 + threadIdx.x;
    if (e >= EE) return;
    const int* ed = blockIdx.y ? e1 : e0;
    atomicAdd(&hist[blockIdx.y*NN + ed[2*e]], 1);
}

__global__ __launch_bounds__(256) void k_psum(const int* __restrict__ hist, int* __restrict__ part){
    int b = blockIdx.x, y = blockIdx.y, t = threadIdx.x;
    const int* cnt = hist + y*NN;
    int i0 = b*SCB + t*4;
    int s = 0;
#pragma unroll
    for (int u=0;u<4;u++){ int i=i0+u; if (i<NN) s += cnt[i]; }
#pragma unroll
    for (int o=32;o>0;o>>=1) s += __shfl_down(s,o);
    __shared__ int sd[4];
    if ((t&63)==0) sd[t>>6] = s;
    __syncthreads();
    if (t==0) part[y*128 + b] = sd[0]+sd[1]+sd[2]+sd[3];
}

__global__ __launch_bounds__(128) void k_pscan(int* __restrict__ part, int* __restrict__ off0, int* __restrict__ off1){
    int y = blockIdx.y, t = threadIdx.x;
    __shared__ int sd[128];
    int v = (t < SNB) ? part[y*128 + t] : 0;
    sd[t] = v;
    __syncthreads();
    for (int o=1;o<128;o<<=1){
        int x2 = 0;
        if (t >= o) x2 = sd[t-o];
        __syncthreads();
        if (t >= o) sd[t] += x2;
        __syncthreads();
    }
    if (t < SNB) part[y*128 + t] = sd[t] - v;     // exclusive
    if (t == 127){
        int* off = y ? off1 : off0;
        off[NN] = sd[127];                         // total = EE
    }
}

__global__ __launch_bounds__(256) void k_papply(const int* __restrict__ hist, const int* __restrict__ part,
                                                int* __restrict__ off0, int* __restrict__ off1,
                                                int* __restrict__ cur){
    int b = blockIdx.x, y = blockIdx.y, t = threadIdx.x;
    const int* cnt = hist + y*NN;
    int* off = y ? off1 : off0;
    int* cu  = cur + y*NN;
    int i0 = b*SCB + t*4;
    int v[4]; int s = 0;
#pragma unroll
    for (int u=0;u<4;u++){ int i=i0+u; v[u] = (i<NN) ? cnt[i] : 0; s += v[u]; }
    __shared__ int sd[256];
    sd[t] = s;
    __syncthreads();
    for (int o=1;o<256;o<<=1){
        int x2 = 0;
        if (t >= o) x2 = sd[t-o];
        __syncthreads();
        if (t >= o) sd[t] += x2;
        __syncthreads();
    }
    int excl = part[y*128 + b] + sd[t] - s;
#pragma unroll
    for (int u=0;u<4;u++){
        int i = i0+u;
        if (i<NN){ off[i]=excl; cu[i]=excl; excl += v[u]; }
    }
}

__global__ void k_fill2(const int* __restrict__ e0, const int* __restrict__ e1,
                        int* __restrict__ cur, int* __restrict__ csr0, int* __restrict__ csr1){
    int e = blockIdx.x*256 + threadIdx.x;
    if (e >= EE) return;
    const int* ed = blockIdx.y ? e1 : e0;
    int* csr = blockIdx.y ? csr1 : csr0;
    int dst = ed[2*e], src = ed[2*e+1];
    int pos = atomicAdd(&cur[blockIdx.y*NN + dst], 1);
    csr[pos] = src;
}

// ---------------- gather (u32 packed fp16); degree -> cols 150/151 ----------------
__global__ void k_gath2(const u16* __restrict__ u0, const u16* __restrict__ u1,
                        const int* __restrict__ off0, const int* __restrict__ csr0,
                        const int* __restrict__ off1, const int* __restrict__ csr1,
                        u16* __restrict__ U0, u16* __restrict__ U1){
    int d = blockIdx.x*4 + (threadIdx.x>>6);
    if (d >= NN) return;
    int lane = threadIdx.x & 63;
    const u16* u = blockIdx.y ? u1 : u0;
    const int* off = blockIdx.y ? off1 : off0;
    const int* csr = blockIdx.y ? csr1 : csr0;
    u16* U = blockIdx.y ? U1 : U0;
    int e0 = off[d], e1 = off[d+1];
    bool tl = lane < 12;
    float s0=0.f, s1=0.f, t0=0.f, t1=0.f;
    for (int e=e0; e<e1; e++){
        const u32* r = (const u32*)(u + (size_t)csr[e]*APIT);
        u32 v = r[lane];
        s0 += h2f((u16)(v & 0xffffu));
        s1 += h2f((u16)(v >> 16));
        if (tl){
            u32 w = r[64+lane];
            t0 += h2f((u16)(w & 0xffffu));
            t1 += h2f((u16)(w >> 16));
        }
    }
    if (lane == 11){ t0 = (float)(e1-e0); t1 = t0; }   // cols 150,151 = degree
    u32* Ur = (u32*)(U + (size_t)d*APIT);
    Ur[lane] = (u32)f2h(s0) | ((u32)f2h(s1) << 16);
    if (tl) Ur[64+lane] = (u32)f2h(t0) | ((u32)f2h(t1) << 16);
}

// ---------------- segment sum + readout ----------------
__global__ void k_seg(const u16* __restrict__ H, const int* __restrict__ gid, float* __restrict__ g){
    int f = threadIdx.x;
    if (f >= 150) return;
    int i0 = blockIdx.x*512;
    int i1 = i0 + 512; if (i1 > NN) i1 = NN;
    float acc = 0.f;
    int cg = gid[i0];
    for (int i=i0; i<i1; i++){
        int gg = gid[i];
        if (gg != cg){ atomicAdd(&g[cg*150+f], acc); acc=0.f; cg=gg; }
        acc += h2f(H[(size_t)i*APIT + f]);
    }
    atomicAdd(&g[cg*150+f], acc);
}

__global__ void k_mlp(const float* __restrict__ g, const float* __restrict__ pt,
                      const float* __restrict__ fc1p, const float* __restrict__ fc1b,
                      const float* __restrict__ fc2W, const float* __restrict__ fc2b,
                      const float* __restrict__ fcLW, const float* __restrict__ fcLb,
                      float* __restrict__ out){
    __shared__ float X[GG][152];
    __shared__ float Y[GG][80];
    __shared__ float Z[GG][80];
    int t = threadIdx.x;
    for (int idx=t; idx<GG*152; idx+=256){
        int gi=idx/152, c=idx-gi*152;
        float v = 0.f;
        if (c < 150){
            float lg = logf(g[gi*150+c]);
            if (lg != lg) lg = 0.f;
            v = fmaxf(lg, 0.f);
        } else if (c == 150) v = pt[gi];
        X[gi][c] = v;
    }
    __syncthreads();
    for (int idx=t; idx<GG*80; idx+=256){
        int gi=idx/80, o=idx-gi*80;
        float acc = fc1b[o];
        for (int k=0;k<151;k++) acc = fmaf(X[gi][k], fc1p[o*160+k], acc);
        Y[gi][o] = acc>0.f ? acc : 0.01f*acc;
    }
    __syncthreads();
    for (int idx=t; idx<GG*80; idx+=256){
        int gi=idx/80, o=idx-gi*80;
        float acc = fc2b[o];
        for (int k=0;k<80;k++) acc = fmaf(Y[gi][k], fc2W[o*80+k], acc);
        Z[gi][o] = acc>0.f ? acc : 0.01f*acc;
    }
    __syncthreads();
    for (int idx=t; idx<GG*10; idx+=256){
        int gi=idx/10, o=idx-gi*10;
        float acc = fcLb[o];
        for (int k=0;k<80;k++) acc = fmaf(Z[gi][k], fcLW[o*80+k], acc);
        out[idx] = acc;
    }
}

// ---------------- host ----------------
extern "C" void kernel_launch(void* const* d_in, const int* in_sizes, int n_in,
                              void* d_out, int out_size, void* d_ws, size_t ws_size,
                              hipStream_t stream) {
    const float* nodes = (const float*)d_in[0];
    const float* pt    = (const float*)d_in[1];
    const float* W1_0 = (const float*)d_in[2];  const float* b1_0 = (const float*)d_in[3];
    const float* W2_0 = (const float*)d_in[4];  const float* b2_0 = (const float*)d_in[5];
    const float* W1_1 = (const float*)d_in[6];  const float* b1_1 = (const float*)d_in[7];
    const float* W2_1 = (const float*)d_in[8];  const float* b2_1 = (const float*)d_in[9];
    const float* Wih = (const float*)d_in[10];  const float* bih = (const float*)d_in[11];
    const float* Whh = (const float*)d_in[12];  const float* bhh = (const float*)d_in[13];
    const float* fc1W = (const float*)d_in[14]; const float* fc1b = (const float*)d_in[15];
    const float* fc2W = (const float*)d_in[16]; const float* fc2b = (const float*)d_in[17];
    const float* fcLW = (const float*)d_in[18]; const float* fcLb = (const float*)d_in[19];
    const int* edges0 = (const int*)d_in[20];
    const int* edges1 = (const int*)d_in[21];
    const int* gid = (const int*)d_in[22];
    float* out = (float*)d_out;

    char* p = (char*)d_ws;
    auto alloc = [&](size_t bytes){ char* r = p; p += (bytes + 255) & ~(size_t)255; return r; };
    u16* XA  = (u16*)alloc((size_t)MROW*APIT*2);
    u16* XB  = (u16*)alloc((size_t)MROW*APIT*2);
    u16* U0  = (u16*)alloc((size_t)MROW*APIT*2);
    u16* U1  = (u16*)alloc((size_t)MROW*APIT*2);
    u16* Yu1 = (u16*)alloc((size_t)MROW*APIT*2);
    u16* W1h = (u16*)alloc((size_t)2*CMAT*2);    // [set0|set1] fp16
    u16* Wh  = (u16*)alloc((size_t)3*CMAT*2);    // Whh gates r,z,n fp16
    u16* Cb  = (u16*)alloc((size_t)6*CMAT*2);    // composite fp16 (deg cols folded)
    float* tb   = (float*)alloc(4*160*4);
    float* b1t0 = (float*)alloc(160*4);
    float* b1t1 = (float*)alloc(160*4);
    float* fc1p = (float*)alloc(80*160*4);
    float* gbuf = (float*)alloc(GG*150*4);
    int* off0 = (int*)alloc((NN+1)*4);
    int* off1 = (int*)alloc((NN+1)*4);
    int* cur  = (int*)alloc((size_t)2*NN*4);
    int* hist = (int*)alloc((size_t)2*NN*4);
    int* part = (int*)alloc(2*128*4);
    int* csr0 = (int*)alloc((size_t)EE*4);
    int* csr1 = (int*)alloc((size_t)EE*4);
    (void)alloc(4096);   // tail pad for harmless last-row K-chunk overrun reads

    // ---- prep ----
    k_cast16<<<120, 256, 0, stream>>>(W1_0, 0, W1h);
    k_cast16<<<120, 256, 0, stream>>>(W1_1, 0, W1h + CMAT);
    k_cast16<<<120, 256, 0, stream>>>(Whh, 0,   Wh);
    k_cast16<<<120, 256, 0, stream>>>(Whh, 150, Wh + CMAT);
    k_cast16<<<120, 256, 0, stream>>>(Whh, 300, Wh + 2*CMAT);
    k_comp<<<(6*192*160 + 255)/256, 256, 0, stream>>>(Wih, W2_0, W2_1, b2_0, b2_1, Cb);
    k_tabs<<<4, 256, 0, stream>>>(bih, bhh, b1_0, b1_1, tb, b1t0, b1t1);
    k_padfc1<<<50, 256, 0, stream>>>(fc1W, fc1p);
    k_inith<<<(NN*152 + 255)/256, 256, 0, stream>>>(nodes, XA);

    // ---- CSR (both sets batched via grid.y) ----
    hipMemsetAsync(hist, 0, (size_t)2*NN*sizeof(int), stream);
    dim3 gE((EE+255)/256, 2), gS(SNB, 2), g1(1, 2);
    k_hist2<<<gE, 256, 0, stream>>>(edges0, edges1, hist);
    k_psum<<<gS, 256, 0, stream>>>(hist, part);
    k_pscan<<<g1, 128, 0, stream>>>(part, off0, off1);
    k_papply<<<gS, 256, 0, stream>>>(hist, part, off0, off1, cur);
    k_fill2<<<gE, 256, 0, stream>>>(edges0, edges1, cur, csr0, csr1);

    // ---- message passes ----
    u16* Hc = XA; u16* Hx = XB;
    dim3 gT(MROW/64, 3);
    dim3 gGa((NN+3)/4, 2);
    for (int ps=0; ps<4; ps++){
        u16* yu0 = Hx;   // u scratch for set0 aliases h_next; dead before mega writes Hx
        k_ugemm2<<<gT, 256, 0, stream>>>(Hc, W1h, b1t0, b1t1, yu0, Yu1);
        k_gath2<<<gGa, 256, 0, stream>>>(yu0, Yu1, off0, csr0, off1, csr1, U0, U1);
        k_mega<<<gT, 256, 0, stream>>>(Hc, U0, U1, Cb, Wh, tb, Hx);
        u16* t = Hc; Hc = Hx; Hx = t;
    }

    // ---- readout ----
    hipMemsetAsync(gbuf, 0, GG*150*sizeof(float), stream);
    k_seg<<<(NN+511)/512, 192, 0, stream>>>(Hc, gid, gbuf);
    k_mlp<<<1, 256, 0, stream>>>(gbuf, pt, fc1p, fc1b, fc2W, fc2b, fcLW, fcLb, out);
}

// Round 11
// 1416.295 us; speedup vs baseline: 1.8082x; 1.0797x over previous
//
#include <hip/hip_runtime.h>

typedef unsigned short u16;
typedef unsigned int u32;
typedef __attribute__((ext_vector_type(8))) short s8v;      // 8x16-bit
typedef __attribute__((ext_vector_type(8))) _Float16 h8v;   // 8 fp16
typedef __attribute__((ext_vector_type(4))) float f4v;      // C/D frag

#define NN 100000
#define MROW 100096
#define EE 500000
#define GG 16
#define APIT 152      // A-source row pitch (u16, fp16): H, u, U ; U cols 150/151 = degree
#define CPIT 160      // weight row pitch (u16, fp16 single-plane)
#define CMAT (192*CPIT)
#define SCB 1024      // scan elems per block
#define SNB 98        // ceil(NN/SCB)

__device__ __forceinline__ u16 f2h(float x){ union{u16 u;_Float16 f;}c; c.f=(_Float16)x; return c.u; }
__device__ __forceinline__ float h2f(u16 b){ union{u16 u;_Float16 f;}c; c.u=b; return (float)c.f; }

#define GLOAD_LDS(gp, lp) \
    __builtin_amdgcn_global_load_lds((const __attribute__((address_space(1))) void*)(gp), \
                                     (__attribute__((address_space(3))) void*)(lp), 16, 0, 0)

// ---------------- staging (coalesced, swizzled) ----------------
template<int NI>
__device__ __forceinline__ void stage(const u16* base, const int (&off)[NI], int koff,
                                      const int (&lds)[NI], u16* dst){
#pragma unroll
    for (int i=0;i<NI;i++) GLOAD_LDS(base+off[i]+koff, dst+lds[i]);
}

// ---------------- MFMA helpers (fp16): A frags in regs, W frags from LDS ----------------
__device__ __forceinline__ void mf3h(const s8v (&af)[4], const u16* lWp, int wfo, int mstr,
                                     f4v (&X)[4], f4v (&Y)[4], f4v (&Z)[4]){
    h8v w0 = *(const h8v*)(lWp+wfo);
    h8v w1 = *(const h8v*)(lWp+mstr+wfo);
    h8v w2 = *(const h8v*)(lWp+2*mstr+wfo);
#pragma unroll
    for (int mi=0;mi<4;mi++){
        X[mi]=__builtin_amdgcn_mfma_f32_16x16x32_f16(*(const h8v*)&af[mi],w0,X[mi],0,0,0);
        Y[mi]=__builtin_amdgcn_mfma_f32_16x16x32_f16(*(const h8v*)&af[mi],w1,Y[mi],0,0,0);
        Z[mi]=__builtin_amdgcn_mfma_f32_16x16x32_f16(*(const h8v*)&af[mi],w2,Z[mi],0,0,0);
    }
}
__device__ __forceinline__ void mf2h(const s8v (&af)[4], const u16* lWp, int wfo, int mstr,
                                     f4v (&X)[4], f4v (&Y)[4]){
    h8v w0 = *(const h8v*)(lWp+wfo);
    h8v w1 = *(const h8v*)(lWp+mstr+wfo);
#pragma unroll
    for (int mi=0;mi<4;mi++){
        X[mi]=__builtin_amdgcn_mfma_f32_16x16x32_f16(*(const h8v*)&af[mi],w0,X[mi],0,0,0);
        Y[mi]=__builtin_amdgcn_mfma_f32_16x16x32_f16(*(const h8v*)&af[mi],w1,Y[mi],0,0,0);
    }
}

__device__ __forceinline__ void lda64(const u16* lA_, const int (&aF)[2][4], s8v (&a)[2][4]){
#pragma unroll
    for (int ks=0;ks<2;ks++)
#pragma unroll
        for (int mi=0;mi<4;mi++) a[ks][mi] = *(const s8v*)(lA_+aF[ks][mi]);
}
__device__ __forceinline__ void lda32(const u16* lA_, const int (&aF)[4], s8v (&a)[4]){
#pragma unroll
    for (int mi=0;mi<4;mi++) a[mi] = *(const s8v*)(lA_+aF[mi]);
}

// ---------------- edge-MLP layer 1 (both sets): u_s = lrelu(h @ W1_s^T + b1_s) ----------------
__global__ __launch_bounds__(256,3) void k_ugemm2(const u16* __restrict__ H,
    const u16* __restrict__ W1h,   // 2 fp16 mats contiguous: [set0|set1]
    const float* __restrict__ b1t0, const float* __restrict__ b1t1,
    u16* __restrict__ u0, u16* __restrict__ u1)
{
    __shared__ u16 lA[64*64], lW[2*64*64];
    int tid=threadIdx.x, wv=tid>>6, lane=tid&63, lr=lane&15, quad=lane>>4;
    int m0=blockIdx.x*64, n0=blockIdx.y*64;
    int aL64[2], aO64[2];
#pragma unroll
    for (int i=0;i<2;i++){ int s=tid+i*256, row=s>>3, q8=((s&7)^(row&7))<<3;
        aL64[i]=s<<3; aO64[i]=(m0+row)*APIT+q8; }
    int aL32[1], aO32[1];
    { int s=tid, row=s>>2, q8=((s&3)^(row&3))<<3; aL32[0]=s<<3; aO32[0]=(m0+row)*APIT+q8; }
    int wL64[4], wO64[4];
#pragma unroll
    for (int i=0;i<4;i++){ int s=tid+i*256, sel=s>>9, rem=s&511, row=rem>>3, q8=((rem&7)^(row&7))<<3;
        wL64[i]=sel*4096+rem*8; wO64[i]=sel*CMAT+(n0+row)*CPIT+q8; }
    int wL32[2], wO32[2];
#pragma unroll
    for (int i=0;i<2;i++){ int s=tid+i*256, sel=s>>8, rem=s&255, row=rem>>2, q8=((rem&3)^(row&3))<<3;
        wL32[i]=sel*2048+rem*8; wO32[i]=sel*CMAT+(n0+row)*CPIT+q8; }
    int aF64[2][4], wF64[2], aF32[4], wF32;
#pragma unroll
    for (int ks=0;ks<2;ks++){
#pragma unroll
        for (int mi=0;mi<4;mi++){ int row=mi*16+lr, ph=(ks*4+quad)^(row&7); aF64[ks][mi]=row*64+ph*8; }
        int wr=wv*16+lr, wp=(ks*4+quad)^(wr&7); wF64[ks]=wr*64+wp*8;
    }
#pragma unroll
    for (int mi=0;mi<4;mi++){ int row=mi*16+lr, ph=quad^(row&3); aF32[mi]=row*32+ph*8; }
    { int wr=wv*16+lr, wp=quad^(wr&3); wF32=wr*32+wp*8; }

    f4v a0[4]={}, a1[4]={};
    s8v a[2][4]; s8v a32[4];
#pragma unroll
    for (int kc=0;kc<2;kc++){
        int koff=kc*64;
        __syncthreads();
        stage<2>(H,aO64,koff,aL64,lA);
        stage<4>(W1h,wO64,koff,wL64,lW);
        __syncthreads();
        lda64(lA,aF64,a);
#pragma unroll
        for (int ks=0;ks<2;ks++) mf2h(a[ks],lW,wF64[ks],4096,a0,a1);
    }
    __syncthreads();
    stage<1>(H,aO32,128,aL32,lA);
    stage<2>(W1h,wO32,128,wL32,lW);
    __syncthreads();
    lda32(lA,aF32,a32);
    mf2h(a32,lW,wF32,2048,a0,a1);

    int c = n0 + wv*16 + lr;
    if (c < 152){
        float bb0=b1t0[c], bb1=b1t1[c];
#pragma unroll
        for (int mi=0;mi<4;mi++)
#pragma unroll
            for (int reg=0;reg<4;reg++){
                int r = m0 + mi*16 + quad*4 + reg;
                if (r >= NN) continue;
                float v0=a0[mi][reg]+bb0; v0 = v0>0.f ? v0 : 0.01f*v0;
                float v1=a1[mi][reg]+bb1; v1 = v1>0.f ? v1 : 0.01f*v1;
                if (c>=150){ v0=0.f; v1=0.f; }
                u0[(size_t)r*APIT+c]=f2h(v0);
                u1[(size_t)r*APIT+c]=f2h(v1);
            }
    }
}

// ---------------- fused GRU mega-kernel (all-fp16) ----------------
__global__ __launch_bounds__(256,3) void k_mega(const u16* __restrict__ H,
    const u16* __restrict__ U0, const u16* __restrict__ U1,
    const u16* __restrict__ Cb,   // 6 fp16 mats: [s][gate r,z,n] (deg cols 150/151 folded)
    const u16* __restrict__ Wh,   // 3 fp16 mats: Whh gates r,z,n
    const float* __restrict__ tb, u16* __restrict__ Hn)
{
    __shared__ u16 lA[64*64], lW[3*64*64];
    int tid=threadIdx.x, wv=tid>>6, lane=tid&63, lr=lane&15, quad=lane>>4;
    int m0=blockIdx.x*64, n0=blockIdx.y*64;
    int aL64[2], aO64[2];
#pragma unroll
    for (int i=0;i<2;i++){ int s=tid+i*256, row=s>>3, q8=((s&7)^(row&7))<<3;
        aL64[i]=s<<3; aO64[i]=(m0+row)*APIT+q8; }
    int aL32[1], aO32[1];
    { int s=tid, row=s>>2, q8=((s&3)^(row&3))<<3; aL32[0]=s<<3; aO32[0]=(m0+row)*APIT+q8; }
    int wL64[6], wO64[6];
#pragma unroll
    for (int i=0;i<6;i++){ int s=tid+i*256, sel=s>>9, rem=s&511, row=rem>>3, q8=((rem&7)^(row&7))<<3;
        wL64[i]=sel*4096+rem*8; wO64[i]=sel*CMAT+(n0+row)*CPIT+q8; }
    int wL32[3], wO32[3];
#pragma unroll
    for (int i=0;i<3;i++){ int s=tid+i*256, sel=s>>8, rem=s&255, row=rem>>2, q8=((rem&3)^(row&3))<<3;
        wL32[i]=sel*2048+rem*8; wO32[i]=sel*CMAT+(n0+row)*CPIT+q8; }
    int aF64[2][4], wF64[2], aF32[4], wF32;
#pragma unroll
    for (int ks=0;ks<2;ks++){
#pragma unroll
        for (int mi=0;mi<4;mi++){ int row=mi*16+lr, ph=(ks*4+quad)^(row&7); aF64[ks][mi]=row*64+ph*8; }
        int wr=wv*16+lr, wp=(ks*4+quad)^(wr&7); wF64[ks]=wr*64+wp*8;
    }
#pragma unroll
    for (int mi=0;mi<4;mi++){ int row=mi*16+lr, ph=quad^(row&3); aF32[mi]=row*32+ph*8; }
    { int wr=wv*16+lr, wp=quad^(wr&3); wF32=wr*32+wp*8; }

    f4v aR[4]={}, aZ[4]={}, aI[4]={}, aHh[4]={};

    auto dopass = [&](const u16* A, const u16* Wg, f4v (&aT)[4]){
        s8v a[2][4]; s8v a32[4];
#pragma unroll
        for (int kc=0;kc<2;kc++){
            int koff=kc*64;
            __syncthreads();
            stage<2>(A,aO64,koff,aL64,lA);
            stage<6>(Wg,wO64,koff,wL64,lW);
            __syncthreads();
            lda64(lA,aF64,a);
#pragma unroll
            for (int ks=0;ks<2;ks++) mf3h(a[ks],lW,wF64[ks],4096,aR,aZ,aT);
        }
        __syncthreads();
        stage<1>(A,aO32,128,aL32,lA);
        stage<3>(Wg,wO32,128,wL32,lW);
        __syncthreads();
        lda32(lA,aF32,a32);
        mf3h(a32,lW,wF32,2048,aR,aZ,aT);
    };
    dopass(U0, Cb,          aI);
    dopass(U1, Cb + 3*CMAT, aI);
    dopass(H,  Wh,          aHh);

    // ---- GRU epilogue ----
    int c = n0 + wv*16 + lr;
    if (c < 152){
        float bR=tb[c], bZ=tb[160+c], bI=tb[320+c], bHn=tb[480+c];
#pragma unroll
        for (int mi=0;mi<4;mi++)
#pragma unroll
            for (int reg=0;reg<4;reg++){
                int r = m0 + mi*16 + quad*4 + reg;
                if (r >= NN) continue;
                float pr=aR[mi][reg]+bR, pz=aZ[mi][reg]+bZ, pi=aI[mi][reg]+bI, ph_=aHh[mi][reg]+bHn;
                float rg = 1.f/(1.f+__expf(-pr));
                float zg = 1.f/(1.f+__expf(-pz));
                float e2 = __expf(2.f*(pi + rg*ph_));
                float n  = 1.f - 2.f/(e2+1.f);
                float hold = h2f(H[(size_t)r*APIT+c]);
                float o = (1.f-zg)*n + zg*hold;
                if (c>=150) o = 0.f;
                Hn[(size_t)r*APIT+c] = f2h(o);
            }
    }
}

// ---------------- prep kernels ----------------
__global__ void k_cast16(const float* __restrict__ src, int rowoff, u16* __restrict__ dst){
    int idx = blockIdx.x*256 + threadIdx.x;     // 192*160
    if (idx >= 192*160) return;
    int r = idx/160, c = idx - r*160;
    float x = (r<150 && c<150) ? src[(size_t)(rowoff+r)*150 + c] : 0.f;
    dst[(size_t)r*CPIT + c] = f2h(x);
}

// composite C[s*3+g] = Wih_g @ W2_s (cols 0..149); col150(s=0)/col151(s=1) = Wih_g @ b2_s ; fp16
__global__ void k_comp(const float* __restrict__ Wih, const float* __restrict__ W2_0,
                       const float* __restrict__ W2_1, const float* __restrict__ b2_0,
                       const float* __restrict__ b2_1, u16* __restrict__ Cb){
    int idx = blockIdx.x*256 + threadIdx.x;     // 6*192*160
    if (idx >= 6*192*160) return;
    int mat = idx/(192*160), rem = idx - mat*(192*160);
    int o = rem/160, c = rem - o*160;
    int s = mat/3, g = mat - s*3;
    float v = 0.f;
    if (o < 150){
        const float* wrow = Wih + (size_t)(g*150+o)*150;
        if (c < 150){
            const float* W2 = s ? W2_1 : W2_0;
            for (int j=0;j<150;j++) v += wrow[j] * W2[(size_t)j*150 + c];
        } else if (c==150 && s==0){
            for (int j=0;j<150;j++) v += wrow[j] * b2_0[j];
        } else if (c==151 && s==1){
            for (int j=0;j<150;j++) v += wrow[j] * b2_1[j];
        }
    }
    Cb[(size_t)mat*CMAT + o*CPIT + c] = f2h(v);
}

__global__ void k_tabs(const float* bih,const float* bhh,
                       const float* b1_0,const float* b1_1,
                       float* tb, float* b1t0, float* b1t1){
    int idx = blockIdx.x*256 + threadIdx.x;     // 6*160
    if (idx >= 6*160) return;
    int t = idx/160, c = idx - t*160;
    float v = 0.f;
    if (c < 150){
        if (t==0) v = bih[c]+bhh[c];
        else if (t==1) v = bih[150+c]+bhh[150+c];
        else if (t==2) v = bih[300+c];
        else if (t==3) v = bhh[300+c];
        else if (t==4) v = b1_0[c];
        else v = b1_1[c];
    }
    if (t<4) tb[t*160+c]=v;
    else if (t==4) b1t0[c]=v;
    else b1t1[c]=v;
}

__global__ void k_padfc1(const float* __restrict__ s, float* __restrict__ d){
    int idx = blockIdx.x*256 + threadIdx.x;     // 80*160
    if (idx >= 80*160) return;
    int r = idx/160, c = idx - r*160;
    d[idx] = (c<151) ? s[r*151 + c] : 0.f;
}

__global__ void k_inith(const float* __restrict__ nodes, u16* __restrict__ H){
    int idx = blockIdx.x*256 + threadIdx.x;     // NN*152
    if (idx >= NN*152) return;
    int m = idx/152, c = idx - m*152;
    float x = (c<150) ? nodes[(size_t)m*150 + c] : 0.f;
    H[(size_t)m*APIT + c] = f2h(x);
}

// ---------------- CSR build (multi-block scan; grid.y = edge set) ----------------
__global__ void k_hist2(const int* __restrict__ e0, const int* __restrict__ e1, int* __restrict__ hist){
    int e = blockIdx.x*256 + threadIdx.x;
    if (e >= EE) return;
    const int* ed = blockIdx.y ? e1 : e0;
    atomicAdd(&hist[blockIdx.y*NN + ed[2*e]], 1);
}

__global__ __launch_bounds__(256) void k_psum(const int* __restrict__ hist, int* __restrict__ part){
    int b = blockIdx.x, y = blockIdx.y, t = threadIdx.x;
    const int* cnt = hist + y*NN;
    int i0 = b*SCB + t*4;
    int s = 0;
#pragma unroll
    for (int u=0;u<4;u++){ int i=i0+u; if (i<NN) s += cnt[i]; }
#pragma unroll
    for (int o=32;o>0;o>>=1) s += __shfl_down(s,o);
    __shared__ int sd[4];
    if ((t&63)==0) sd[t>>6] = s;
    __syncthreads();
    if (t==0) part[y*128 + b] = sd[0]+sd[1]+sd[2]+sd[3];
}

__global__ __launch_bounds__(128) void k_pscan(int* __restrict__ part, int* __restrict__ off0, int* __restrict__ off1){
    int y = blockIdx.y, t = threadIdx.x;
    __shared__ int sd[128];
    int v = (t < SNB) ? part[y*128 + t] : 0;
    sd[t] = v;
    __syncthreads();
    for (int o=1;o<128;o<<=1){
        int x2 = 0;
        if (t >= o) x2 = sd[t-o];
        __syncthreads();
        if (t >= o) sd[t] += x2;
        __syncthreads();
    }
    if (t < SNB) part[y*128 + t] = sd[t] - v;     // exclusive
    if (t == 127){
        int* off = y ? off1 : off0;
        off[NN] = sd[127];                         // total = EE
    }
}

__global__ __launch_bounds__(256) void k_papply(const int* __restrict__ hist, const int* __restrict__ part,
                                                int* __restrict__ off0, int* __restrict__ off1,
                                                int* __restrict__ cur){
    int b = blockIdx.x, y = blockIdx.y, t = threadIdx.x;
    const int* cnt = hist + y*NN;
    int* off = y ? off1 : off0;
    int* cu  = cur + y*NN;
    int i0 = b*SCB + t*4;
    int v[4]; int s = 0;
#pragma unroll
    for (int u=0;u<4;u++){ int i=i0+u; v[u] = (i<NN) ? cnt[i] : 0; s += v[u]; }
    __shared__ int sd[256];
    sd[t] = s;
    __syncthreads();
    for (int o=1;o<256;o<<=1){
        int x2 = 0;
        if (t >= o) x2 = sd[t-o];
        __syncthreads();
        if (t >= o) sd[t] += x2;
        __syncthreads();
    }
    int excl = part[y*128 + b] + sd[t] - s;
#pragma unroll
    for (int u=0;u<4;u++){
        int i = i0+u;
        if (i<NN){ off[i]=excl; cu[i]=excl; excl += v[u]; }
    }
}

__global__ void k_fill2(const int* __restrict__ e0, const int* __restrict__ e1,
                        int* __restrict__ cur, int* __restrict__ csr0, int* __restrict__ csr1){
    int e = blockIdx.x*256 + threadIdx.x;
    if (e >= EE) return;
    const int* ed = blockIdx.y ? e1 : e0;
    int* csr = blockIdx.y ? csr1 : csr0;
    int dst = ed[2*e], src = ed[2*e+1];
    int pos = atomicAdd(&cur[blockIdx.y*NN + dst], 1);
    csr[pos] = src;
}

// ---------------- gather (u32 packed fp16); degree -> cols 150/151 ----------------
__global__ void k_gath2(const u16* __restrict__ u0, const u16* __restrict__ u1,
                        const int* __restrict__ off0, const int* __restrict__ csr0,
                        const int* __restrict__ off1, const int* __restrict__ csr1,
                        u16* __restrict__ U0, u16* __restrict__ U1){
    int d = blockIdx.x*4 + (threadIdx.x>>6);
    if (d >= NN) return;
    int lane = threadIdx.x & 63;
    const u16* u = blockIdx.y ? u1 : u0;
    const int* off = blockIdx.y ? off1 : off0;
    const int* csr = blockIdx.y ? csr1 : csr0;
    u16* U = blockIdx.y ? U1 : U0;
    int e0 = off[d], e1 = off[d+1];
    bool tl = lane < 12;
    float s0=0.f, s1=0.f, t0=0.f, t1=0.f;
    for (int e=e0; e<e1; e++){
        const u32* r = (const u32*)(u + (size_t)csr[e]*APIT);
        u32 v = r[lane];
        s0 += h2f((u16)(v & 0xffffu));
        s1 += h2f((u16)(v >> 16));
        if (tl){
            u32 w = r[64+lane];
            t0 += h2f((u16)(w & 0xffffu));
            t1 += h2f((u16)(w >> 16));
        }
    }
    if (lane == 11){ t0 = (float)(e1-e0); t1 = t0; }   // cols 150,151 = degree
    u32* Ur = (u32*)(U + (size_t)d*APIT);
    Ur[lane] = (u32)f2h(s0) | ((u32)f2h(s1) << 16);
    if (tl) Ur[64+lane] = (u32)f2h(t0) | ((u32)f2h(t1) << 16);
}

// ---------------- segment sum (64-row chunks for latency hiding) + readout ----------------
__global__ void k_seg(const u16* __restrict__ H, const int* __restrict__ gid, float* __restrict__ g){
    int f = threadIdx.x;
    if (f >= 150) return;
    int i0 = blockIdx.x*64;
    int i1 = i0 + 64; if (i1 > NN) i1 = NN;
    float acc = 0.f;
    int cg = gid[i0];
    for (int i=i0; i<i1; i++){
        int gg = gid[i];
        if (gg != cg){ atomicAdd(&g[cg*150+f], acc); acc=0.f; cg=gg; }
        acc += h2f(H[(size_t)i*APIT + f]);
    }
    atomicAdd(&g[cg*150+f], acc);
}

__global__ void k_mlp(const float* __restrict__ g, const float* __restrict__ pt,
                      const float* __restrict__ fc1p, const float* __restrict__ fc1b,
                      const float* __restrict__ fc2W, const float* __restrict__ fc2b,
                      const float* __restrict__ fcLW, const float* __restrict__ fcLb,
                      float* __restrict__ out){
    __shared__ float X[GG][152];
    __shared__ float Y[GG][80];
    __shared__ float Z[GG][80];
    int t = threadIdx.x;
    for (int idx=t; idx<GG*152; idx+=256){
        int gi=idx/152, c=idx-gi*152;
        float v = 0.f;
        if (c < 150){
            float lg = logf(g[gi*150+c]);
            if (lg != lg) lg = 0.f;
            v = fmaxf(lg, 0.f);
        } else if (c == 150) v = pt[gi];
        X[gi][c] = v;
    }
    __syncthreads();
    for (int idx=t; idx<GG*80; idx+=256){
        int gi=idx/80, o=idx-gi*80;
        float acc = fc1b[o];
        for (int k=0;k<151;k++) acc = fmaf(X[gi][k], fc1p[o*160+k], acc);
        Y[gi][o] = acc>0.f ? acc : 0.01f*acc;
    }
    __syncthreads();
    for (int idx=t; idx<GG*80; idx+=256){
        int gi=idx/80, o=idx-gi*80;
        float acc = fc2b[o];
        for (int k=0;k<80;k++) acc = fmaf(Y[gi][k], fc2W[o*80+k], acc);
        Z[gi][o] = acc>0.f ? acc : 0.01f*acc;
    }
    __syncthreads();
    for (int idx=t; idx<GG*10; idx+=256){
        int gi=idx/10, o=idx-gi*10;
        float acc = fcLb[o];
        for (int k=0;k<80;k++) acc = fmaf(Z[gi][k], fcLW[o*80+k], acc);
        out[idx] = acc;
    }
}

// ---------------- host ----------------
extern "C" void kernel_launch(void* const* d_in, const int* in_sizes, int n_in,
                              void* d_out, int out_size, void* d_ws, size_t ws_size,
                              hipStream_t stream) {
    const float* nodes = (const float*)d_in[0];
    const float* pt    = (const float*)d_in[1];
    const float* W1_0 = (const float*)d_in[2];  const float* b1_0 = (const float*)d_in[3];
    const float* W2_0 = (const float*)d_in[4];  const float* b2_0 = (const float*)d_in[5];
    const float* W1_1 = (const float*)d_in[6];  const float* b1_1 = (const float*)d_in[7];
    const float* W2_1 = (const float*)d_in[8];  const float* b2_1 = (const float*)d_in[9];
    const float* Wih = (const float*)d_in[10];  const float* bih = (const float*)d_in[11];
    const float* Whh = (const float*)d_in[12];  const float* bhh = (const float*)d_in[13];
    const float* fc1W = (const float*)d_in[14]; const float* fc1b = (const float*)d_in[15];
    const float* fc2W = (const float*)d_in[16]; const float* fc2b = (const float*)d_in[17];
    const float* fcLW = (const float*)d_in[18]; const float* fcLb = (const float*)d_in[19];
    const int* edges0 = (const int*)d_in[20];
    const int* edges1 = (const int*)d_in[21];
    const int* gid = (const int*)d_in[22];
    float* out = (float*)d_out;

    char* p = (char*)d_ws;
    auto alloc = [&](size_t bytes){ char* r = p; p += (bytes + 255) & ~(size_t)255; return r; };
    u16* XA  = (u16*)alloc((size_t)MROW*APIT*2);
    u16* XB  = (u16*)alloc((size_t)MROW*APIT*2);
    u16* U0  = (u16*)alloc((size_t)MROW*APIT*2);
    u16* U1  = (u16*)alloc((size_t)MROW*APIT*2);
    u16* Yu1 = (u16*)alloc((size_t)MROW*APIT*2);
    u16* W1h = (u16*)alloc((size_t)2*CMAT*2);    // [set0|set1] fp16
    u16* Wh  = (u16*)alloc((size_t)3*CMAT*2);    // Whh gates r,z,n fp16
    u16* Cb  = (u16*)alloc((size_t)6*CMAT*2);    // composite fp16 (deg cols folded)
    float* tb   = (float*)alloc(4*160*4);
    float* b1t0 = (float*)alloc(160*4);
    float* b1t1 = (float*)alloc(160*4);
    float* fc1p = (float*)alloc(80*160*4);
    float* gbuf = (float*)alloc(GG*150*4);
    int* off0 = (int*)alloc((NN+1)*4);
    int* off1 = (int*)alloc((NN+1)*4);
    int* cur  = (int*)alloc((size_t)2*NN*4);
    int* hist = (int*)alloc((size_t)2*NN*4);
    int* part = (int*)alloc(2*128*4);
    int* csr0 = (int*)alloc((size_t)EE*4);
    int* csr1 = (int*)alloc((size_t)EE*4);
    (void)alloc(4096);   // tail pad for harmless last-row K-chunk overrun reads

    // ---- prep ----
    k_cast16<<<120, 256, 0, stream>>>(W1_0, 0, W1h);
    k_cast16<<<120, 256, 0, stream>>>(W1_1, 0, W1h + CMAT);
    k_cast16<<<120, 256, 0, stream>>>(Whh, 0,   Wh);
    k_cast16<<<120, 256, 0, stream>>>(Whh, 150, Wh + CMAT);
    k_cast16<<<120, 256, 0, stream>>>(Whh, 300, Wh + 2*CMAT);
    k_comp<<<(6*192*160 + 255)/256, 256, 0, stream>>>(Wih, W2_0, W2_1, b2_0, b2_1, Cb);
    k_tabs<<<4, 256, 0, stream>>>(bih, bhh, b1_0, b1_1, tb, b1t0, b1t1);
    k_padfc1<<<50, 256, 0, stream>>>(fc1W, fc1p);
    k_inith<<<(NN*152 + 255)/256, 256, 0, stream>>>(nodes, XA);

    // ---- CSR (both sets batched via grid.y) ----
    hipMemsetAsync(hist, 0, (size_t)2*NN*sizeof(int), stream);
    dim3 gE((EE+255)/256, 2), gS(SNB, 2), g1(1, 2);
    k_hist2<<<gE, 256, 0, stream>>>(edges0, edges1, hist);
    k_psum<<<gS, 256, 0, stream>>>(hist, part);
    k_pscan<<<g1, 128, 0, stream>>>(part, off0, off1);
    k_papply<<<gS, 256, 0, stream>>>(hist, part, off0, off1, cur);
    k_fill2<<<gE, 256, 0, stream>>>(edges0, edges1, cur, csr0, csr1);

    // ---- message passes ----
    u16* Hc = XA; u16* Hx = XB;
    dim3 gT(MROW/64, 3);
    dim3 gGa((NN+3)/4, 2);
    for (int ps=0; ps<4; ps++){
        u16* yu0 = Hx;   // u scratch for set0 aliases h_next; dead before mega writes Hx
        k_ugemm2<<<gT, 256, 0, stream>>>(Hc, W1h, b1t0, b1t1, yu0, Yu1);
        k_gath2<<<gGa, 256, 0, stream>>>(yu0, Yu1, off0, csr0, off1, csr1, U0, U1);
        k_mega<<<gT, 256, 0, stream>>>(Hc, U0, U1, Cb, Wh, tb, Hx);
        u16* t = Hc; Hc = Hx; Hx = t;
    }

    // ---- readout ----
    hipMemsetAsync(gbuf, 0, GG*150*sizeof(float), stream);
    k_seg<<<(NN+63)/64, 192, 0, stream>>>(Hc, gid, gbuf);
    k_mlp<<<1, 256, 0, stream>>>(gbuf, pt, fc1p, fc1b, fc2W, fc2b, fcLW, fcLb, out);
}

// Round 12
// 1230.209 us; speedup vs baseline: 2.0817x; 1.1513x over previous
//
#include <hip/hip_runtime.h>

typedef unsigned short u16;
typedef unsigned int u32;
typedef __attribute__((ext_vector_type(8))) short s8v;      // 8x16-bit
typedef __attribute__((ext_vector_type(8))) _Float16 h8v;   // 8 fp16
typedef __attribute__((ext_vector_type(4))) float f4v;      // C/D frag

#define NN 100000
#define MROW 100096
#define EE 500000
#define GG 16
#define APIT 152      // A-source row pitch (u16, fp16): H, u, U ; U cols 150/151 = degree
#define CPIT 160      // weight row pitch (u16, fp16 single-plane)
#define CMAT (192*CPIT)
#define SCB 1024      // scan elems per block
#define SNB 98        // ceil(NN/SCB)

__device__ __forceinline__ u16 f2h(float x){ union{u16 u;_Float16 f;}c; c.f=(_Float16)x; return c.u; }
__device__ __forceinline__ float h2f(u16 b){ union{u16 u;_Float16 f;}c; c.u=b; return (float)c.f; }

#define GLOAD_LDS(gp, lp) \
    __builtin_amdgcn_global_load_lds((const __attribute__((address_space(1))) void*)(gp), \
                                     (__attribute__((address_space(3))) void*)(lp), 16, 0, 0)

// ---------------- staging (coalesced, swizzled) ----------------
template<int NI>
__device__ __forceinline__ void stage(const u16* base, const int (&off)[NI], int koff,
                                      const int (&lds)[NI], u16* dst){
#pragma unroll
    for (int i=0;i<NI;i++) GLOAD_LDS(base+off[i]+koff, dst+lds[i]);
}

// ---------------- MFMA helpers (fp16): A frags in regs, W frags from LDS ----------------
__device__ __forceinline__ void mf3h(const s8v (&af)[4], const u16* lWp, int wfo, int mstr,
                                     f4v (&X)[4], f4v (&Y)[4], f4v (&Z)[4]){
    h8v w0 = *(const h8v*)(lWp+wfo);
    h8v w1 = *(const h8v*)(lWp+mstr+wfo);
    h8v w2 = *(const h8v*)(lWp+2*mstr+wfo);
#pragma unroll
    for (int mi=0;mi<4;mi++){
        X[mi]=__builtin_amdgcn_mfma_f32_16x16x32_f16(*(const h8v*)&af[mi],w0,X[mi],0,0,0);
        Y[mi]=__builtin_amdgcn_mfma_f32_16x16x32_f16(*(const h8v*)&af[mi],w1,Y[mi],0,0,0);
        Z[mi]=__builtin_amdgcn_mfma_f32_16x16x32_f16(*(const h8v*)&af[mi],w2,Z[mi],0,0,0);
    }
}
__device__ __forceinline__ void mf2h(const s8v (&af)[4], const u16* lWp, int wfo, int mstr,
                                     f4v (&X)[4], f4v (&Y)[4]){
    h8v w0 = *(const h8v*)(lWp+wfo);
    h8v w1 = *(const h8v*)(lWp+mstr+wfo);
#pragma unroll
    for (int mi=0;mi<4;mi++){
        X[mi]=__builtin_amdgcn_mfma_f32_16x16x32_f16(*(const h8v*)&af[mi],w0,X[mi],0,0,0);
        Y[mi]=__builtin_amdgcn_mfma_f32_16x16x32_f16(*(const h8v*)&af[mi],w1,Y[mi],0,0,0);
    }
}

__device__ __forceinline__ void lda64(const u16* lA_, const int (&aF)[2][4], s8v (&a)[2][4]){
#pragma unroll
    for (int ks=0;ks<2;ks++)
#pragma unroll
        for (int mi=0;mi<4;mi++) a[ks][mi] = *(const s8v*)(lA_+aF[ks][mi]);
}
__device__ __forceinline__ void lda32(const u16* lA_, const int (&aF)[4], s8v (&a)[4]){
#pragma unroll
    for (int mi=0;mi<4;mi++) a[mi] = *(const s8v*)(lA_+aF[mi]);
}

// ---------------- edge-MLP layer 1 (both sets): u_s = lrelu(h @ W1_s^T + b1_s) ----------------
__global__ __launch_bounds__(256,3) void k_ugemm2(const u16* __restrict__ H,
    const u16* __restrict__ W1h,   // 2 fp16 mats contiguous: [set0|set1]
    const float* __restrict__ b1t0, const float* __restrict__ b1t1,
    u16* __restrict__ u0, u16* __restrict__ u1)
{
    __shared__ u16 lA[64*64], lW[2*64*64];
    int tid=threadIdx.x, wv=tid>>6, lane=tid&63, lr=lane&15, quad=lane>>4;
    int m0=blockIdx.x*64, n0=blockIdx.y*64;
    int aL64[2], aO64[2];
#pragma unroll
    for (int i=0;i<2;i++){ int s=tid+i*256, row=s>>3, q8=((s&7)^(row&7))<<3;
        aL64[i]=s<<3; aO64[i]=(m0+row)*APIT+q8; }
    int aL32[1], aO32[1];
    { int s=tid, row=s>>2, q8=((s&3)^(row&3))<<3; aL32[0]=s<<3; aO32[0]=(m0+row)*APIT+q8; }
    int wL64[4], wO64[4];
#pragma unroll
    for (int i=0;i<4;i++){ int s=tid+i*256, sel=s>>9, rem=s&511, row=rem>>3, q8=((rem&7)^(row&7))<<3;
        wL64[i]=sel*4096+rem*8; wO64[i]=sel*CMAT+(n0+row)*CPIT+q8; }
    int wL32[2], wO32[2];
#pragma unroll
    for (int i=0;i<2;i++){ int s=tid+i*256, sel=s>>8, rem=s&255, row=rem>>2, q8=((rem&3)^(row&3))<<3;
        wL32[i]=sel*2048+rem*8; wO32[i]=sel*CMAT+(n0+row)*CPIT+q8; }
    int aF64[2][4], wF64[2], aF32[4], wF32;
#pragma unroll
    for (int ks=0;ks<2;ks++){
#pragma unroll
        for (int mi=0;mi<4;mi++){ int row=mi*16+lr, ph=(ks*4+quad)^(row&7); aF64[ks][mi]=row*64+ph*8; }
        int wr=wv*16+lr, wp=(ks*4+quad)^(wr&7); wF64[ks]=wr*64+wp*8;
    }
#pragma unroll
    for (int mi=0;mi<4;mi++){ int row=mi*16+lr, ph=quad^(row&3); aF32[mi]=row*32+ph*8; }
    { int wr=wv*16+lr, wp=quad^(wr&3); wF32=wr*32+wp*8; }

    f4v a0[4]={}, a1[4]={};
    s8v a[2][4]; s8v a32[4];
#pragma unroll
    for (int kc=0;kc<2;kc++){
        int koff=kc*64;
        __syncthreads();
        stage<2>(H,aO64,koff,aL64,lA);
        stage<4>(W1h,wO64,koff,wL64,lW);
        __syncthreads();
        lda64(lA,aF64,a);
#pragma unroll
        for (int ks=0;ks<2;ks++) mf2h(a[ks],lW,wF64[ks],4096,a0,a1);
    }
    __syncthreads();
    stage<1>(H,aO32,128,aL32,lA);
    stage<2>(W1h,wO32,128,wL32,lW);
    __syncthreads();
    lda32(lA,aF32,a32);
    mf2h(a32,lW,wF32,2048,a0,a1);

    int c = n0 + wv*16 + lr;
    if (c < 152){
        float bb0=b1t0[c], bb1=b1t1[c];
#pragma unroll
        for (int mi=0;mi<4;mi++)
#pragma unroll
            for (int reg=0;reg<4;reg++){
                int r = m0 + mi*16 + quad*4 + reg;
                if (r >= NN) continue;
                float v0=a0[mi][reg]+bb0; v0 = v0>0.f ? v0 : 0.01f*v0;
                float v1=a1[mi][reg]+bb1; v1 = v1>0.f ? v1 : 0.01f*v1;
                if (c>=150){ v0=0.f; v1=0.f; }
                u0[(size_t)r*APIT+c]=f2h(v0);
                u1[(size_t)r*APIT+c]=f2h(v1);
            }
    }
}

// ---------------- fused GRU mega-kernel (all-fp16) ----------------
__global__ __launch_bounds__(256,3) void k_mega(const u16* __restrict__ H,
    const u16* __restrict__ U0, const u16* __restrict__ U1,
    const u16* __restrict__ Cb,   // 6 fp16 mats: [s][gate r,z,n] (deg cols 150/151 folded)
    const u16* __restrict__ Wh,   // 3 fp16 mats: Whh gates r,z,n
    const float* __restrict__ tb, u16* __restrict__ Hn)
{
    __shared__ u16 lA[64*64], lW[3*64*64];
    int tid=threadIdx.x, wv=tid>>6, lane=tid&63, lr=lane&15, quad=lane>>4;
    int m0=blockIdx.x*64, n0=blockIdx.y*64;
    int aL64[2], aO64[2];
#pragma unroll
    for (int i=0;i<2;i++){ int s=tid+i*256, row=s>>3, q8=((s&7)^(row&7))<<3;
        aL64[i]=s<<3; aO64[i]=(m0+row)*APIT+q8; }
    int aL32[1], aO32[1];
    { int s=tid, row=s>>2, q8=((s&3)^(row&3))<<3; aL32[0]=s<<3; aO32[0]=(m0+row)*APIT+q8; }
    int wL64[6], wO64[6];
#pragma unroll
    for (int i=0;i<6;i++){ int s=tid+i*256, sel=s>>9, rem=s&511, row=rem>>3, q8=((rem&7)^(row&7))<<3;
        wL64[i]=sel*4096+rem*8; wO64[i]=sel*CMAT+(n0+row)*CPIT+q8; }
    int wL32[3], wO32[3];
#pragma unroll
    for (int i=0;i<3;i++){ int s=tid+i*256, sel=s>>8, rem=s&255, row=rem>>2, q8=((rem&3)^(row&3))<<3;
        wL32[i]=sel*2048+rem*8; wO32[i]=sel*CMAT+(n0+row)*CPIT+q8; }
    int aF64[2][4], wF64[2], aF32[4], wF32;
#pragma unroll
    for (int ks=0;ks<2;ks++){
#pragma unroll
        for (int mi=0;mi<4;mi++){ int row=mi*16+lr, ph=(ks*4+quad)^(row&7); aF64[ks][mi]=row*64+ph*8; }
        int wr=wv*16+lr, wp=(ks*4+quad)^(wr&7); wF64[ks]=wr*64+wp*8;
    }
#pragma unroll
    for (int mi=0;mi<4;mi++){ int row=mi*16+lr, ph=quad^(row&3); aF32[mi]=row*32+ph*8; }
    { int wr=wv*16+lr, wp=quad^(wr&3); wF32=wr*32+wp*8; }

    f4v aR[4]={}, aZ[4]={}, aI[4]={}, aHh[4]={};

    auto dopass = [&](const u16* A, const u16* Wg, f4v (&aT)[4]){
        s8v a[2][4]; s8v a32[4];
#pragma unroll
        for (int kc=0;kc<2;kc++){
            int koff=kc*64;
            __syncthreads();
            stage<2>(A,aO64,koff,aL64,lA);
            stage<6>(Wg,wO64,koff,wL64,lW);
            __syncthreads();
            lda64(lA,aF64,a);
#pragma unroll
            for (int ks=0;ks<2;ks++) mf3h(a[ks],lW,wF64[ks],4096,aR,aZ,aT);
        }
        __syncthreads();
        stage<1>(A,aO32,128,aL32,lA);
        stage<3>(Wg,wO32,128,wL32,lW);
        __syncthreads();
        lda32(lA,aF32,a32);
        mf3h(a32,lW,wF32,2048,aR,aZ,aT);
    };
    dopass(U0, Cb,          aI);
    dopass(U1, Cb + 3*CMAT, aI);
    dopass(H,  Wh,          aHh);

    // ---- GRU epilogue ----
    int c = n0 + wv*16 + lr;
    if (c < 152){
        float bR=tb[c], bZ=tb[160+c], bI=tb[320+c], bHn=tb[480+c];
#pragma unroll
        for (int mi=0;mi<4;mi++)
#pragma unroll
            for (int reg=0;reg<4;reg++){
                int r = m0 + mi*16 + quad*4 + reg;
                if (r >= NN) continue;
                float pr=aR[mi][reg]+bR, pz=aZ[mi][reg]+bZ, pi=aI[mi][reg]+bI, ph_=aHh[mi][reg]+bHn;
                float rg = 1.f/(1.f+__expf(-pr));
                float zg = 1.f/(1.f+__expf(-pz));
                float e2 = __expf(2.f*(pi + rg*ph_));
                float n  = 1.f - 2.f/(e2+1.f);
                float hold = h2f(H[(size_t)r*APIT+c]);
                float o = (1.f-zg)*n + zg*hold;
                if (c>=150) o = 0.f;
                Hn[(size_t)r*APIT+c] = f2h(o);
            }
    }
}

// ---------------- prep kernels ----------------
__global__ void k_cast16(const float* __restrict__ src, int rowoff, u16* __restrict__ dst){
    int idx = blockIdx.x*256 + threadIdx.x;     // 192*160
    if (idx >= 192*160) return;
    int r = idx/160, c = idx - r*160;
    float x = (r<150 && c<150) ? src[(size_t)(rowoff+r)*150 + c] : 0.f;
    dst[(size_t)r*CPIT + c] = f2h(x);
}

// composite C[s*3+g] = Wih_g @ W2_s (cols 0..149); col150(s=0)/col151(s=1) = Wih_g @ b2_s ; fp16
__global__ void k_comp(const float* __restrict__ Wih, const float* __restrict__ W2_0,
                       const float* __restrict__ W2_1, const float* __restrict__ b2_0,
                       const float* __restrict__ b2_1, u16* __restrict__ Cb){
    int idx = blockIdx.x*256 + threadIdx.x;     // 6*192*160
    if (idx >= 6*192*160) return;
    int mat = idx/(192*160), rem = idx - mat*(192*160);
    int o = rem/160, c = rem - o*160;
    int s = mat/3, g = mat - s*3;
    float v = 0.f;
    if (o < 150){
        const float* wrow = Wih + (size_t)(g*150+o)*150;
        if (c < 150){
            const float* W2 = s ? W2_1 : W2_0;
            for (int j=0;j<150;j++) v += wrow[j] * W2[(size_t)j*150 + c];
        } else if (c==150 && s==0){
            for (int j=0;j<150;j++) v += wrow[j] * b2_0[j];
        } else if (c==151 && s==1){
            for (int j=0;j<150;j++) v += wrow[j] * b2_1[j];
        }
    }
    Cb[(size_t)mat*CMAT + o*CPIT + c] = f2h(v);
}

__global__ void k_tabs(const float* bih,const float* bhh,
                       const float* b1_0,const float* b1_1,
                       float* tb, float* b1t0, float* b1t1){
    int idx = blockIdx.x*256 + threadIdx.x;     // 6*160
    if (idx >= 6*160) return;
    int t = idx/160, c = idx - t*160;
    float v = 0.f;
    if (c < 150){
        if (t==0) v = bih[c]+bhh[c];
        else if (t==1) v = bih[150+c]+bhh[150+c];
        else if (t==2) v = bih[300+c];
        else if (t==3) v = bhh[300+c];
        else if (t==4) v = b1_0[c];
        else v = b1_1[c];
    }
    if (t<4) tb[t*160+c]=v;
    else if (t==4) b1t0[c]=v;
    else b1t1[c]=v;
}

__global__ void k_padfc1(const float* __restrict__ s, float* __restrict__ d){
    int idx = blockIdx.x*256 + threadIdx.x;     // 80*160
    if (idx >= 80*160) return;
    int r = idx/160, c = idx - r*160;
    d[idx] = (c<151) ? s[r*151 + c] : 0.f;
}

__global__ void k_inith(const float* __restrict__ nodes, u16* __restrict__ H){
    int idx = blockIdx.x*256 + threadIdx.x;     // NN*152
    if (idx >= NN*152) return;
    int m = idx/152, c = idx - m*152;
    float x = (c<150) ? nodes[(size_t)m*150 + c] : 0.f;
    H[(size_t)m*APIT + c] = f2h(x);
}

// ---------------- CSR build (multi-block scan; grid.y = edge set) ----------------
__global__ void k_hist2(const int* __restrict__ e0, const int* __restrict__ e1, int* __restrict__ hist){
    int e = blockIdx.x*256 + threadIdx.x;
    if (e >= EE) return;
    const int* ed = blockIdx.y ? e1 : e0;
    atomicAdd(&hist[blockIdx.y*NN + ed[2*e]], 1);
}

__global__ __launch_bounds__(256) void k_psum(const int* __restrict__ hist, int* __restrict__ part){
    int b = blockIdx.x, y = blockIdx.y, t = threadIdx.x;
    const int* cnt = hist + y*NN;
    int i0 = b*SCB + t*4;
    int s = 0;
#pragma unroll
    for (int u=0;u<4;u++){ int i=i0+u; if (i<NN) s += cnt[i]; }
#pragma unroll
    for (int o=32;o>0;o>>=1) s += __shfl_down(s,o);
    __shared__ int sd[4];
    if ((t&63)==0) sd[t>>6] = s;
    __syncthreads();
    if (t==0) part[y*128 + b] = sd[0]+sd[1]+sd[2]+sd[3];
}

__global__ __launch_bounds__(128) void k_pscan(int* __restrict__ part, int* __restrict__ off0, int* __restrict__ off1){
    int y = blockIdx.y, t = threadIdx.x;
    __shared__ int sd[128];
    int v = (t < SNB) ? part[y*128 + t] : 0;
    sd[t] = v;
    __syncthreads();
    for (int o=1;o<128;o<<=1){
        int x2 = 0;
        if (t >= o) x2 = sd[t-o];
        __syncthreads();
        if (t >= o) sd[t] += x2;
        __syncthreads();
    }
    if (t < SNB) part[y*128 + t] = sd[t] - v;     // exclusive
    if (t == 127){
        int* off = y ? off1 : off0;
        off[NN] = sd[127];                         // total = EE
    }
}

__global__ __launch_bounds__(256) void k_papply(const int* __restrict__ hist, const int* __restrict__ part,
                                                int* __restrict__ off0, int* __restrict__ off1,
                                                int* __restrict__ cur){
    int b = blockIdx.x, y = blockIdx.y, t = threadIdx.x;
    const int* cnt = hist + y*NN;
    int* off = y ? off1 : off0;
    int* cu  = cur + y*NN;
    int i0 = b*SCB + t*4;
    int v[4]; int s = 0;
#pragma unroll
    for (int u=0;u<4;u++){ int i=i0+u; v[u] = (i<NN) ? cnt[i] : 0; s += v[u]; }
    __shared__ int sd[256];
    sd[t] = s;
    __syncthreads();
    for (int o=1;o<256;o<<=1){
        int x2 = 0;
        if (t >= o) x2 = sd[t-o];
        __syncthreads();
        if (t >= o) sd[t] += x2;
        __syncthreads();
    }
    int excl = part[y*128 + b] + sd[t] - s;
#pragma unroll
    for (int u=0;u<4;u++){
        int i = i0+u;
        if (i<NN){ off[i]=excl; cu[i]=excl; excl += v[u]; }
    }
}

__global__ void k_fill2(const int* __restrict__ e0, const int* __restrict__ e1,
                        int* __restrict__ cur, int* __restrict__ csr0, int* __restrict__ csr1){
    int e = blockIdx.x*256 + threadIdx.x;
    if (e >= EE) return;
    const int* ed = blockIdx.y ? e1 : e0;
    int* csr = blockIdx.y ? csr1 : csr0;
    int dst = ed[2*e], src = ed[2*e+1];
    int pos = atomicAdd(&cur[blockIdx.y*NN + dst], 1);
    csr[pos] = src;
}

// ---------------- gather (unroll-4 for MLP); degree -> cols 150/151 ----------------
__global__ void k_gath2(const u16* __restrict__ u0, const u16* __restrict__ u1,
                        const int* __restrict__ off0, const int* __restrict__ csr0,
                        const int* __restrict__ off1, const int* __restrict__ csr1,
                        u16* __restrict__ U0, u16* __restrict__ U1){
    int d = blockIdx.x*4 + (threadIdx.x>>6);
    if (d >= NN) return;
    int lane = threadIdx.x & 63;
    const u16* u = blockIdx.y ? u1 : u0;
    const int* off = blockIdx.y ? off1 : off0;
    const int* csr = blockIdx.y ? csr1 : csr0;
    u16* U = blockIdx.y ? U1 : U0;
    int e0 = off[d], e1 = off[d+1];
    bool tl = lane < 12;
    float s0=0.f, s1=0.f, t0=0.f, t1=0.f;
    int e = e0;
    for (; e+4 <= e1; e += 4){
        const u32* r0 = (const u32*)(u + (size_t)csr[e]  *APIT);
        const u32* r1 = (const u32*)(u + (size_t)csr[e+1]*APIT);
        const u32* r2 = (const u32*)(u + (size_t)csr[e+2]*APIT);
        const u32* r3 = (const u32*)(u + (size_t)csr[e+3]*APIT);
        u32 v0=r0[lane], v1=r1[lane], v2=r2[lane], v3=r3[lane];
        u32 w0=0, w1=0, w2=0, w3=0;
        if (tl){ w0=r0[64+lane]; w1=r1[64+lane]; w2=r2[64+lane]; w3=r3[64+lane]; }
        s0 += h2f((u16)(v0&0xffffu)) + h2f((u16)(v1&0xffffu)) + h2f((u16)(v2&0xffffu)) + h2f((u16)(v3&0xffffu));
        s1 += h2f((u16)(v0>>16))     + h2f((u16)(v1>>16))     + h2f((u16)(v2>>16))     + h2f((u16)(v3>>16));
        if (tl){
            t0 += h2f((u16)(w0&0xffffu)) + h2f((u16)(w1&0xffffu)) + h2f((u16)(w2&0xffffu)) + h2f((u16)(w3&0xffffu));
            t1 += h2f((u16)(w0>>16))     + h2f((u16)(w1>>16))     + h2f((u16)(w2>>16))     + h2f((u16)(w3>>16));
        }
    }
    for (; e < e1; e++){
        const u32* r = (const u32*)(u + (size_t)csr[e]*APIT);
        u32 v = r[lane];
        s0 += h2f((u16)(v & 0xffffu));
        s1 += h2f((u16)(v >> 16));
        if (tl){
            u32 w = r[64+lane];
            t0 += h2f((u16)(w & 0xffffu));
            t1 += h2f((u16)(w >> 16));
        }
    }
    if (lane == 11){ t0 = (float)(e1-e0); t1 = t0; }   // cols 150,151 = degree
    u32* Ur = (u32*)(U + (size_t)d*APIT);
    Ur[lane] = (u32)f2h(s0) | ((u32)f2h(s1) << 16);
    if (tl) Ur[64+lane] = (u32)f2h(t0) | ((u32)f2h(t1) << 16);
}

// ---------------- segment sum (64-row chunks for latency hiding) + readout ----------------
__global__ void k_seg(const u16* __restrict__ H, const int* __restrict__ gid, float* __restrict__ g){
    int f = threadIdx.x;
    if (f >= 150) return;
    int i0 = blockIdx.x*64;
    int i1 = i0 + 64; if (i1 > NN) i1 = NN;
    float acc = 0.f;
    int cg = gid[i0];
    for (int i=i0; i<i1; i++){
        int gg = gid[i];
        if (gg != cg){ atomicAdd(&g[cg*150+f], acc); acc=0.f; cg=gg; }
        acc += h2f(H[(size_t)i*APIT + f]);
    }
    atomicAdd(&g[cg*150+f], acc);
}

__global__ void k_mlp(const float* __restrict__ g, const float* __restrict__ pt,
                      const float* __restrict__ fc1p, const float* __restrict__ fc1b,
                      const float* __restrict__ fc2W, const float* __restrict__ fc2b,
                      const float* __restrict__ fcLW, const float* __restrict__ fcLb,
                      float* __restrict__ out){
    __shared__ float X[GG][152];
    __shared__ float Y[GG][80];
    __shared__ float Z[GG][80];
    int t = threadIdx.x;
    for (int idx=t; idx<GG*152; idx+=256){
        int gi=idx/152, c=idx-gi*152;
        float v = 0.f;
        if (c < 150){
            float lg = logf(g[gi*150+c]);
            if (lg != lg) lg = 0.f;
            v = fmaxf(lg, 0.f);
        } else if (c == 150) v = pt[gi];
        X[gi][c] = v;
    }
    __syncthreads();
    for (int idx=t; idx<GG*80; idx+=256){
        int gi=idx/80, o=idx-gi*80;
        float acc = fc1b[o];
        for (int k=0;k<151;k++) acc = fmaf(X[gi][k], fc1p[o*160+k], acc);
        Y[gi][o] = acc>0.f ? acc : 0.01f*acc;
    }
    __syncthreads();
    for (int idx=t; idx<GG*80; idx+=256){
        int gi=idx/80, o=idx-gi*80;
        float acc = fc2b[o];
        for (int k=0;k<80;k++) acc = fmaf(Y[gi][k], fc2W[o*80+k], acc);
        Z[gi][o] = acc>0.f ? acc : 0.01f*acc;
    }
    __syncthreads();
    for (int idx=t; idx<GG*10; idx+=256){
        int gi=idx/10, o=idx-gi*10;
        float acc = fcLb[o];
        for (int k=0;k<80;k++) acc = fmaf(Z[gi][k], fcLW[o*80+k], acc);
        out[idx] = acc;
    }
}

// ---------------- host ----------------
extern "C" void kernel_launch(void* const* d_in, const int* in_sizes, int n_in,
                              void* d_out, int out_size, void* d_ws, size_t ws_size,
                              hipStream_t stream) {
    const float* nodes = (const float*)d_in[0];
    const float* pt    = (const float*)d_in[1];
    const float* W1_0 = (const float*)d_in[2];  const float* b1_0 = (const float*)d_in[3];
    const float* W2_0 = (const float*)d_in[4];  const float* b2_0 = (const float*)d_in[5];
    const float* W1_1 = (const float*)d_in[6];  const float* b1_1 = (const float*)d_in[7];
    const float* W2_1 = (const float*)d_in[8];  const float* b2_1 = (const float*)d_in[9];
    const float* Wih = (const float*)d_in[10];  const float* bih = (const float*)d_in[11];
    const float* Whh = (const float*)d_in[12];  const float* bhh = (const float*)d_in[13];
    const float* fc1W = (const float*)d_in[14]; const float* fc1b = (const float*)d_in[15];
    const float* fc2W = (const float*)d_in[16]; const float* fc2b = (const float*)d_in[17];
    const float* fcLW = (const float*)d_in[18]; const float* fcLb = (const float*)d_in[19];
    const int* edges0 = (const int*)d_in[20];
    const int* edges1 = (const int*)d_in[21];
    const int* gid = (const int*)d_in[22];
    float* out = (float*)d_out;

    char* p = (char*)d_ws;
    auto alloc = [&](size_t bytes){ char* r = p; p += (bytes + 255) & ~(size_t)255; return r; };
    u16* XA  = (u16*)alloc((size_t)MROW*APIT*2);
    u16* XB  = (u16*)alloc((size_t)MROW*APIT*2);
    u16* U0  = (u16*)alloc((size_t)MROW*APIT*2);
    u16* U1  = (u16*)alloc((size_t)MROW*APIT*2);
    u16* Yu1 = (u16*)alloc((size_t)MROW*APIT*2);
    u16* W1h = (u16*)alloc((size_t)2*CMAT*2);    // [set0|set1] fp16
    u16* Wh  = (u16*)alloc((size_t)3*CMAT*2);    // Whh gates r,z,n fp16
    u16* Cb  = (u16*)alloc((size_t)6*CMAT*2);    // composite fp16 (deg cols folded)
    float* tb   = (float*)alloc(4*160*4);
    float* b1t0 = (float*)alloc(160*4);
    float* b1t1 = (float*)alloc(160*4);
    float* fc1p = (float*)alloc(80*160*4);
    float* gbuf = (float*)alloc(GG*150*4);
    int* off0 = (int*)alloc((NN+1)*4);
    int* off1 = (int*)alloc((NN+1)*4);
    int* cur  = (int*)alloc((size_t)2*NN*4);
    int* hist = (int*)alloc((size_t)2*NN*4);
    int* part = (int*)alloc(2*128*4);
    int* csr0 = (int*)alloc((size_t)EE*4);
    int* csr1 = (int*)alloc((size_t)EE*4);
    (void)alloc(4096);   // tail pad for harmless last-row K-chunk overrun reads

    // ---- prep ----
    k_cast16<<<120, 256, 0, stream>>>(W1_0, 0, W1h);
    k_cast16<<<120, 256, 0, stream>>>(W1_1, 0, W1h + CMAT);
    k_cast16<<<120, 256, 0, stream>>>(Whh, 0,   Wh);
    k_cast16<<<120, 256, 0, stream>>>(Whh, 150, Wh + CMAT);
    k_cast16<<<120, 256, 0, stream>>>(Whh, 300, Wh + 2*CMAT);
    k_comp<<<(6*192*160 + 255)/256, 256, 0, stream>>>(Wih, W2_0, W2_1, b2_0, b2_1, Cb);
    k_tabs<<<4, 256, 0, stream>>>(bih, bhh, b1_0, b1_1, tb, b1t0, b1t1);
    k_padfc1<<<50, 256, 0, stream>>>(fc1W, fc1p);
    k_inith<<<(NN*152 + 255)/256, 256, 0, stream>>>(nodes, XA);

    // ---- CSR (both sets batched via grid.y) ----
    hipMemsetAsync(hist, 0, (size_t)2*NN*sizeof(int), stream);
    dim3 gE((EE+255)/256, 2), gS(SNB, 2), g1(1, 2);
    k_hist2<<<gE, 256, 0, stream>>>(edges0, edges1, hist);
    k_psum<<<gS, 256, 0, stream>>>(hist, part);
    k_pscan<<<g1, 128, 0, stream>>>(part, off0, off1);
    k_papply<<<gS, 256, 0, stream>>>(hist, part, off0, off1, cur);
    k_fill2<<<gE, 256, 0, stream>>>(edges0, edges1, cur, csr0, csr1);

    // ---- message passes ----
    u16* Hc = XA; u16* Hx = XB;
    dim3 gT(MROW/64, 3);
    dim3 gGa((NN+3)/4, 2);
    for (int ps=0; ps<4; ps++){
        u16* yu0 = Hx;   // u scratch for set0 aliases h_next; dead before mega writes Hx
        k_ugemm2<<<gT, 256, 0, stream>>>(Hc, W1h, b1t0, b1t1, yu0, Yu1);
        k_gath2<<<gGa, 256, 0, stream>>>(yu0, Yu1, off0, csr0, off1, csr1, U0, U1);
        k_mega<<<gT, 256, 0, stream>>>(Hc, U0, U1, Cb, Wh, tb, Hx);
        u16* t = Hc; Hc = Hx; Hx = t;
    }

    // ---- readout ----
    hipMemsetAsync(gbuf, 0, GG*150*sizeof(float), stream);
    k_seg<<<(NN+63)/64, 192, 0, stream>>>(Hc, gid, gbuf);
    k_mlp<<<1, 256, 0, stream>>>(gbuf, pt, fc1p, fc1b, fc2W, fc2b, fcLW, fcLb, out);
}

// Round 13
// 1198.166 us; speedup vs baseline: 2.1374x; 1.0267x over previous
//
#include <hip/hip_runtime.h>

typedef unsigned short u16;
typedef unsigned int u32;
typedef __attribute__((ext_vector_type(8))) short s8v;      // 8x16-bit
typedef __attribute__((ext_vector_type(8))) _Float16 h8v;   // 8 fp16
typedef __attribute__((ext_vector_type(4))) float f4v;      // C/D frag

#define NN 100000
#define MROW 100096
#define EE 500000
#define GG 16
#define APIT 152      // A-source row pitch (u16, fp16): H, u, U ; U cols 150/151 = degree
#define WFM 30720     // frag-order weight mat size (u16) = 192 rows x 160 k
#define SCB 1024      // scan elems per block
#define SNB 98        // ceil(NN/SCB)

__device__ __forceinline__ u16 f2h(float x){ union{u16 u;_Float16 f;}c; c.f=(_Float16)x; return c.u; }
__device__ __forceinline__ float h2f(u16 b){ union{u16 u;_Float16 f;}c; c.u=b; return (float)c.f; }

#define GLOAD_LDS(gp, lp) \
    __builtin_amdgcn_global_load_lds((const __attribute__((address_space(1))) void*)(gp), \
                                     (__attribute__((address_space(3))) void*)(lp), 16, 0, 0)

// frag-order weight index: mat-local. row<192, k<160.
// chunk = (row>>4)*5 + (k>>5); lane = ((k>>3)&3)*16 + (row&15); elem = chunk*512 + lane*8 + (k&7)
__device__ __forceinline__ size_t widx(int row, int k){
    return (size_t)(((row>>4)*5 + (k>>5))*512) + ((((k>>3)&3)*16 + (row&15))*8) + (k&7);
}

// ---------------- staging (coalesced, swizzled) ----------------
template<int NI>
__device__ __forceinline__ void stage(const u16* base, const int (&off)[NI], int koff,
                                      const int (&lds)[NI], u16* dst){
#pragma unroll
    for (int i=0;i<NI;i++) GLOAD_LDS(base+off[i]+koff, dst+lds[i]);
}

__device__ __forceinline__ void lda64(const u16* lA_, const int (&aF)[2][4], s8v (&a)[2][4]){
#pragma unroll
    for (int ks=0;ks<2;ks++)
#pragma unroll
        for (int mi=0;mi<4;mi++) a[ks][mi] = *(const s8v*)(lA_+aF[ks][mi]);
}
__device__ __forceinline__ void lda32(const u16* lA_, const int (&aF)[4], s8v (&a)[4]){
#pragma unroll
    for (int mi=0;mi<4;mi++) a[mi] = *(const s8v*)(lA_+aF[mi]);
}

// direct frag-order W loads + MFMA
__device__ __forceinline__ void mf3d(const s8v (&af)[4], const u16* wp,
                                     f4v (&X)[4], f4v (&Y)[4], f4v (&Z)[4]){
    h8v w0 = *(const h8v*)(wp);
    h8v w1 = *(const h8v*)(wp + WFM);
    h8v w2 = *(const h8v*)(wp + 2*WFM);
#pragma unroll
    for (int mi=0;mi<4;mi++){
        X[mi]=__builtin_amdgcn_mfma_f32_16x16x32_f16(*(const h8v*)&af[mi],w0,X[mi],0,0,0);
        Y[mi]=__builtin_amdgcn_mfma_f32_16x16x32_f16(*(const h8v*)&af[mi],w1,Y[mi],0,0,0);
        Z[mi]=__builtin_amdgcn_mfma_f32_16x16x32_f16(*(const h8v*)&af[mi],w2,Z[mi],0,0,0);
    }
}
__device__ __forceinline__ void mf2d(const s8v (&af)[4], const u16* wp,
                                     f4v (&X)[4], f4v (&Y)[4]){
    h8v w0 = *(const h8v*)(wp);
    h8v w1 = *(const h8v*)(wp + WFM);
#pragma unroll
    for (int mi=0;mi<4;mi++){
        X[mi]=__builtin_amdgcn_mfma_f32_16x16x32_f16(*(const h8v*)&af[mi],w0,X[mi],0,0,0);
        Y[mi]=__builtin_amdgcn_mfma_f32_16x16x32_f16(*(const h8v*)&af[mi],w1,Y[mi],0,0,0);
    }
}

// ---------------- edge-MLP layer 1 (both sets): u_s = lrelu(h @ W1_s^T + b1_s) ----------------
__global__ __launch_bounds__(256,3) void k_ugemm2(const u16* __restrict__ H,
    const u16* __restrict__ W1f,   // 2 frag-order fp16 mats: [set0|set1]
    const float* __restrict__ b1t0, const float* __restrict__ b1t1,
    u16* __restrict__ u0, u16* __restrict__ u1)
{
    __shared__ u16 lA[64*64];
    int tid=threadIdx.x, wv=tid>>6, lane=tid&63, lr=lane&15, quad=lane>>4;
    int m0=blockIdx.x*64, n0=blockIdx.y*64;
    int aL64[2], aO64[2];
#pragma unroll
    for (int i=0;i<2;i++){ int s=tid+i*256, row=s>>3, q8=((s&7)^(row&7))<<3;
        aL64[i]=s<<3; aO64[i]=(m0+row)*APIT+q8; }
    int aL32[1], aO32[1];
    { int s=tid, row=s>>2, q8=((s&3)^(row&3))<<3; aL32[0]=s<<3; aO32[0]=(m0+row)*APIT+q8; }
    int aF64[2][4], aF32[4];
#pragma unroll
    for (int ks=0;ks<2;ks++)
#pragma unroll
        for (int mi=0;mi<4;mi++){ int row=mi*16+lr, ph=(ks*4+quad)^(row&7); aF64[ks][mi]=row*64+ph*8; }
#pragma unroll
    for (int mi=0;mi<4;mi++){ int row=mi*16+lr, ph=quad^(row&3); aF32[mi]=row*32+ph*8; }
    int jw = blockIdx.y*4 + wv;                         // 16-row weight chunk this wave owns
    const u16* Wp = W1f + (size_t)(jw*5)*512 + lane*8;  // +q*512 per 32-k chunk; +WFM per mat

    f4v a0[4]={}, a1[4]={};
    s8v a[2][4]; s8v a32[4];
#pragma unroll
    for (int kc=0;kc<2;kc++){
        int koff=kc*64;
        __syncthreads();
        stage<2>(H,aO64,koff,aL64,lA);
        __syncthreads();
        lda64(lA,aF64,a);
#pragma unroll
        for (int ks=0;ks<2;ks++) mf2d(a[ks], Wp + (kc*2+ks)*512, a0,a1);
    }
    __syncthreads();
    stage<1>(H,aO32,128,aL32,lA);
    __syncthreads();
    lda32(lA,aF32,a32);
    mf2d(a32, Wp + 4*512, a0,a1);

    int c = n0 + wv*16 + lr;
    if (c < 152){
        float bb0=b1t0[c], bb1=b1t1[c];
#pragma unroll
        for (int mi=0;mi<4;mi++)
#pragma unroll
            for (int reg=0;reg<4;reg++){
                int r = m0 + mi*16 + quad*4 + reg;
                if (r >= NN) continue;
                float v0=a0[mi][reg]+bb0; v0 = v0>0.f ? v0 : 0.01f*v0;
                float v1=a1[mi][reg]+bb1; v1 = v1>0.f ? v1 : 0.01f*v1;
                if (c>=150){ v0=0.f; v1=0.f; }
                u0[(size_t)r*APIT+c]=f2h(v0);
                u1[(size_t)r*APIT+c]=f2h(v1);
            }
    }
}

// ---------------- fused GRU mega-kernel (all-fp16, direct frag-order W) ----------------
__global__ __launch_bounds__(256,3) void k_mega(const u16* __restrict__ H,
    const u16* __restrict__ U0, const u16* __restrict__ U1,
    const u16* __restrict__ Cf,   // 6 frag-order mats: [s][gate r,z,n] (deg cols folded)
    const u16* __restrict__ Whf,  // 3 frag-order mats: Whh gates r,z,n
    const float* __restrict__ tb, u16* __restrict__ Hn)
{
    __shared__ u16 lA[64*64];
    int tid=threadIdx.x, wv=tid>>6, lane=tid&63, lr=lane&15, quad=lane>>4;
    int m0=blockIdx.x*64, n0=blockIdx.y*64;
    int aL64[2], aO64[2];
#pragma unroll
    for (int i=0;i<2;i++){ int s=tid+i*256, row=s>>3, q8=((s&7)^(row&7))<<3;
        aL64[i]=s<<3; aO64[i]=(m0+row)*APIT+q8; }
    int aL32[1], aO32[1];
    { int s=tid, row=s>>2, q8=((s&3)^(row&3))<<3; aL32[0]=s<<3; aO32[0]=(m0+row)*APIT+q8; }
    int aF64[2][4], aF32[4];
#pragma unroll
    for (int ks=0;ks<2;ks++)
#pragma unroll
        for (int mi=0;mi<4;mi++){ int row=mi*16+lr, ph=(ks*4+quad)^(row&7); aF64[ks][mi]=row*64+ph*8; }
#pragma unroll
    for (int mi=0;mi<4;mi++){ int row=mi*16+lr, ph=quad^(row&3); aF32[mi]=row*32+ph*8; }
    int jw = blockIdx.y*4 + wv;
    int laneoff = lane*8;

    f4v aR[4]={}, aZ[4]={}, aI[4]={}, aHh[4]={};

    auto dopass = [&](const u16* A, const u16* Wg, f4v (&aT)[4]){
        const u16* Wp = Wg + (size_t)(jw*5)*512 + laneoff;
        s8v a[2][4]; s8v a32[4];
#pragma unroll
        for (int kc=0;kc<2;kc++){
            int koff=kc*64;
            __syncthreads();
            stage<2>(A,aO64,koff,aL64,lA);
            __syncthreads();
            lda64(lA,aF64,a);
#pragma unroll
            for (int ks=0;ks<2;ks++) mf3d(a[ks], Wp + (kc*2+ks)*512, aR,aZ,aT);
        }
        __syncthreads();
        stage<1>(A,aO32,128,aL32,lA);
        __syncthreads();
        lda32(lA,aF32,a32);
        mf3d(a32, Wp + 4*512, aR,aZ,aT);
    };
    dopass(U0, Cf,          aI);
    dopass(U1, Cf + 3*WFM,  aI);
    dopass(H,  Whf,         aHh);

    // ---- GRU epilogue ----
    int c = n0 + wv*16 + lr;
    if (c < 152){
        float bR=tb[c], bZ=tb[160+c], bI=tb[320+c], bHn=tb[480+c];
#pragma unroll
        for (int mi=0;mi<4;mi++)
#pragma unroll
            for (int reg=0;reg<4;reg++){
                int r = m0 + mi*16 + quad*4 + reg;
                if (r >= NN) continue;
                float pr=aR[mi][reg]+bR, pz=aZ[mi][reg]+bZ, pi=aI[mi][reg]+bI, ph_=aHh[mi][reg]+bHn;
                float rg = 1.f/(1.f+__expf(-pr));
                float zg = 1.f/(1.f+__expf(-pz));
                float e2 = __expf(2.f*(pi + rg*ph_));
                float n  = 1.f - 2.f/(e2+1.f);
                float hold = h2f(H[(size_t)r*APIT+c]);
                float o = (1.f-zg)*n + zg*hold;
                if (c>=150) o = 0.f;
                Hn[(size_t)r*APIT+c] = f2h(o);
            }
    }
}

// ---------------- prep kernels (write frag-order) ----------------
__global__ void k_cast16(const float* __restrict__ src, int rowoff, u16* __restrict__ dst){
    int idx = blockIdx.x*256 + threadIdx.x;     // 192*160
    if (idx >= 192*160) return;
    int r = idx/160, c = idx - r*160;
    float x = (r<150 && c<150) ? src[(size_t)(rowoff+r)*150 + c] : 0.f;
    dst[widx(r,c)] = f2h(x);
}

// composite C[s*3+g] = Wih_g @ W2_s (cols 0..149); col150(s=0)/col151(s=1) = Wih_g @ b2_s ; fp16
__global__ void k_comp(const float* __restrict__ Wih, const float* __restrict__ W2_0,
                       const float* __restrict__ W2_1, const float* __restrict__ b2_0,
                       const float* __restrict__ b2_1, u16* __restrict__ Cf){
    int idx = blockIdx.x*256 + threadIdx.x;     // 6*192*160
    if (idx >= 6*192*160) return;
    int mat = idx/(192*160), rem = idx - mat*(192*160);
    int o = rem/160, c = rem - o*160;
    int s = mat/3, g = mat - s*3;
    float v = 0.f;
    if (o < 150){
        const float* wrow = Wih + (size_t)(g*150+o)*150;
        if (c < 150){
            const float* W2 = s ? W2_1 : W2_0;
            for (int j=0;j<150;j++) v += wrow[j] * W2[(size_t)j*150 + c];
        } else if (c==150 && s==0){
            for (int j=0;j<150;j++) v += wrow[j] * b2_0[j];
        } else if (c==151 && s==1){
            for (int j=0;j<150;j++) v += wrow[j] * b2_1[j];
        }
    }
    Cf[(size_t)mat*WFM + widx(o,c)] = f2h(v);
}

__global__ void k_tabs(const float* bih,const float* bhh,
                       const float* b1_0,const float* b1_1,
                       float* tb, float* b1t0, float* b1t1){
    int idx = blockIdx.x*256 + threadIdx.x;     // 6*160
    if (idx >= 6*160) return;
    int t = idx/160, c = idx - t*160;
    float v = 0.f;
    if (c < 150){
        if (t==0) v = bih[c]+bhh[c];
        else if (t==1) v = bih[150+c]+bhh[150+c];
        else if (t==2) v = bih[300+c];
        else if (t==3) v = bhh[300+c];
        else if (t==4) v = b1_0[c];
        else v = b1_1[c];
    }
    if (t<4) tb[t*160+c]=v;
    else if (t==4) b1t0[c]=v;
    else b1t1[c]=v;
}

__global__ void k_padfc1(const float* __restrict__ s, float* __restrict__ d){
    int idx = blockIdx.x*256 + threadIdx.x;     // 80*160
    if (idx >= 80*160) return;
    int r = idx/160, c = idx - r*160;
    d[idx] = (c<151) ? s[r*151 + c] : 0.f;
}

__global__ void k_inith(const float* __restrict__ nodes, u16* __restrict__ H){
    int idx = blockIdx.x*256 + threadIdx.x;     // NN*152
    if (idx >= NN*152) return;
    int m = idx/152, c = idx - m*152;
    float x = (c<150) ? nodes[(size_t)m*150 + c] : 0.f;
    H[(size_t)m*APIT + c] = f2h(x);
}

// ---------------- CSR build (multi-block scan; grid.y = edge set) ----------------
__global__ void k_hist2(const int* __restrict__ e0, const int* __restrict__ e1, int* __restrict__ hist){
    int e = blockIdx.x*256 + threadIdx.x;
    if (e >= EE) return;
    const int* ed = blockIdx.y ? e1 : e0;
    atomicAdd(&hist[blockIdx.y*NN + ed[2*e]], 1);
}

__global__ __launch_bounds__(256) void k_psum(const int* __restrict__ hist, int* __restrict__ part){
    int b = blockIdx.x, y = blockIdx.y, t = threadIdx.x;
    const int* cnt = hist + y*NN;
    int i0 = b*SCB + t*4;
    int s = 0;
#pragma unroll
    for (int u=0;u<4;u++){ int i=i0+u; if (i<NN) s += cnt[i]; }
#pragma unroll
    for (int o=32;o>0;o>>=1) s += __shfl_down(s,o);
    __shared__ int sd[4];
    if ((t&63)==0) sd[t>>6] = s;
    __syncthreads();
    if (t==0) part[y*128 + b] = sd[0]+sd[1]+sd[2]+sd[3];
}

__global__ __launch_bounds__(128) void k_pscan(int* __restrict__ part, int* __restrict__ off0, int* __restrict__ off1){
    int y = blockIdx.y, t = threadIdx.x;
    __shared__ int sd[128];
    int v = (t < SNB) ? part[y*128 + t] : 0;
    sd[t] = v;
    __syncthreads();
    for (int o=1;o<128;o<<=1){
        int x2 = 0;
        if (t >= o) x2 = sd[t-o];
        __syncthreads();
        if (t >= o) sd[t] += x2;
        __syncthreads();
    }
    if (t < SNB) part[y*128 + t] = sd[t] - v;     // exclusive
    if (t == 127){
        int* off = y ? off1 : off0;
        off[NN] = sd[127];                         // total = EE
    }
}

__global__ __launch_bounds__(256) void k_papply(const int* __restrict__ hist, const int* __restrict__ part,
                                                int* __restrict__ off0, int* __restrict__ off1,
                                                int* __restrict__ cur){
    int b = blockIdx.x, y = blockIdx.y, t = threadIdx.x;
    const int* cnt = hist + y*NN;
    int* off = y ? off1 : off0;
    int* cu  = cur + y*NN;
    int i0 = b*SCB + t*4;
    int v[4]; int s = 0;
#pragma unroll
    for (int u=0;u<4;u++){ int i=i0+u; v[u] = (i<NN) ? cnt[i] : 0; s += v[u]; }
    __shared__ int sd[256];
    sd[t] = s;
    __syncthreads();
    for (int o=1;o<256;o<<=1){
        int x2 = 0;
        if (t >= o) x2 = sd[t-o];
        __syncthreads();
        if (t >= o) sd[t] += x2;
        __syncthreads();
    }
    int excl = part[y*128 + b] + sd[t] - s;
#pragma unroll
    for (int u=0;u<4;u++){
        int i = i0+u;
        if (i<NN){ off[i]=excl; cu[i]=excl; excl += v[u]; }
    }
}

__global__ void k_fill2(const int* __restrict__ e0, const int* __restrict__ e1,
                        int* __restrict__ cur, int* __restrict__ csr0, int* __restrict__ csr1){
    int e = blockIdx.x*256 + threadIdx.x;
    if (e >= EE) return;
    const int* ed = blockIdx.y ? e1 : e0;
    int* csr = blockIdx.y ? csr1 : csr0;
    int dst = ed[2*e], src = ed[2*e+1];
    int pos = atomicAdd(&cur[blockIdx.y*NN + dst], 1);
    csr[pos] = src;
}

// ---------------- gather (unroll-4 for MLP); degree -> cols 150/151 ----------------
__global__ void k_gath2(const u16* __restrict__ u0, const u16* __restrict__ u1,
                        const int* __restrict__ off0, const int* __restrict__ csr0,
                        const int* __restrict__ off1, const int* __restrict__ csr1,
                        u16* __restrict__ U0, u16* __restrict__ U1){
    int d = blockIdx.x*4 + (threadIdx.x>>6);
    if (d >= NN) return;
    int lane = threadIdx.x & 63;
    const u16* u = blockIdx.y ? u1 : u0;
    const int* off = blockIdx.y ? off1 : off0;
    const int* csr = blockIdx.y ? csr1 : csr0;
    u16* U = blockIdx.y ? U1 : U0;
    int e0 = off[d], e1 = off[d+1];
    bool tl = lane < 12;
    float s0=0.f, s1=0.f, t0=0.f, t1=0.f;
    int e = e0;
    for (; e+4 <= e1; e += 4){
        const u32* r0 = (const u32*)(u + (size_t)csr[e]  *APIT);
        const u32* r1 = (const u32*)(u + (size_t)csr[e+1]*APIT);
        const u32* r2 = (const u32*)(u + (size_t)csr[e+2]*APIT);
        const u32* r3 = (const u32*)(u + (size_t)csr[e+3]*APIT);
        u32 v0=r0[lane], v1=r1[lane], v2=r2[lane], v3=r3[lane];
        u32 w0=0, w1=0, w2=0, w3=0;
        if (tl){ w0=r0[64+lane]; w1=r1[64+lane]; w2=r2[64+lane]; w3=r3[64+lane]; }
        s0 += h2f((u16)(v0&0xffffu)) + h2f((u16)(v1&0xffffu)) + h2f((u16)(v2&0xffffu)) + h2f((u16)(v3&0xffffu));
        s1 += h2f((u16)(v0>>16))     + h2f((u16)(v1>>16))     + h2f((u16)(v2>>16))     + h2f((u16)(v3>>16));
        if (tl){
            t0 += h2f((u16)(w0&0xffffu)) + h2f((u16)(w1&0xffffu)) + h2f((u16)(w2&0xffffu)) + h2f((u16)(w3&0xffffu));
            t1 += h2f((u16)(w0>>16))     + h2f((u16)(w1>>16))     + h2f((u16)(w2>>16))     + h2f((u16)(w3>>16));
        }
    }
    for (; e < e1; e++){
        const u32* r = (const u32*)(u + (size_t)csr[e]*APIT);
        u32 v = r[lane];
        s0 += h2f((u16)(v & 0xffffu));
        s1 += h2f((u16)(v >> 16));
        if (tl){
            u32 w = r[64+lane];
            t0 += h2f((u16)(w & 0xffffu));
            t1 += h2f((u16)(w >> 16));
        }
    }
    if (lane == 11){ t0 = (float)(e1-e0); t1 = t0; }   // cols 150,151 = degree
    u32* Ur = (u32*)(U + (size_t)d*APIT);
    Ur[lane] = (u32)f2h(s0) | ((u32)f2h(s1) << 16);
    if (tl) Ur[64+lane] = (u32)f2h(t0) | ((u32)f2h(t1) << 16);
}

// ---------------- segment sum (64-row chunks) + readout ----------------
__global__ void k_seg(const u16* __restrict__ H, const int* __restrict__ gid, float* __restrict__ g){
    int f = threadIdx.x;
    if (f >= 150) return;
    int i0 = blockIdx.x*64;
    int i1 = i0 + 64; if (i1 > NN) i1 = NN;
    float acc = 0.f;
    int cg = gid[i0];
    for (int i=i0; i<i1; i++){
        int gg = gid[i];
        if (gg != cg){ atomicAdd(&g[cg*150+f], acc); acc=0.f; cg=gg; }
        acc += h2f(H[(size_t)i*APIT + f]);
    }
    atomicAdd(&g[cg*150+f], acc);
}

__global__ void k_mlp(const float* __restrict__ g, const float* __restrict__ pt,
                      const float* __restrict__ fc1p, const float* __restrict__ fc1b,
                      const float* __restrict__ fc2W, const float* __restrict__ fc2b,
                      const float* __restrict__ fcLW, const float* __restrict__ fcLb,
                      float* __restrict__ out){
    __shared__ float X[GG][152];
    __shared__ float Y[GG][80];
    __shared__ float Z[GG][80];
    int t = threadIdx.x;
    for (int idx=t; idx<GG*152; idx+=256){
        int gi=idx/152, c=idx-gi*152;
        float v = 0.f;
        if (c < 150){
            float lg = logf(g[gi*150+c]);
            if (lg != lg) lg = 0.f;
            v = fmaxf(lg, 0.f);
        } else if (c == 150) v = pt[gi];
        X[gi][c] = v;
    }
    __syncthreads();
    for (int idx=t; idx<GG*80; idx+=256){
        int gi=idx/80, o=idx-gi*80;
        float acc = fc1b[o];
        for (int k=0;k<151;k++) acc = fmaf(X[gi][k], fc1p[o*160+k], acc);
        Y[gi][o] = acc>0.f ? acc : 0.01f*acc;
    }
    __syncthreads();
    for (int idx=t; idx<GG*80; idx+=256){
        int gi=idx/80, o=idx-gi*80;
        float acc = fc2b[o];
        for (int k=0;k<80;k++) acc = fmaf(Y[gi][k], fc2W[o*80+k], acc);
        Z[gi][o] = acc>0.f ? acc : 0.01f*acc;
    }
    __syncthreads();
    for (int idx=t; idx<GG*10; idx+=256){
        int gi=idx/10, o=idx-gi*10;
        float acc = fcLb[o];
        for (int k=0;k<80;k++) acc = fmaf(Z[gi][k], fcLW[o*80+k], acc);
        out[idx] = acc;
    }
}

// ---------------- host ----------------
extern "C" void kernel_launch(void* const* d_in, const int* in_sizes, int n_in,
                              void* d_out, int out_size, void* d_ws, size_t ws_size,
                              hipStream_t stream) {
    const float* nodes = (const float*)d_in[0];
    const float* pt    = (const float*)d_in[1];
    const float* W1_0 = (const float*)d_in[2];  const float* b1_0 = (const float*)d_in[3];
    const float* W2_0 = (const float*)d_in[4];  const float* b2_0 = (const float*)d_in[5];
    const float* W1_1 = (const float*)d_in[6];  const float* b1_1 = (const float*)d_in[7];
    const float* W2_1 = (const float*)d_in[8];  const float* b2_1 = (const float*)d_in[9];
    const float* Wih = (const float*)d_in[10];  const float* bih = (const float*)d_in[11];
    const float* Whh = (const float*)d_in[12];  const float* bhh = (const float*)d_in[13];
    const float* fc1W = (const float*)d_in[14]; const float* fc1b = (const float*)d_in[15];
    const float* fc2W = (const float*)d_in[16]; const float* fc2b = (const float*)d_in[17];
    const float* fcLW = (const float*)d_in[18]; const float* fcLb = (const float*)d_in[19];
    const int* edges0 = (const int*)d_in[20];
    const int* edges1 = (const int*)d_in[21];
    const int* gid = (const int*)d_in[22];
    float* out = (float*)d_out;

    char* p = (char*)d_ws;
    auto alloc = [&](size_t bytes){ char* r = p; p += (bytes + 255) & ~(size_t)255; return r; };
    u16* XA  = (u16*)alloc((size_t)MROW*APIT*2);
    u16* XB  = (u16*)alloc((size_t)MROW*APIT*2);
    u16* U0  = (u16*)alloc((size_t)MROW*APIT*2);
    u16* U1  = (u16*)alloc((size_t)MROW*APIT*2);
    u16* Yu1 = (u16*)alloc((size_t)MROW*APIT*2);
    u16* W1f = (u16*)alloc((size_t)2*WFM*2);     // [set0|set1] frag-order fp16
    u16* Whf = (u16*)alloc((size_t)3*WFM*2);     // Whh gates r,z,n frag-order fp16
    u16* Cf  = (u16*)alloc((size_t)6*WFM*2);     // composite frag-order fp16
    float* tb   = (float*)alloc(4*160*4);
    float* b1t0 = (float*)alloc(160*4);
    float* b1t1 = (float*)alloc(160*4);
    float* fc1p = (float*)alloc(80*160*4);
    float* gbuf = (float*)alloc(GG*150*4);
    int* off0 = (int*)alloc((NN+1)*4);
    int* off1 = (int*)alloc((NN+1)*4);
    int* cur  = (int*)alloc((size_t)2*NN*4);
    int* hist = (int*)alloc((size_t)2*NN*4);
    int* part = (int*)alloc(2*128*4);
    int* csr0 = (int*)alloc((size_t)EE*4);
    int* csr1 = (int*)alloc((size_t)EE*4);
    (void)alloc(4096);   // tail pad for harmless last-row K-chunk overrun reads

    // ---- prep ----
    k_cast16<<<120, 256, 0, stream>>>(W1_0, 0, W1f);
    k_cast16<<<120, 256, 0, stream>>>(W1_1, 0, W1f + WFM);
    k_cast16<<<120, 256, 0, stream>>>(Whh, 0,   Whf);
    k_cast16<<<120, 256, 0, stream>>>(Whh, 150, Whf + WFM);
    k_cast16<<<120, 256, 0, stream>>>(Whh, 300, Whf + 2*WFM);
    k_comp<<<(6*192*160 + 255)/256, 256, 0, stream>>>(Wih, W2_0, W2_1, b2_0, b2_1, Cf);
    k_tabs<<<4, 256, 0, stream>>>(bih, bhh, b1_0, b1_1, tb, b1t0, b1t1);
    k_padfc1<<<50, 256, 0, stream>>>(fc1W, fc1p);
    k_inith<<<(NN*152 + 255)/256, 256, 0, stream>>>(nodes, XA);

    // ---- CSR (both sets batched via grid.y) ----
    hipMemsetAsync(hist, 0, (size_t)2*NN*sizeof(int), stream);
    dim3 gE((EE+255)/256, 2), gS(SNB, 2), g1(1, 2);
    k_hist2<<<gE, 256, 0, stream>>>(edges0, edges1, hist);
    k_psum<<<gS, 256, 0, stream>>>(hist, part);
    k_pscan<<<g1, 128, 0, stream>>>(part, off0, off1);
    k_papply<<<gS, 256, 0, stream>>>(hist, part, off0, off1, cur);
    k_fill2<<<gE, 256, 0, stream>>>(edges0, edges1, cur, csr0, csr1);

    // ---- message passes ----
    u16* Hc = XA; u16* Hx = XB;
    dim3 gT(MROW/64, 3);
    dim3 gGa((NN+3)/4, 2);
    for (int ps=0; ps<4; ps++){
        u16* yu0 = Hx;   // u scratch for set0 aliases h_next; dead before mega writes Hx
        k_ugemm2<<<gT, 256, 0, stream>>>(Hc, W1f, b1t0, b1t1, yu0, Yu1);
        k_gath2<<<gGa, 256, 0, stream>>>(yu0, Yu1, off0, csr0, off1, csr1, U0, U1);
        k_mega<<<gT, 256, 0, stream>>>(Hc, U0, U1, Cf, Whf, tb, Hx);
        u16* t = Hc; Hc = Hx; Hx = t;
    }

    // ---- readout ----
    hipMemsetAsync(gbuf, 0, GG*150*sizeof(float), stream);
    k_seg<<<(NN+63)/64, 192, 0, stream>>>(Hc, gid, gbuf);
    k_mlp<<<1, 256, 0, stream>>>(gbuf, pt, fc1p, fc1b, fc2W, fc2b, fcLW, fcLb, out);
}